// Round 2
// baseline (26064.041 us; speedup 1.0000x reference)
//
#include <hip/hip_runtime.h>
#include <hip/hip_bf16.h>

typedef __hip_bfloat16 bf16;

// ---------- helpers ----------
__device__ __forceinline__ float ldf(const float* p){ return *p; }
__device__ __forceinline__ float ldf(const bf16* p){ return __bfloat162float(*p); }
__device__ __forceinline__ void stf(float* p, float v){ *p = v; }
__device__ __forceinline__ void stf(bf16* p, float v){ *p = __float2bfloat16(v); }

__device__ __forceinline__ float gelu_f(float x){
  return 0.5f * x * (1.f + erff(x * 0.7071067811865475f));
}

template<bool MAX>
__device__ __forceinline__ float block_reduce(float v){
  __shared__ float s[4];
  #pragma unroll
  for (int o = 32; o > 0; o >>= 1){
    float t = __shfl_down(v, o, 64);
    v = MAX ? fmaxf(v, t) : (v + t);
  }
  int lane = threadIdx.x & 63, w = threadIdx.x >> 6;
  __syncthreads();
  if (lane == 0) s[w] = v;
  __syncthreads();
  return MAX ? fmaxf(fmaxf(s[0], s[1]), fmaxf(s[2], s[3]))
             : (s[0] + s[1] + s[2] + s[3]);
}

// ---------- dtype detect + convert ----------
// flag = 1 -> inputs are fp32; flag = 0 -> inputs are bf16.
__global__ void detect_k(const unsigned* __restrict__ x, int* __restrict__ flag){
  __shared__ int cnt[256];
  int tid = threadIdx.x;
  int c = 0;
  for (int i = tid; i < 4096; i += 256){
    unsigned h = x[i] & 0xffffu;        // low half-word as bf16
    int e = (int)((h >> 7) & 0xff);
    if (h == 0u || (e >= 100 && e <= 133)) c++;   // |v| in ~[2^-27, 128)
  }
  cnt[tid] = c;
  __syncthreads();
  for (int o = 128; o > 0; o >>= 1){ if (tid < o) cnt[tid] += cnt[tid+o]; __syncthreads(); }
  if (tid == 0) *flag = (cnt[0] < 2048) ? 1 : 0;
}

__global__ __launch_bounds__(256) void cvt_x_k(const void* __restrict__ src,
                                               float* __restrict__ X,
                                               const int* __restrict__ flag){
  int p = blockIdx.x*256 + threadIdx.x;
  X[p] = (*flag) ? ((const float*)src)[p]
                 : __bfloat162float(((const bf16*)src)[p]);
}

struct WCvt { const void* src[24]; long long cum[25]; };

__global__ __launch_bounds__(256) void cvt_w_k(WCvt a, bf16* __restrict__ WB,
                                               long long total, const int* __restrict__ flag){
  long long i = (long long)blockIdx.x*256 + threadIdx.x;
  if (i >= total) return;
  int t = 0;
  while (a.cum[t+1] <= i) t++;
  long long e = i - a.cum[t];
  WB[i] = (*flag) ? __float2bfloat16(((const float*)a.src[t])[e])
                  : ((const bf16*)a.src[t])[e];
}

__global__ __launch_bounds__(256) void store_out_k(const float* __restrict__ X,
                                                   void* __restrict__ out,
                                                   const int* __restrict__ flag){
  int p = blockIdx.x*256 + threadIdx.x;
  if (*flag) ((float*)out)[p] = X[p];
  else       ((bf16*)out)[p] = __float2bfloat16(X[p]);
}

// ---------- generic batched GEMM ----------
// C[bz] = act( alpha*op(A)@op(B) (+bias_n) )*scale_m + shift_m + bias_m  (+C if beta)
// Requires M%64==0, N%64==0, K%16==0. blockDim=256.
template<typename TA, typename TB, typename TC, bool TRA, bool TRB>
__global__ __launch_bounds__(256) void gemm_k(
    int M, int N, int K,
    const TA* __restrict__ A, int lda, long long sA,
    const TB* __restrict__ B, int ldb, long long sB,
    TC* __restrict__ C, int ldc, long long sC,
    float alpha, int beta,
    const bf16* __restrict__ bias_n,
    const bf16* __restrict__ bias_m,
    const float* __restrict__ scale_m,
    const float* __restrict__ shift_m,
    int act)
{
  __shared__ float As[16][65];
  __shared__ float Bs[16][65];
  const int tid = threadIdx.x;
  const int tx = tid & 15, ty = tid >> 4;
  const int m0 = blockIdx.y * 64, n0 = blockIdx.x * 64;
  const TA* Ab = A + (long long)blockIdx.z * sA;
  const TB* Bb = B + (long long)blockIdx.z * sB;
  TC* Cb = C + (long long)blockIdx.z * sC;

  float acc[4][4] = {};

  for (int k0 = 0; k0 < K; k0 += 16){
    if constexpr (!TRA){
      int kk = tid & 15, mmb = tid >> 4;
      #pragma unroll
      for (int r = 0; r < 4; ++r){
        int mm = mmb + 16*r;
        As[kk][mm] = ldf(&Ab[(long long)(m0+mm)*lda + (k0+kk)]);
      }
    } else {
      int mm = tid & 63, kkb = tid >> 6;
      #pragma unroll
      for (int r = 0; r < 4; ++r){
        int kk = kkb + 4*r;
        As[kk][mm] = ldf(&Ab[(long long)(k0+kk)*lda + (m0+mm)]);
      }
    }
    if constexpr (!TRB){
      int nn = tid & 63, kkb = tid >> 6;
      #pragma unroll
      for (int r = 0; r < 4; ++r){
        int kk = kkb + 4*r;
        Bs[kk][nn] = ldf(&Bb[(long long)(k0+kk)*ldb + (n0+nn)]);
      }
    } else {
      int kk = tid & 15, nnb = tid >> 4;
      #pragma unroll
      for (int r = 0; r < 4; ++r){
        int nn = nnb + 16*r;
        Bs[kk][nn] = ldf(&Bb[(long long)(n0+nn)*ldb + (k0+kk)]);
      }
    }
    __syncthreads();
    #pragma unroll
    for (int kk = 0; kk < 16; ++kk){
      float a[4], b[4];
      #pragma unroll
      for (int i = 0; i < 4; ++i) a[i] = As[kk][ty*4+i];
      #pragma unroll
      for (int j = 0; j < 4; ++j) b[j] = Bs[kk][tx*4+j];
      #pragma unroll
      for (int i = 0; i < 4; ++i)
        #pragma unroll
        for (int j = 0; j < 4; ++j)
          acc[i][j] += a[i] * b[j];
    }
    __syncthreads();
  }

  #pragma unroll
  for (int i = 0; i < 4; ++i){
    int m = m0 + ty*4 + i;
    float sm  = scale_m ? scale_m[m] : 1.f;
    float shm = shift_m ? shift_m[m] : 0.f;
    float bm  = bias_m ? __bfloat162float(bias_m[m]) : 0.f;
    #pragma unroll
    for (int j = 0; j < 4; ++j){
      int n = n0 + tx*4 + j;
      float v = acc[i][j] * alpha;
      if (bias_n) v += __bfloat162float(bias_n[n]);
      v = v * sm + shm + bm;
      if (act == 1) v = gelu_f(v);
      long long idx = (long long)m*ldc + n;
      if (beta) v += ldf(&Cb[idx]);
      stf(&Cb[idx], v);
    }
  }
}

template<typename TA, typename TB, typename TC, bool TRA, bool TRB>
static void gemm(hipStream_t st, int batch, int M, int N, int K,
                 const TA* A, int lda, long long sA,
                 const TB* B, int ldb, long long sB,
                 TC* C, int ldc, long long sC,
                 float alpha = 1.f, int beta = 0,
                 const bf16* bias_n = nullptr, const bf16* bias_m = nullptr,
                 const float* scale_m = nullptr, const float* shift_m = nullptr,
                 int act = 0)
{
  dim3 g(N/64, M/64, batch);
  gemm_k<TA,TB,TC,TRA,TRB><<<g, 256, 0, st>>>(M,N,K,A,lda,sA,B,ldb,sB,C,ldc,sC,
                                              alpha,beta,bias_n,bias_m,scale_m,shift_m,act);
}

// ---------- LayerNorm: one block per row of 512 ----------
__global__ __launch_bounds__(256) void ln_k(const float* __restrict__ X, float* __restrict__ Y,
                                            const bf16* __restrict__ w, const bf16* __restrict__ b){
  long long row = blockIdx.x;
  const float* x = X + row*512;
  float* y = Y + row*512;
  int tid = threadIdx.x;
  float v0 = x[tid], v1 = x[tid+256];
  float mean = block_reduce<false>(v0+v1) * (1.f/512.f);
  float msq  = block_reduce<false>(v0*v0+v1*v1) * (1.f/512.f);
  float var = msq - mean*mean;
  float rs = rsqrtf(var + 1e-5f);
  y[tid]     = (v0-mean)*rs*__bfloat162float(w[tid])     + __bfloat162float(b[tid]);
  y[tid+256] = (v1-mean)*rs*__bfloat162float(w[tid+256]) + __bfloat162float(b[tid+256]);
}

// ---------- softmax over last dim, in place; cols in {512,1024} ----------
template<typename T>
__global__ __launch_bounds__(256) void softmax_k(T* __restrict__ data, int cols){
  long long row = blockIdx.x;
  T* p = data + row * (long long)cols;
  int tid = threadIdx.x;
  int per = cols >> 8;
  float v[4];
  float mx = -3.4e38f;
  for (int r = 0; r < per; ++r){ v[r] = ldf(&p[tid + (r<<8)]); mx = fmaxf(mx, v[r]); }
  mx = block_reduce<true>(mx);
  float sum = 0.f;
  for (int r = 0; r < per; ++r){ v[r] = expf(v[r] - mx); sum += v[r]; }
  sum = block_reduce<false>(sum);
  float inv = 1.f / sum;
  for (int r = 0; r < per; ++r) stf(&p[tid + (r<<8)], v[r] * inv);
}

// ---------- 3x3 conv on attention maps (8->8 channels), one batch, SAME pad ----------
__global__ __launch_bounds__(256) void conv_attn_k(
    const bf16* __restrict__ in, bf16* __restrict__ out,
    const bf16* __restrict__ w, const bf16* __restrict__ bias)
{
  __shared__ float wt[8][8][9];
  __shared__ float bs[8];
  __shared__ bf16 tile[8][18][66];
  int tid = threadIdx.x;
  for (int t = tid; t < 576; t += 256) ((float*)wt)[t] = __bfloat162float(w[t]);
  if (tid < 8) bs[tid] = __bfloat162float(bias[tid]);
  int i0 = blockIdx.y * 16, j0 = blockIdx.x * 64;
  for (int t = tid; t < 8*18*66; t += 256){
    int hi = t / (18*66); int rem = t - hi*(18*66);
    int ii = rem / 66, jj = rem - ii*66;
    int gi = i0 + ii - 1, gj = j0 + jj - 1;
    float v = 0.f;
    if ((unsigned)gi < 1024u && (unsigned)gj < 1024u)
      v = __bfloat162float(in[(hi*1024 + gi)*1024 + gj]);
    tile[hi][ii][jj] = __float2bfloat16(v);
  }
  __syncthreads();
  #pragma unroll
  for (int r = 0; r < 4; ++r){
    int p = tid + 256*r;
    int ii = p >> 6, jj = p & 63;
    float acc[8];
    #pragma unroll
    for (int ho = 0; ho < 8; ++ho) acc[ho] = bs[ho];
    #pragma unroll
    for (int hi = 0; hi < 8; ++hi){
      float nb[9];
      #pragma unroll
      for (int di = 0; di < 3; ++di)
        #pragma unroll
        for (int dj = 0; dj < 3; ++dj)
          nb[di*3+dj] = __bfloat162float(tile[hi][ii+di][jj+dj]);
      #pragma unroll
      for (int ho = 0; ho < 8; ++ho){
        float a = acc[ho];
        #pragma unroll
        for (int d = 0; d < 9; ++d) a += wt[ho][hi][d] * nb[d];
        acc[ho] = a;
      }
    }
    #pragma unroll
    for (int ho = 0; ho < 8; ++ho)
      out[(ho*1024 + (i0+ii))*1024 + (j0+jj)] = __float2bfloat16(acc[ho]);
  }
}

// ---------- 3x3 conv, 1 channel, on (B,512,512) fp32 spectral map ----------
__global__ __launch_bounds__(256) void conv_spec_k(const float* __restrict__ in, float* __restrict__ out,
                                                   const bf16* __restrict__ w, const bf16* __restrict__ bias){
  int p = blockIdx.x*256 + threadIdx.x;
  int j = p & 511, i = (p >> 9) & 511, b = p >> 18;
  const float* ib = in + (long long)b*262144;
  float acc = __bfloat162float(bias[0]);
  #pragma unroll
  for (int di = 0; di < 3; ++di){
    int gi = i + di - 1;
    if ((unsigned)gi >= 512u) continue;
    #pragma unroll
    for (int dj = 0; dj < 3; ++dj){
      int gj = j + dj - 1;
      if ((unsigned)gj >= 512u) continue;
      acc += __bfloat162float(w[di*3+dj]) * ib[gi*512 + gj];
    }
  }
  out[p] = acc;
}

// ---------- depthwise 3x3 over 32x32 token grid; H2 (b,n,c) -> T1 (b,c,n) ----------
__global__ __launch_bounds__(256) void dwconv_k(const float* __restrict__ H2, float* __restrict__ T1,
                                                const bf16* __restrict__ w, const bf16* __restrict__ bias){
  int p = blockIdx.x*256 + threadIdx.x;
  int c = p & 511;
  int n = (p >> 9) & 1023;
  int b = p >> 19;
  int wi = n >> 5, hi = n & 31;
  float acc = __bfloat162float(bias[c]);
  #pragma unroll
  for (int di = 0; di < 3; ++di){
    int gw = wi + di - 1;
    if ((unsigned)gw >= 32u) continue;
    #pragma unroll
    for (int dj = 0; dj < 3; ++dj){
      int gh = hi + dj - 1;
      if ((unsigned)gh >= 32u) continue;
      acc += __bfloat162float(w[c*9 + di*3 + dj]) * H2[((long long)b*1024 + (gw*32+gh))*512 + c];
    }
  }
  T1[((long long)b*512 + c)*1024 + n] = acc;
}

// ---------- fold pw bias + BN(eval) into per-channel scale/shift ----------
__global__ void bnaff_k(const bf16* __restrict__ pwb, const bf16* __restrict__ g,
                        const bf16* __restrict__ bb, const bf16* __restrict__ m,
                        const bf16* __restrict__ v, float* __restrict__ scale,
                        float* __restrict__ shift){
  int o = threadIdx.x;
  float s = __bfloat162float(g[o]) * rsqrtf(__bfloat162float(v[o]) + 1e-5f);
  scale[o] = s;
  shift[o] = (__bfloat162float(pwb[o]) - __bfloat162float(m[o])) * s + __bfloat162float(bb[o]);
}

// ---------- X += H2 + T4^T ----------
__global__ __launch_bounds__(256) void add3_k(float* __restrict__ X, const float* __restrict__ H2,
                                              const float* __restrict__ T4){
  int p = blockIdx.x*256 + threadIdx.x;
  int c = p & 511; int n = (p >> 9) & 1023; int b = p >> 19;
  X[p] += H2[p] + T4[((long long)b*512 + c)*1024 + n];
}

// ---------- orchestration ----------
extern "C" void kernel_launch(void* const* d_in, const int* in_sizes, int n_in,
                              void* d_out, int out_size, void* d_ws, size_t ws_size,
                              hipStream_t stream)
{
  (void)in_sizes; (void)n_in; (void)out_size; (void)ws_size;

  // ---- workspace arena ----
  char* base = (char*)d_ws;
  float* X    = (float*)base;                       // 2,097,152 f
  float* Hbuf = X    + 2097152;                     // 2,097,152 f
  float* OUTH = Hbuf + 2097152;                     // 2,097,152 f
  float* OUT  = OUTH + 2097152;                     // 2,097,152 f
  bf16*  QKV  = (bf16*)(OUT + 2097152);             // 6,291,456 bf16
  bf16*  ATTN = QKV  + 6291456;                     // 8,388,608 bf16
  bf16*  ATTNC= ATTN + 8388608;                     // 8,388,608 bf16
  bf16*  WB   = ATTNC + 8388608;                    // 18,916,680 bf16 (pad to 18,916,864)
  float* BNAFF= (float*)(WB + 18916864);            // 512 f
  int*   FLAG = (int*)(BNAFF + 512);

  // aliases (sequentially dead regions)
  float* SQK    = (float*)ATTN;          // (b,512,2048) spectral q|k  (16.78 MB)
  float* ASPEC  = OUTH;                  // (b,512,512)
  float* ASPECC = OUTH + 1048576;
  float* T1 = (float*)ATTN;              // (b,512,1024) dwconv out
  float* T3 = T1 + 2097152;              // (b,512,1024) c1 out
  float* T2 = (float*)ATTNC;             // (b,256,1024) pw+bn out
  float* T4 = T2 + 1048576;              // (b,512,1024) c2 out

  // ---- weight arena layout (inputs 1..24) ----
  static const long long wsz[24] = {
    2048, 2048, 3145728, 1048576, 2048, 2304, 32, 12582912, 36, 4,
    2048, 2048, 18432, 2048, 524288, 1024, 1024, 1024, 1024, 1024,
    524288, 2048, 1048576, 2048 };
  WCvt wc;
  long long cum = 0;
  bf16* wbp[24];
  for (int t = 0; t < 24; ++t){
    wc.src[t] = d_in[t+1];
    wc.cum[t] = cum;
    wbp[t] = WB + cum;
    cum += wsz[t];
  }
  wc.cum[24] = cum;                      // 18,916,680

  bf16 *w_ln1w = wbp[0],  *w_ln1b = wbp[1],  *w_Wqkv = wbp[2],  *w_Wout = wbp[3];
  bf16 *w_bout = wbp[4],  *w_spw  = wbp[5],  *w_spb  = wbp[6],  *w_Wqs  = wbp[7];
  bf16 *w_specw= wbp[8],  *w_specb= wbp[9],  *w_ln2w = wbp[10], *w_ln2b = wbp[11];
  bf16 *w_dww  = wbp[12], *w_dwb  = wbp[13], *w_pww  = wbp[14], *w_pwb  = wbp[15];
  bf16 *w_bng  = wbp[16], *w_bnb  = wbp[17], *w_bnm  = wbp[18], *w_bnv  = wbp[19];
  bf16 *w_c1w  = wbp[20], *w_c1b  = wbp[21], *w_c2w  = wbp[22], *w_c2b  = wbp[23];

  // ---- dtype detect + convert ----
  detect_k<<<1, 256, 0, stream>>>((const unsigned*)d_in[0], FLAG);
  cvt_x_k<<<8192, 256, 0, stream>>>(d_in[0], X, FLAG);
  cvt_w_k<<<(int)((cum + 255) / 256), 256, 0, stream>>>(wc, WB, cum, FLAG);

  for (int l = 0; l < 4; ++l){
    // --- spatial attention ---
    ln_k<<<4096, 256, 0, stream>>>(X, Hbuf, w_ln1w + l*512, w_ln1b + l*512);
    gemm<float,bf16,bf16,false,false>(stream, 1, 4096, 1536, 512,
        Hbuf, 512, 0, w_Wqkv + (long long)l*512*1536, 1536, 0, QKV, 1536, 0);
    for (int b = 0; b < 4; ++b){
      bf16* qkvb = QKV + (long long)b*1024*1536;
      gemm<bf16,bf16,bf16,false,true>(stream, 8, 1024, 1024, 64,
          qkvb, 1536, 64, qkvb + 512, 1536, 64, ATTN, 1024, 1048576, 0.125f);
      softmax_k<bf16><<<8192, 256, 0, stream>>>(ATTN, 1024);
      conv_attn_k<<<dim3(16,64), 256, 0, stream>>>(ATTN, ATTNC, w_spw + l*576, w_spb + l*8);
      gemm<bf16,bf16,float,false,false>(stream, 8, 1024, 64, 1024,
          ATTNC, 1024, 1048576, qkvb + 1024, 1536, 64,
          OUTH + (long long)b*1024*512, 512, 64);
    }
    gemm<float,bf16,float,false,false>(stream, 1, 4096, 512, 512,
        OUTH, 512, 0, w_Wout + (long long)l*512*512, 512, 0, OUT, 512, 0,
        1.f, 0, w_bout + l*512);
    // --- spectral attention on h^T ---
    gemm<float,bf16,float,true,false>(stream, 4, 512, 2048, 1024,
        Hbuf, 512, 524288, w_Wqs + (long long)l*1024*3072, 3072, 0, SQK, 2048, 1048576);
    gemm<float,float,float,false,true>(stream, 4, 512, 512, 1024,
        SQK, 2048, 1048576, SQK + 1024, 2048, 1048576, ASPEC, 512, 262144, 0.125f);
    softmax_k<float><<<2048, 256, 0, stream>>>(ASPEC, 512);
    conv_spec_k<<<4096, 256, 0, stream>>>(ASPEC, ASPECC, w_specw + l*9, w_specb + l);
    gemm<float,float,float,false,false>(stream, 4, 1024, 512, 512,
        OUT, 512, 524288, ASPECC, 512, 262144, X, 512, 524288, 1.f, 1);
    // --- conv FFN ---
    ln_k<<<4096, 256, 0, stream>>>(X, Hbuf, w_ln2w + l*512, w_ln2b + l*512);
    dwconv_k<<<8192, 256, 0, stream>>>(Hbuf, T1, w_dww + l*4608, w_dwb + l*512);
    bnaff_k<<<1, 256, 0, stream>>>(w_pwb + l*256, w_bng + l*256, w_bnb + l*256,
                                   w_bnm + l*256, w_bnv + l*256, BNAFF, BNAFF + 256);
    gemm<bf16,float,float,false,false>(stream, 4, 256, 1024, 512,
        w_pww + (long long)l*256*512, 512, 0, T1, 1024, 524288, T2, 1024, 262144,
        1.f, 0, nullptr, nullptr, BNAFF, BNAFF + 256);
    gemm<bf16,float,float,false,false>(stream, 4, 512, 1024, 256,
        w_c1w + (long long)l*512*256, 256, 0, T2, 1024, 262144, T3, 1024, 524288,
        1.f, 0, nullptr, w_c1b + l*512, nullptr, nullptr, 1);
    gemm<bf16,float,float,false,false>(stream, 4, 512, 1024, 512,
        w_c2w + (long long)l*512*512, 512, 0, T3, 1024, 524288, T4, 1024, 524288,
        1.f, 0, nullptr, w_c2b + l*512, nullptr, nullptr, 1);
    add3_k<<<8192, 256, 0, stream>>>(X, Hbuf, T4);
  }

  store_out_k<<<8192, 256, 0, stream>>>(X, d_out, FLAG);
}

// Round 3
// 2448.749 us; speedup vs baseline: 10.6438x; 10.6438x over previous
//
#include <hip/hip_runtime.h>
#include <hip/hip_bf16.h>

typedef __hip_bfloat16 bf16;
typedef __attribute__((ext_vector_type(8))) short bf16x8;
typedef __attribute__((ext_vector_type(4))) float f32x4;

// ---------- helpers ----------
__device__ __forceinline__ float b2f(bf16 v){ return __bfloat162float(v); }
__device__ __forceinline__ bf16 f2b(float v){ return __float2bfloat16(v); }
__device__ __forceinline__ float bits2f(unsigned u){ return __uint_as_float(u << 16); }

__device__ __forceinline__ float gelu_f(float x){
  return 0.5f * x * (1.f + erff(x * 0.7071067811865475f));
}

__device__ __forceinline__ void gload_lds(const void* g, void* l){
  __builtin_amdgcn_global_load_lds((const __attribute__((address_space(1))) void*)g,
                                   (__attribute__((address_space(3))) void*)l, 16, 0, 0);
}

template<bool MAX>
__device__ __forceinline__ float block_reduce(float v){
  __shared__ float s[4];
  #pragma unroll
  for (int o = 32; o > 0; o >>= 1){
    float t = __shfl_down(v, o, 64);
    v = MAX ? fmaxf(v, t) : (v + t);
  }
  int lane = threadIdx.x & 63, w = threadIdx.x >> 6;
  __syncthreads();
  if (lane == 0) s[w] = v;
  __syncthreads();
  return MAX ? fmaxf(fmaxf(s[0], s[1]), fmaxf(s[2], s[3]))
             : (s[0] + s[1] + s[2] + s[3]);
}

// ---------- dtype detect + converters ----------
__global__ void detect_k(const unsigned* __restrict__ x, int* __restrict__ flag){
  __shared__ int cnt[256];
  int tid = threadIdx.x;
  int c = 0;
  for (int i = tid; i < 4096; i += 256){
    unsigned h = x[i] & 0xffffu;
    int e = (int)((h >> 7) & 0xff);
    if (h == 0u || (e >= 100 && e <= 133)) c++;
  }
  cnt[tid] = c;
  __syncthreads();
  for (int o = 128; o > 0; o >>= 1){ if (tid < o) cnt[tid] += cnt[tid+o]; __syncthreads(); }
  if (tid == 0) *flag = (cnt[0] < 2048) ? 1 : 0;
}

__global__ __launch_bounds__(256) void cvt_x_k(const void* __restrict__ src,
                                               float* __restrict__ X,
                                               const int* __restrict__ flag){
  int p = blockIdx.x*256 + threadIdx.x;
  X[p] = (*flag) ? ((const float*)src)[p]
                 : __bfloat162float(((const bf16*)src)[p]);
}

struct WCvt21 { const void* src[21]; long long cum[22]; };

__global__ __launch_bounds__(256) void cvt_w_k(WCvt21 a, bf16* __restrict__ WB,
                                               long long total, const int* __restrict__ flag){
  long long i = (long long)blockIdx.x*256 + threadIdx.x;
  if (i >= total) return;
  int t = 0;
  while (a.cum[t+1] <= i) t++;
  long long e = i - a.cum[t];
  WB[i] = (*flag) ? __float2bfloat16(((const float*)a.src[t])[e])
                  : ((const bf16*)a.src[t])[e];
}

// transpose + convert weight: dst[z][c][r] = src[z][r][c], tiles 64x64
__global__ __launch_bounds__(256) void wtrans_k(const void* __restrict__ src, bf16* __restrict__ dst,
                                                int ld_src, int ldd, long long sSrc, long long sDst,
                                                const int* __restrict__ flag){
  __shared__ bf16 t[64][65];
  int z = blockIdx.z;
  int r0 = blockIdx.x*64, c0 = blockIdx.y*64;
  int lane = threadIdx.x & 63, quad = threadIdx.x >> 6;
  const float* sf = (const float*)src;
  const bf16* sb = (const bf16*)src;
  int fl = *flag;
  #pragma unroll
  for (int k = 0; k < 16; ++k){
    int r = quad*16 + k;
    long long idx = z*sSrc + (long long)(r0+r)*ld_src + c0 + lane;
    float v = fl ? sf[idx] : b2f(sb[idx]);
    t[r][lane] = f2b(v);
  }
  __syncthreads();
  #pragma unroll
  for (int k = 0; k < 16; ++k){
    int c = quad*16 + k;
    dst[z*sDst + (long long)(c0+c)*ldd + r0 + lane] = t[lane][c];
  }
}

__global__ __launch_bounds__(256) void store_out_k(const float* __restrict__ X,
                                                   void* __restrict__ out,
                                                   const int* __restrict__ flag){
  int p = blockIdx.x*256 + threadIdx.x;
  if (*flag) ((float*)out)[p] = X[p];
  else       ((bf16*)out)[p] = f2b(X[p]);
}

// ---------- MFMA GEMM: C[z] = epi( alpha * A(MxK,row) x Bt(NxK,row)^T ) ----------
// BM=128, BN=NF*32; 4 waves in 2x2; wave tile 64 x (NF*16). K % 32 == 0.
template<int NF, typename TC>
__global__ __launch_bounds__(256) void gmfma_k(
    int M, int N, int K,
    const bf16* __restrict__ A, int lda, long long sA,
    const bf16* __restrict__ Bt, int ldb, long long sB,
    TC* __restrict__ C, int ldc, long long sC,
    float alpha, int beta,
    const bf16* __restrict__ bias_n,
    const float* __restrict__ scale_n,
    const float* __restrict__ shift_n,
    int act)
{
  constexpr int BN = NF*32;
  constexpr int CH = 8 + BN/16;     // 1KB staging chunks: 8 for A, BN/16 for B
  __shared__ bf16 Asm[128][32];
  __shared__ bf16 Bsm[BN][32];
  const int tid = threadIdx.x;
  const int lane = tid & 63, wid = tid >> 6;
  const int wm = wid >> 1, wn = wid & 1;
  const int m0 = blockIdx.y*128, n0 = blockIdx.x*BN;
  const bf16* Ab = A + (long long)blockIdx.z * sA;
  const bf16* Bb = Bt + (long long)blockIdx.z * sB;
  TC* Cb = C + (long long)blockIdx.z * sC;

  f32x4 acc[4][NF];
  f32x4 zero = {0.f, 0.f, 0.f, 0.f};
  #pragma unroll
  for (int m = 0; m < 4; ++m)
    #pragma unroll
    for (int n = 0; n < NF; ++n) acc[m][n] = zero;

  const int rchunk = lane >> 2;          // row within 16-row chunk
  const int kchunk = (lane & 3) * 8;     // k element offset (16B)
  const int row16 = lane & 15, kq = (lane >> 4) * 8;

  for (int k0 = 0; k0 < K; k0 += 32){
    #pragma unroll
    for (int cc = 0; cc < CH/4; ++cc){
      int c = wid + cc*4;
      if (c < 8){
        int row = c*16 + rchunk;
        gload_lds(Ab + (long long)(m0+row)*lda + k0 + kchunk, &Asm[c*16][0]);
      } else {
        int row = (c-8)*16 + rchunk;
        gload_lds(Bb + (long long)(n0+row)*ldb + k0 + kchunk, &Bsm[(c-8)*16][0]);
      }
    }
    __syncthreads();
    bf16x8 af[4], bfr[NF];
    #pragma unroll
    for (int m = 0; m < 4; ++m)
      af[m] = *(const bf16x8*)&Asm[wm*64 + m*16 + row16][kq];
    #pragma unroll
    for (int n = 0; n < NF; ++n)
      bfr[n] = *(const bf16x8*)&Bsm[wn*(NF*16) + n*16 + row16][kq];
    #pragma unroll
    for (int m = 0; m < 4; ++m)
      #pragma unroll
      for (int n = 0; n < NF; ++n)
        acc[m][n] = __builtin_amdgcn_mfma_f32_16x16x32_bf16(af[m], bfr[n], acc[m][n], 0, 0, 0);
    __syncthreads();
  }

  #pragma unroll
  for (int m = 0; m < 4; ++m){
    #pragma unroll
    for (int n = 0; n < NF; ++n){
      int gn = n0 + wn*(NF*16) + n*16 + (lane & 15);
      float bn_ = bias_n ? b2f(bias_n[gn]) : 0.f;
      float sc = scale_n ? scale_n[gn] : 1.f;
      float sh = shift_n ? shift_n[gn] : 0.f;
      #pragma unroll
      for (int r = 0; r < 4; ++r){
        int gm = m0 + wm*64 + m*16 + (lane >> 4)*4 + r;
        float v = acc[m][n][r] * alpha + bn_;
        v = v * sc + sh;
        if (act) v = gelu_f(v);
        long long idx = (long long)gm*ldc + gn;
        if (beta){
          float old;
          if constexpr (__is_same(TC, float)) old = Cb[idx]; else old = b2f(Cb[idx]);
          v += old;
        }
        if constexpr (__is_same(TC, float)) Cb[idx] = v; else Cb[idx] = f2b(v);
      }
    }
  }
}

template<int NF, typename TC>
static void gmfma(hipStream_t st, int z, int M, int N, int K,
                  const bf16* A, int lda, long long sA,
                  const bf16* Bt, int ldb, long long sB,
                  TC* C, int ldc, long long sC,
                  float alpha = 1.f, int beta = 0,
                  const bf16* bias_n = nullptr,
                  const float* scale_n = nullptr, const float* shift_n = nullptr,
                  int act = 0)
{
  dim3 g(N/(NF*32), M/128, z);
  gmfma_k<NF,TC><<<g, 256, 0, st>>>(M,N,K,A,lda,sA,Bt,ldb,sB,C,ldc,sC,
                                    alpha,beta,bias_n,scale_n,shift_n,act);
}

// ---------- LayerNorm fp32 -> bf16 ----------
__global__ __launch_bounds__(256) void ln_k(const float* __restrict__ X, bf16* __restrict__ Y,
                                            const bf16* __restrict__ w, const bf16* __restrict__ b){
  long long row = blockIdx.x;
  const float* x = X + row*512;
  bf16* y = Y + row*512;
  int tid = threadIdx.x;
  float v0 = x[tid], v1 = x[tid+256];
  float mean = block_reduce<false>(v0+v1) * (1.f/512.f);
  float msq  = block_reduce<false>(v0*v0+v1*v1) * (1.f/512.f);
  float var = msq - mean*mean;
  float rs = rsqrtf(var + 1e-5f);
  y[tid]     = f2b((v0-mean)*rs*b2f(w[tid])     + b2f(b[tid]));
  y[tid+256] = f2b((v1-mean)*rs*b2f(w[tid+256]) + b2f(b[tid+256]));
}

// ---------- softmax over last dim in place ----------
__device__ __forceinline__ float ldf(const float* p){ return *p; }
__device__ __forceinline__ float ldf(const bf16* p){ return b2f(*p); }
__device__ __forceinline__ void stf(float* p, float v){ *p = v; }
__device__ __forceinline__ void stf(bf16* p, float v){ *p = f2b(v); }

template<typename T>
__global__ __launch_bounds__(256) void softmax_k(T* __restrict__ data, int cols){
  long long row = blockIdx.x;
  T* p = data + row * (long long)cols;
  int tid = threadIdx.x;
  int per = cols >> 8;
  float v[4];
  float mx = -3.4e38f;
  for (int r = 0; r < per; ++r){ v[r] = ldf(&p[tid + (r<<8)]); mx = fmaxf(mx, v[r]); }
  mx = block_reduce<true>(mx);
  float sum = 0.f;
  for (int r = 0; r < per; ++r){ v[r] = expf(v[r] - mx); sum += v[r]; }
  sum = block_reduce<false>(sum);
  float inv = 1.f / sum;
  for (int r = 0; r < per; ++r) stf(&p[tid + (r<<8)], v[r] * inv);
}

// ---------- 3x3 conv on attention maps (8->8 ch), one batch ----------
// grid (1024/64, 1024/4); block 256 = 4 rows x 64 cols; 1 out position/thread
__global__ __launch_bounds__(256) void conv_attn_k(
    const bf16* __restrict__ in, bf16* __restrict__ out,
    const bf16* __restrict__ w, const bf16* __restrict__ bias)
{
  __shared__ float wt[8][8][9];
  __shared__ float bs[8];
  __shared__ bf16 tile[8][6][66];
  int tid = threadIdx.x;
  for (int t = tid; t < 576; t += 256) ((float*)wt)[t] = b2f(w[t]);
  if (tid < 8) bs[tid] = b2f(bias[tid]);
  int j0 = blockIdx.x * 64, i0 = blockIdx.y * 4;
  for (int t = tid; t < 8*6*66; t += 256){
    int hi = t / 396; int rem = t - hi*396;
    int ii = rem / 66, jj = rem - ii*66;
    int gi = i0 + ii - 1, gj = j0 + jj - 1;
    float v = 0.f;
    if ((unsigned)gi < 1024u && (unsigned)gj < 1024u)
      v = b2f(in[(hi << 20) + (gi << 10) + gj]);
    tile[hi][ii][jj] = f2b(v);
  }
  __syncthreads();
  int jj = tid & 63, ii = tid >> 6;
  float acc[8];
  #pragma unroll
  for (int ho = 0; ho < 8; ++ho) acc[ho] = bs[ho];
  #pragma unroll
  for (int hi = 0; hi < 8; ++hi){
    float nb[9];
    #pragma unroll
    for (int di = 0; di < 3; ++di)
      #pragma unroll
      for (int dj = 0; dj < 3; ++dj)
        nb[di*3+dj] = b2f(tile[hi][ii+di][jj+dj]);
    #pragma unroll
    for (int ho = 0; ho < 8; ++ho){
      float a = acc[ho];
      #pragma unroll
      for (int d = 0; d < 9; ++d) a += wt[ho][hi][d] * nb[d];
      acc[ho] = a;
    }
  }
  int oi = i0 + ii, oj = j0 + jj;
  #pragma unroll
  for (int ho = 0; ho < 8; ++ho)
    out[(ho << 20) + (oi << 10) + oj] = f2b(acc[ho]);
}

// ---------- 3x3 conv, 1 ch, (B,512,512) fp32 in, bf16 TRANSPOSED out ----------
__global__ __launch_bounds__(256) void conv_spec_k(const float* __restrict__ in, bf16* __restrict__ out,
                                                   const bf16* __restrict__ w, const bf16* __restrict__ bias){
  int p = blockIdx.x*256 + threadIdx.x;           // i fastest
  int i = p & 511, j = (p >> 9) & 511, b = p >> 18;
  const float* ib = in + (long long)b*262144;
  float acc = b2f(bias[0]);
  #pragma unroll
  for (int di = 0; di < 3; ++di){
    int gi = i + di - 1;
    if ((unsigned)gi >= 512u) continue;
    #pragma unroll
    for (int dj = 0; dj < 3; ++dj){
      int gj = j + dj - 1;
      if ((unsigned)gj >= 512u) continue;
      acc += b2f(w[di*3+dj]) * ib[gi*512 + gj];
    }
  }
  out[(long long)b*262144 + j*512 + i] = f2b(acc);  // transposed: out[e][d]=a[d][e]
}

// ---------- depthwise 3x3; Hbuf (b,n,c) bf16 -> T1 (b,n,c) bf16; 2 ch per thread ----------
__global__ __launch_bounds__(256) void dwconv_k(const bf16* __restrict__ H2, bf16* __restrict__ T1,
                                                const bf16* __restrict__ w, const bf16* __restrict__ bias){
  int p = blockIdx.x*256 + threadIdx.x;           // 4*1024*256
  int cp = p & 255;
  int n = (p >> 8) & 1023;
  int b = p >> 18;
  int c0 = cp*2;
  int wi = n >> 5, hg = n & 31;
  float a0 = b2f(bias[c0]), a1 = b2f(bias[c0+1]);
  #pragma unroll
  for (int di = 0; di < 3; ++di){
    int gw = wi + di - 1;
    if ((unsigned)gw >= 32u) continue;
    #pragma unroll
    for (int dj = 0; dj < 3; ++dj){
      int gh = hg + dj - 1;
      if ((unsigned)gh >= 32u) continue;
      unsigned hv = *(const unsigned*)&H2[((long long)b*1024 + (gw*32+gh))*512 + c0];
      float w0 = b2f(w[c0*9 + di*3 + dj]);
      float w1 = b2f(w[(c0+1)*9 + di*3 + dj]);
      a0 += w0 * bits2f(hv & 0xffffu);
      a1 += w1 * bits2f(hv >> 16);
    }
  }
  bf16 h0 = f2b(a0), h1 = f2b(a1);
  unsigned o = ((unsigned)*(unsigned short*)&h1 << 16) | (unsigned)*(unsigned short*)&h0;
  *(unsigned*)&T1[((long long)b*1024 + n)*512 + c0] = o;
}

// ---------- fold pw bias + BN(eval) into per-channel scale/shift ----------
__global__ void bnaff_k(const bf16* __restrict__ pwb, const bf16* __restrict__ g,
                        const bf16* __restrict__ bb, const bf16* __restrict__ m,
                        const bf16* __restrict__ v, float* __restrict__ scale,
                        float* __restrict__ shift){
  int o = threadIdx.x;
  float s = b2f(g[o]) * rsqrtf(b2f(v[o]) + 1e-5f);
  scale[o] = s;
  shift[o] = (b2f(pwb[o]) - b2f(m[o])) * s + b2f(bb[o]);
}

// ---------- X += Hbuf + T4 (all [b][n][c], elementwise) ----------
__global__ __launch_bounds__(256) void add3_k(float* __restrict__ X, const bf16* __restrict__ Hb,
                                              const bf16* __restrict__ T4){
  int p = blockIdx.x*256 + threadIdx.x;
  X[p] += b2f(Hb[p]) + b2f(T4[p]);
}

// ---------- Vt[b*8+h][d][n] = QKV[b][n][1024 + h*64 + d] ----------
__global__ __launch_bounds__(256) void vtrans_k(const bf16* __restrict__ QKV, bf16* __restrict__ Vt){
  __shared__ bf16 t[64][65];
  int z = blockIdx.z; int b = z >> 3, h = z & 7;
  const bf16* src = QKV + (long long)b*1572864 + 1024 + h*64;
  bf16* dst = Vt + (long long)z*65536;
  int n0 = blockIdx.x*64;
  int lane = threadIdx.x & 63, quad = threadIdx.x >> 6;
  #pragma unroll
  for (int k = 0; k < 16; ++k){
    int r = quad*16 + k;
    t[r][lane] = src[(long long)(n0+r)*1536 + lane];
  }
  __syncthreads();
  #pragma unroll
  for (int k = 0; k < 16; ++k){
    int d = quad*16 + k;
    dst[(long long)d*1024 + n0 + lane] = t[lane][d];
  }
}

// ---------- HbufT[b][c][n] = Hbuf[b][n][c] ----------
__global__ __launch_bounds__(256) void htrans_k(const bf16* __restrict__ Hb, bf16* __restrict__ HT){
  __shared__ bf16 t[64][65];
  int b = blockIdx.z;
  int n0 = blockIdx.x*64, c0 = blockIdx.y*64;
  int lane = threadIdx.x & 63, quad = threadIdx.x >> 6;
  #pragma unroll
  for (int k = 0; k < 16; ++k){
    int r = quad*16 + k;
    t[r][lane] = Hb[((long long)b*1024 + n0 + r)*512 + c0 + lane];
  }
  __syncthreads();
  #pragma unroll
  for (int k = 0; k < 16; ++k){
    int c = quad*16 + k;
    HT[(long long)b*524288 + (long long)(c0+c)*1024 + n0 + lane] = t[lane][c];
  }
}

// ---------- orchestration ----------
extern "C" void kernel_launch(void* const* d_in, const int* in_sizes, int n_in,
                              void* d_out, int out_size, void* d_ws, size_t ws_size,
                              hipStream_t stream)
{
  (void)in_sizes; (void)n_in; (void)out_size; (void)ws_size;

  // ---- arena ----
  float* X     = (float*)d_ws;                    // 2,097,152 f32
  bf16*  WBsm  = (bf16*)(X + 2097152);            // 2,139,648 (21 small tensors)
  bf16*  WqkvT = WBsm  + 2139648;                 // 3,145,728
  bf16*  WoutT = WqkvT + 3145728;                 // 1,048,576
  bf16*  WqsT  = WoutT + 1048576;                 // 8,388,608
  bf16*  Hbuf  = WqsT  + 8388608;                 // 2,097,152
  bf16*  HbufT = Hbuf  + 2097152;                 // 2,097,152
  bf16*  QKV   = HbufT + 2097152;                 // 6,291,456
  bf16*  Vt    = QKV   + 6291456;                 // 2,097,152
  bf16*  OUTH  = Vt    + 2097152;                 // 2,097,152  (alias ASPEC f32)
  bf16*  OUT   = OUTH  + 2097152;                 // 2,097,152
  bf16*  ATTN  = OUT   + 2097152;                 // 8,388,608  (alias SQK, T1, T3)
  bf16*  ATTNC = ATTN  + 8388608;                 // 8,388,608  (alias ASPECC_T, T2, T4)
  float* BNAFF = (float*)(ATTNC + 8388608);       // 512 f32
  int*   FLAG  = (int*)(BNAFF + 512);

  float* ASPEC   = (float*)OUTH;                  // (b,512,512) f32
  bf16*  ASPECCT = ATTNC;                         // (b,512,512) bf16, transposed
  bf16*  T1 = ATTN;                               // (b,1024,512)
  bf16*  T3 = ATTN + 2097152;                     // (b,1024,512)
  bf16*  T2 = ATTNC + 2097152;                    // (b,1024,256)
  bf16*  T4 = ATTNC + 4194304;                    // (b,1024,512)
  bf16*  SQK = ATTN;                              // (b,512,2048)

  // ---- small-weight arena: order + sizes ----
  static const int widx[21] = {1,2,5,6,7,9,10,11,12,13,14,15,16,17,18,19,20,21,22,23,24};
  static const long long wsz[21] = {2048,2048,2048,2304,32,36,4,2048,2048,18432,2048,
                                    524288,1024,1024,1024,1024,1024,524288,2048,1048576,2048};
  WCvt21 wc;
  long long cum = 0;
  bf16* wp[21];
  for (int t = 0; t < 21; ++t){
    wc.src[t] = d_in[widx[t]];
    wc.cum[t] = cum;
    wp[t] = WBsm + cum;
    cum += wsz[t];
  }
  wc.cum[21] = cum;

  bf16 *w_ln1w = wp[0],  *w_ln1b = wp[1],  *w_bout = wp[2],  *w_spw = wp[3];
  bf16 *w_spb  = wp[4],  *w_specw= wp[5],  *w_specb= wp[6],  *w_ln2w= wp[7];
  bf16 *w_ln2b = wp[8],  *w_dww  = wp[9],  *w_dwb  = wp[10], *w_pww = wp[11];
  bf16 *w_pwb  = wp[12], *w_bng  = wp[13], *w_bnb  = wp[14], *w_bnm = wp[15];
  bf16 *w_bnv  = wp[16], *w_c1w  = wp[17], *w_c1b  = wp[18], *w_c2w = wp[19];
  bf16 *w_c2b  = wp[20];

  // ---- setup: detect dtype, convert everything ----
  detect_k<<<1, 256, 0, stream>>>((const unsigned*)d_in[0], FLAG);
  cvt_x_k<<<8192, 256, 0, stream>>>(d_in[0], X, FLAG);
  cvt_w_k<<<(int)((cum + 255)/256), 256, 0, stream>>>(wc, WBsm, cum, FLAG);
  wtrans_k<<<dim3(8,24,4), 256, 0, stream>>>(d_in[3], WqkvT, 1536, 512, 786432LL, 786432LL, FLAG);
  wtrans_k<<<dim3(8, 8,4), 256, 0, stream>>>(d_in[4], WoutT,  512, 512, 262144LL, 262144LL, FLAG);
  wtrans_k<<<dim3(16,32,4),256, 0, stream>>>(d_in[8], WqsT,  3072,1024, 3145728LL,2097152LL, FLAG);

  for (int l = 0; l < 4; ++l){
    // --- spatial attention ---
    ln_k<<<4096, 256, 0, stream>>>(X, Hbuf, w_ln1w + l*512, w_ln1b + l*512);
    gmfma<4,bf16>(stream, 1, 4096, 1536, 512,
        Hbuf, 512, 0, WqkvT + (long long)l*786432, 512, 0, QKV, 1536, 0);
    vtrans_k<<<dim3(16,1,32), 256, 0, stream>>>(QKV, Vt);
    for (int b = 0; b < 4; ++b){
      bf16* qkvb = QKV + (long long)b*1572864;
      gmfma<4,bf16>(stream, 8, 1024, 1024, 64,
          qkvb, 1536, 64, qkvb + 512, 1536, 64, ATTN, 1024, 1048576, 0.125f);
      softmax_k<bf16><<<8192, 256, 0, stream>>>(ATTN, 1024);
      conv_attn_k<<<dim3(16,256), 256, 0, stream>>>(ATTN, ATTNC, w_spw + l*576, w_spb + l*8);
      gmfma<2,bf16>(stream, 8, 1024, 64, 1024,
          ATTNC, 1024, 1048576, Vt + (long long)b*524288, 1024, 65536,
          OUTH + (long long)b*524288, 512, 64);
    }
    gmfma<4,bf16>(stream, 1, 4096, 512, 512,
        OUTH, 512, 0, WoutT + (long long)l*262144, 512, 0, OUT, 512, 0,
        1.f, 0, w_bout + l*512);
    // --- spectral attention ---
    htrans_k<<<dim3(16,8,4), 256, 0, stream>>>(Hbuf, HbufT);
    gmfma<4,bf16>(stream, 4, 512, 2048, 1024,
        HbufT, 1024, 524288, WqsT + (long long)l*2097152, 1024, 0, SQK, 2048, 1048576);
    gmfma<4,float>(stream, 4, 512, 512, 1024,
        SQK, 2048, 1048576, SQK + 1024, 2048, 1048576, ASPEC, 512, 262144, 0.125f);
    softmax_k<float><<<2048, 256, 0, stream>>>(ASPEC, 512);
    conv_spec_k<<<4096, 256, 0, stream>>>(ASPEC, ASPECCT, w_specw + l*9, w_specb + l);
    gmfma<4,float>(stream, 4, 1024, 512, 512,
        OUT, 512, 524288, ASPECCT, 512, 262144, X, 512, 524288, 1.f, 1);
    // --- conv FFN ---
    ln_k<<<4096, 256, 0, stream>>>(X, Hbuf, w_ln2w + l*512, w_ln2b + l*512);
    dwconv_k<<<4096, 256, 0, stream>>>(Hbuf, T1, w_dww + l*4608, w_dwb + l*512);
    bnaff_k<<<1, 256, 0, stream>>>(w_pwb + l*256, w_bng + l*256, w_bnb + l*256,
                                   w_bnm + l*256, w_bnv + l*256, BNAFF, BNAFF + 256);
    gmfma<4,bf16>(stream, 4, 1024, 256, 512,
        T1, 512, 524288, w_pww + (long long)l*131072, 512, 0, T2, 256, 262144,
        1.f, 0, nullptr, BNAFF, BNAFF + 256);
    gmfma<4,bf16>(stream, 4, 1024, 512, 256,
        T2, 256, 262144, w_c1w + (long long)l*131072, 256, 0, T3, 512, 524288,
        1.f, 0, w_c1b + l*512, nullptr, nullptr, 1);
    gmfma<4,bf16>(stream, 4, 1024, 512, 512,
        T3, 512, 524288, w_c2w + (long long)l*262144, 512, 0, T4, 512, 524288,
        1.f, 0, w_c2b + l*512, nullptr, nullptr, 1);
    add3_k<<<8192, 256, 0, stream>>>(X, Hbuf, T4);
  }

  store_out_k<<<8192, 256, 0, stream>>>(X, d_out, FLAG);
}

// Round 4
// 1621.906 us; speedup vs baseline: 16.0700x; 1.5098x over previous
//
#include <hip/hip_runtime.h>
#include <hip/hip_bf16.h>

typedef __hip_bfloat16 bf16;
typedef __attribute__((ext_vector_type(8))) short bf16x8;
typedef __attribute__((ext_vector_type(4))) float f32x4;

// ---------- helpers ----------
__device__ __forceinline__ float b2f(bf16 v){ return __bfloat162float(v); }
__device__ __forceinline__ bf16 f2b(float v){ return __float2bfloat16(v); }
__device__ __forceinline__ float bits2f(unsigned u){ return __uint_as_float(u << 16); }

__device__ __forceinline__ float gelu_f(float x){
  return 0.5f * x * (1.f + erff(x * 0.7071067811865475f));
}

__device__ __forceinline__ void gload_lds(const void* g, void* l){
  __builtin_amdgcn_global_load_lds((const __attribute__((address_space(1))) void*)g,
                                   (__attribute__((address_space(3))) void*)l, 16, 0, 0);
}

template<bool MAX>
__device__ __forceinline__ float block_reduce(float v){
  __shared__ float s[4];
  #pragma unroll
  for (int o = 32; o > 0; o >>= 1){
    float t = __shfl_down(v, o, 64);
    v = MAX ? fmaxf(v, t) : (v + t);
  }
  int lane = threadIdx.x & 63, w = threadIdx.x >> 6;
  __syncthreads();
  if (lane == 0) s[w] = v;
  __syncthreads();
  return MAX ? fmaxf(fmaxf(s[0], s[1]), fmaxf(s[2], s[3]))
             : (s[0] + s[1] + s[2] + s[3]);
}

// ---------- dtype detect + converters ----------
__global__ void detect_k(const unsigned* __restrict__ x, int* __restrict__ flag){
  __shared__ int cnt[256];
  int tid = threadIdx.x;
  int c = 0;
  for (int i = tid; i < 4096; i += 256){
    unsigned h = x[i] & 0xffffu;
    int e = (int)((h >> 7) & 0xff);
    if (h == 0u || (e >= 100 && e <= 133)) c++;
  }
  cnt[tid] = c;
  __syncthreads();
  for (int o = 128; o > 0; o >>= 1){ if (tid < o) cnt[tid] += cnt[tid+o]; __syncthreads(); }
  if (tid == 0) *flag = (cnt[0] < 2048) ? 1 : 0;
}

__global__ __launch_bounds__(256) void cvt_x_k(const void* __restrict__ src,
                                               float* __restrict__ X,
                                               const int* __restrict__ flag){
  int p = blockIdx.x*256 + threadIdx.x;
  X[p] = (*flag) ? ((const float*)src)[p]
                 : __bfloat162float(((const bf16*)src)[p]);
}

struct WCvt21 { const void* src[21]; long long cum[22]; };

__global__ __launch_bounds__(256) void cvt_w_k(WCvt21 a, bf16* __restrict__ WB,
                                               long long total, const int* __restrict__ flag){
  long long i = (long long)blockIdx.x*256 + threadIdx.x;
  if (i >= total) return;
  int t = 0;
  while (a.cum[t+1] <= i) t++;
  long long e = i - a.cum[t];
  WB[i] = (*flag) ? __float2bfloat16(((const float*)a.src[t])[e])
                  : ((const bf16*)a.src[t])[e];
}

// transpose + convert weight: dst[z][c][r] = src[z][r][c], tiles 64x64
__global__ __launch_bounds__(256) void wtrans_k(const void* __restrict__ src, bf16* __restrict__ dst,
                                                int ld_src, int ldd, long long sSrc, long long sDst,
                                                const int* __restrict__ flag){
  __shared__ bf16 t[64][65];
  int z = blockIdx.z;
  int r0 = blockIdx.x*64, c0 = blockIdx.y*64;
  int lane = threadIdx.x & 63, quad = threadIdx.x >> 6;
  const float* sf = (const float*)src;
  const bf16* sb = (const bf16*)src;
  int fl = *flag;
  #pragma unroll
  for (int k = 0; k < 16; ++k){
    int r = quad*16 + k;
    long long idx = z*sSrc + (long long)(r0+r)*ld_src + c0 + lane;
    float v = fl ? sf[idx] : b2f(sb[idx]);
    t[r][lane] = f2b(v);
  }
  __syncthreads();
  #pragma unroll
  for (int k = 0; k < 16; ++k){
    int c = quad*16 + k;
    dst[z*sDst + (long long)(c0+c)*ldd + r0 + lane] = t[lane][c];
  }
}

__global__ __launch_bounds__(256) void store_out_k(const float* __restrict__ X,
                                                   void* __restrict__ out,
                                                   const int* __restrict__ flag){
  int p = blockIdx.x*256 + threadIdx.x;
  if (*flag) ((float*)out)[p] = X[p];
  else       ((bf16*)out)[p] = f2b(X[p]);
}

// ---------- MFMA GEMM ----------
// C[z] = epi( alpha * A(MxK,row) x Bt(NxK,row)^T ); z decomposes as (z&7, z>>3)
// BM=MF*32, BN=NF*32; 4 waves 2x2; wave tile (MF*16)x(NF*16). K%32==0.
template<int MF, int NF, typename TC>
__global__ __launch_bounds__(256) void gmfma_k(
    int M, int N, int K,
    const bf16* __restrict__ A, int lda, long long sA, long long sA2,
    const bf16* __restrict__ Bt, int ldb, long long sB, long long sB2,
    TC* __restrict__ C, int ldc, long long sC, long long sC2,
    float alpha, int beta,
    const bf16* __restrict__ bias_n,
    const float* __restrict__ scale_n,
    const float* __restrict__ shift_n,
    const bf16* __restrict__ addF,
    int act)
{
  constexpr int BM = MF*32, BN = NF*32;
  constexpr int CHA = BM/16, CH = (BM+BN)/16;
  static_assert(CH % 4 == 0, "chunks must divide among 4 waves");
  __shared__ bf16 Asm[BM][32];
  __shared__ bf16 Bsm[BN][32];
  const int tid = threadIdx.x;
  const int lane = tid & 63, wid = tid >> 6;
  const int wm = wid >> 1, wn = wid & 1;
  const int m0 = blockIdx.y*BM, n0 = blockIdx.x*BN;
  const int z = blockIdx.z;
  const long long zl = z & 7, zh = z >> 3;
  const bf16* Ab = A + zl*sA + zh*sA2;
  const bf16* Bb = Bt + zl*sB + zh*sB2;
  TC* Cb = C + zl*sC + zh*sC2;

  f32x4 acc[MF][NF];
  f32x4 zero = {0.f, 0.f, 0.f, 0.f};
  #pragma unroll
  for (int m = 0; m < MF; ++m)
    #pragma unroll
    for (int n = 0; n < NF; ++n) acc[m][n] = zero;

  const int rchunk = lane >> 2;          // row within 16-row chunk
  const int kchunk = (lane & 3) * 8;     // k element offset (16B)
  const int row16 = lane & 15, kq = (lane >> 4) * 8;

  for (int k0 = 0; k0 < K; k0 += 32){
    #pragma unroll
    for (int cc = 0; cc < CH/4; ++cc){
      int c = wid + cc*4;
      if (c < CHA){
        int row = c*16 + rchunk;
        gload_lds(Ab + (long long)(m0+row)*lda + k0 + kchunk, &Asm[c*16][0]);
      } else {
        int row = (c-CHA)*16 + rchunk;
        gload_lds(Bb + (long long)(n0+row)*ldb + k0 + kchunk, &Bsm[(c-CHA)*16][0]);
      }
    }
    __syncthreads();
    bf16x8 af[MF], bfr[NF];
    #pragma unroll
    for (int m = 0; m < MF; ++m)
      af[m] = *(const bf16x8*)&Asm[wm*(MF*16) + m*16 + row16][kq];
    #pragma unroll
    for (int n = 0; n < NF; ++n)
      bfr[n] = *(const bf16x8*)&Bsm[wn*(NF*16) + n*16 + row16][kq];
    #pragma unroll
    for (int m = 0; m < MF; ++m)
      #pragma unroll
      for (int n = 0; n < NF; ++n)
        acc[m][n] = __builtin_amdgcn_mfma_f32_16x16x32_bf16(af[m], bfr[n], acc[m][n], 0, 0, 0);
    __syncthreads();
  }

  #pragma unroll
  for (int m = 0; m < MF; ++m){
    #pragma unroll
    for (int n = 0; n < NF; ++n){
      int gn = n0 + wn*(NF*16) + n*16 + (lane & 15);
      float bn_ = bias_n ? b2f(bias_n[gn]) : 0.f;
      float sc = scale_n ? scale_n[gn] : 1.f;
      float sh = shift_n ? shift_n[gn] : 0.f;
      #pragma unroll
      for (int r = 0; r < 4; ++r){
        int gm = m0 + wm*(MF*16) + m*16 + (lane >> 4)*4 + r;
        float v = acc[m][n][r] * alpha + bn_;
        v = v * sc + sh;
        if (act) v = gelu_f(v);
        long long idx = (long long)gm*ldc + gn;
        if (addF) v += b2f(addF[zl*sC + zh*sC2 - ((long long)(Cb - C)) + (long long)(Cb - C) + idx]); // same offset as C
        if (beta){
          float old;
          if constexpr (__is_same(TC, float)) old = Cb[idx]; else old = b2f(Cb[idx]);
          v += old;
        }
        if constexpr (__is_same(TC, float)) Cb[idx] = v; else Cb[idx] = f2b(v);
      }
    }
  }
}

template<int MF, int NF, typename TC>
static void gmfma_x(hipStream_t st, int z, int M, int N, int K,
                    const bf16* A, int lda, long long sA, long long sA2,
                    const bf16* Bt, int ldb, long long sB, long long sB2,
                    TC* C, int ldc, long long sC, long long sC2,
                    float alpha = 1.f, int beta = 0,
                    const bf16* bias_n = nullptr,
                    const float* scale_n = nullptr, const float* shift_n = nullptr,
                    const bf16* addF = nullptr, int act = 0)
{
  dim3 g(N/(NF*32), M/(MF*32), z);
  gmfma_k<MF,NF,TC><<<g, 256, 0, st>>>(M,N,K,A,lda,sA,sA2,Bt,ldb,sB,sB2,C,ldc,sC,sC2,
                                       alpha,beta,bias_n,scale_n,shift_n,addF,act);
}

template<int MF, int NF, typename TC>
static void gmfma(hipStream_t st, int z, int M, int N, int K,
                  const bf16* A, int lda, long long sA,
                  const bf16* Bt, int ldb, long long sB,
                  TC* C, int ldc, long long sC,
                  float alpha = 1.f, int beta = 0,
                  const bf16* bias_n = nullptr,
                  const float* scale_n = nullptr, const float* shift_n = nullptr,
                  const bf16* addF = nullptr, int act = 0)
{
  gmfma_x<MF,NF,TC>(st, z, M, N, K, A, lda, sA, 8*sA, Bt, ldb, sB, 8*sB,
                    C, ldc, sC, 8*sC, alpha, beta, bias_n, scale_n, shift_n, addF, act);
}

// ---------- LayerNorm fp32 -> bf16 ----------
__global__ __launch_bounds__(256) void ln_k(const float* __restrict__ X, bf16* __restrict__ Y,
                                            const bf16* __restrict__ w, const bf16* __restrict__ b){
  long long row = blockIdx.x;
  const float* x = X + row*512;
  bf16* y = Y + row*512;
  int tid = threadIdx.x;
  float v0 = x[tid], v1 = x[tid+256];
  float mean = block_reduce<false>(v0+v1) * (1.f/512.f);
  float msq  = block_reduce<false>(v0*v0+v1*v1) * (1.f/512.f);
  float var = msq - mean*mean;
  float rs = rsqrtf(var + 1e-5f);
  y[tid]     = f2b((v0-mean)*rs*b2f(w[tid])     + b2f(b[tid]));
  y[tid+256] = f2b((v1-mean)*rs*b2f(w[tid+256]) + b2f(b[tid+256]));
}

// ---------- softmax over last dim in place ----------
__device__ __forceinline__ float ldf(const float* p){ return *p; }
__device__ __forceinline__ float ldf(const bf16* p){ return b2f(*p); }
__device__ __forceinline__ void stf(float* p, float v){ *p = v; }
__device__ __forceinline__ void stf(bf16* p, float v){ *p = f2b(v); }

template<typename T>
__global__ __launch_bounds__(256) void softmax_k(T* __restrict__ data, int cols){
  long long row = blockIdx.x;
  T* p = data + row * (long long)cols;
  int tid = threadIdx.x;
  int per = cols >> 8;
  float v[4];
  float mx = -3.4e38f;
  for (int r = 0; r < per; ++r){ v[r] = ldf(&p[tid + (r<<8)]); mx = fmaxf(mx, v[r]); }
  mx = block_reduce<true>(mx);
  float sum = 0.f;
  for (int r = 0; r < per; ++r){ v[r] = expf(v[r] - mx); sum += v[r]; }
  sum = block_reduce<false>(sum);
  float inv = 1.f / sum;
  for (int r = 0; r < per; ++r) stf(&p[tid + (r<<8)], v[r] * inv);
}

// ---------- 3x3 conv on attention maps (8->8 ch), z = batch index ----------
// grid (1024/64, 1024/4, NB); block 256 = 4 rows x 64 cols
__global__ __launch_bounds__(256) void conv_attn_k(
    const bf16* __restrict__ in_, bf16* __restrict__ out_,
    const bf16* __restrict__ w, const bf16* __restrict__ bias)
{
  const bf16* in = in_ + (long long)blockIdx.z * 8388608;
  bf16* out = out_ + (long long)blockIdx.z * 8388608;
  __shared__ float wt[8][8][9];
  __shared__ float bs[8];
  __shared__ bf16 tile[8][6][66];
  int tid = threadIdx.x;
  for (int t = tid; t < 576; t += 256) ((float*)wt)[t] = b2f(w[t]);
  if (tid < 8) bs[tid] = b2f(bias[tid]);
  int j0 = blockIdx.x * 64, i0 = blockIdx.y * 4;
  for (int t = tid; t < 8*6*66; t += 256){
    int hi = t / 396; int rem = t - hi*396;
    int ii = rem / 66, jj = rem - ii*66;
    int gi = i0 + ii - 1, gj = j0 + jj - 1;
    float v = 0.f;
    if ((unsigned)gi < 1024u && (unsigned)gj < 1024u)
      v = b2f(in[(hi << 20) + (gi << 10) + gj]);
    tile[hi][ii][jj] = f2b(v);
  }
  __syncthreads();
  int jj = tid & 63, ii = tid >> 6;
  float acc[8];
  #pragma unroll
  for (int ho = 0; ho < 8; ++ho) acc[ho] = bs[ho];
  #pragma unroll
  for (int hi = 0; hi < 8; ++hi){
    float nb[9];
    #pragma unroll
    for (int di = 0; di < 3; ++di)
      #pragma unroll
      for (int dj = 0; dj < 3; ++dj)
        nb[di*3+dj] = b2f(tile[hi][ii+di][jj+dj]);
    #pragma unroll
    for (int ho = 0; ho < 8; ++ho){
      float a = acc[ho];
      #pragma unroll
      for (int d = 0; d < 9; ++d) a += wt[ho][hi][d] * nb[d];
      acc[ho] = a;
    }
  }
  int oi = i0 + ii, oj = j0 + jj;
  #pragma unroll
  for (int ho = 0; ho < 8; ++ho)
    out[(ho << 20) + (oi << 10) + oj] = f2b(acc[ho]);
}

// ---------- 3x3 conv, 1 ch, (B,512,512) fp32 in -> bf16 TRANSPOSED out ----------
// grid (8,8,4); 64x64 tile; coalesced loads; transpose via LDS
__global__ __launch_bounds__(256) void conv_spec_k(const float* __restrict__ in, bf16* __restrict__ out,
                                                   const bf16* __restrict__ w, const bf16* __restrict__ bias){
  __shared__ float ti[66][67];
  __shared__ bf16 toutT[64][65];
  int b = blockIdx.z;
  int i0 = blockIdx.y*64, j0 = blockIdx.x*64;
  int tid = threadIdx.x;
  const float* ib = in + (long long)b*262144;
  for (int t = tid; t < 66*66; t += 256){
    int r = t / 66, c = t - r*66;
    int gi = i0 + r - 1, gj = j0 + c - 1;
    float v = 0.f;
    if ((unsigned)gi < 512u && (unsigned)gj < 512u) v = ib[gi*512 + gj];
    ti[r][c] = v;
  }
  __syncthreads();
  float w9[9], bv = b2f(bias[0]);
  #pragma unroll
  for (int d = 0; d < 9; ++d) w9[d] = b2f(w[d]);
  int ii = tid & 63;
  #pragma unroll
  for (int q = 0; q < 16; ++q){
    int jj = (tid >> 6)*16 + q;
    float acc = bv;
    #pragma unroll
    for (int di = 0; di < 3; ++di)
      #pragma unroll
      for (int dj = 0; dj < 3; ++dj)
        acc += w9[di*3+dj] * ti[ii+di][jj+dj];
    toutT[jj][ii] = f2b(acc);
  }
  __syncthreads();
  #pragma unroll
  for (int q = 0; q < 16; ++q){
    int jj = (tid >> 6)*16 + q;
    out[(long long)b*262144 + (j0+jj)*512 + i0 + (tid & 63)] = toutT[jj][tid & 63];
  }
}

// ---------- depthwise 3x3; Hbuf (b,n,c) bf16 -> T1 (b,n,c) bf16; 2 ch per thread ----------
__global__ __launch_bounds__(256) void dwconv_k(const bf16* __restrict__ H2, bf16* __restrict__ T1,
                                                const bf16* __restrict__ w, const bf16* __restrict__ bias){
  int p = blockIdx.x*256 + threadIdx.x;
  int cp = p & 255;
  int n = (p >> 8) & 1023;
  int b = p >> 18;
  int c0 = cp*2;
  int wi = n >> 5, hg = n & 31;
  float a0 = b2f(bias[c0]), a1 = b2f(bias[c0+1]);
  #pragma unroll
  for (int di = 0; di < 3; ++di){
    int gw = wi + di - 1;
    if ((unsigned)gw >= 32u) continue;
    #pragma unroll
    for (int dj = 0; dj < 3; ++dj){
      int gh = hg + dj - 1;
      if ((unsigned)gh >= 32u) continue;
      unsigned hv = *(const unsigned*)&H2[((long long)b*1024 + (gw*32+gh))*512 + c0];
      float w0 = b2f(w[c0*9 + di*3 + dj]);
      float w1 = b2f(w[(c0+1)*9 + di*3 + dj]);
      a0 += w0 * bits2f(hv & 0xffffu);
      a1 += w1 * bits2f(hv >> 16);
    }
  }
  bf16 h0 = f2b(a0), h1 = f2b(a1);
  unsigned o = ((unsigned)*(unsigned short*)&h1 << 16) | (unsigned)*(unsigned short*)&h0;
  *(unsigned*)&T1[((long long)b*1024 + n)*512 + c0] = o;
}

// ---------- fold pw bias + BN(eval), all layers; grid(4) x 256 ----------
__global__ void bnaff_all_k(const bf16* __restrict__ pwb, const bf16* __restrict__ g,
                            const bf16* __restrict__ bb, const bf16* __restrict__ m,
                            const bf16* __restrict__ v, float* __restrict__ BNAFF){
  int l = blockIdx.x, o = threadIdx.x;
  float s = b2f(g[l*256+o]) * rsqrtf(b2f(v[l*256+o]) + 1e-5f);
  BNAFF[l*512 + o] = s;
  BNAFF[l*512 + 256 + o] = (b2f(pwb[l*256+o]) - b2f(m[l*256+o])) * s + b2f(bb[l*256+o]);
}

// ---------- Vt[b*8+h][d][n] = QKV[b][n][1024 + h*64 + d] ----------
__global__ __launch_bounds__(256) void vtrans_k(const bf16* __restrict__ QKV, bf16* __restrict__ Vt){
  __shared__ bf16 t[64][65];
  int z = blockIdx.z; int b = z >> 3, h = z & 7;
  const bf16* src = QKV + (long long)b*1572864 + 1024 + h*64;
  bf16* dst = Vt + (long long)z*65536;
  int n0 = blockIdx.x*64;
  int lane = threadIdx.x & 63, quad = threadIdx.x >> 6;
  #pragma unroll
  for (int k = 0; k < 16; ++k){
    int r = quad*16 + k;
    t[r][lane] = src[(long long)(n0+r)*1536 + lane];
  }
  __syncthreads();
  #pragma unroll
  for (int k = 0; k < 16; ++k){
    int d = quad*16 + k;
    dst[(long long)d*1024 + n0 + lane] = t[lane][d];
  }
}

// ---------- HbufT[b][c][n] = Hbuf[b][n][c] ----------
__global__ __launch_bounds__(256) void htrans_k(const bf16* __restrict__ Hb, bf16* __restrict__ HT){
  __shared__ bf16 t[64][65];
  int b = blockIdx.z;
  int n0 = blockIdx.x*64, c0 = blockIdx.y*64;
  int lane = threadIdx.x & 63, quad = threadIdx.x >> 6;
  #pragma unroll
  for (int k = 0; k < 16; ++k){
    int r = quad*16 + k;
    t[r][lane] = Hb[((long long)b*1024 + n0 + r)*512 + c0 + lane];
  }
  __syncthreads();
  #pragma unroll
  for (int k = 0; k < 16; ++k){
    int c = quad*16 + k;
    HT[(long long)b*524288 + (long long)(c0+c)*1024 + n0 + lane] = t[lane][c];
  }
}

// ---------- orchestration ----------
extern "C" void kernel_launch(void* const* d_in, const int* in_sizes, int n_in,
                              void* d_out, int out_size, void* d_ws, size_t ws_size,
                              hipStream_t stream)
{
  (void)in_sizes; (void)n_in; (void)out_size;

  const bool big = ws_size >= 206000000ull;       // batched attention maps path
  const long long ATTN_SZ = big ? 33554432LL : 8388608LL;

  // ---- arena ----
  float* X     = (float*)d_ws;                    // 2,097,152 f32
  bf16*  WBsm  = (bf16*)(X + 2097152);            // 2,139,648
  bf16*  WqkvT = WBsm  + 2139648;                 // 3,145,728
  bf16*  WoutT = WqkvT + 3145728;                 // 1,048,576
  bf16*  WqsT  = WoutT + 1048576;                 // 8,388,608
  bf16*  Hbuf  = WqsT  + 8388608;                 // 2,097,152
  bf16*  HbufT = Hbuf  + 2097152;                 // 2,097,152
  bf16*  QKV   = HbufT + 2097152;                 // 6,291,456
  bf16*  Vt    = QKV   + 6291456;                 // 2,097,152
  bf16*  OUTH  = Vt    + 2097152;                 // 2,097,152  (alias ASPEC f32)
  bf16*  OUT   = OUTH  + 2097152;                 // 2,097,152
  bf16*  ATTN  = OUT   + 2097152;                 // ATTN_SZ    (alias SQK, T1, T3)
  bf16*  ATTNC = ATTN  + ATTN_SZ;                 // ATTN_SZ    (alias ASPECC_T, T2)
  float* BNAFF = (float*)(ATTNC + ATTN_SZ);       // 2048 f32
  int*   FLAG  = (int*)(BNAFF + 2048);

  float* ASPEC   = (float*)OUTH;                  // (b,512,512) f32
  bf16*  ASPECCT = ATTNC;                         // (b,512,512) bf16, transposed
  bf16*  T1 = ATTN;                               // (b,1024,512)
  bf16*  T3 = ATTN + 2097152;                     // (b,1024,512)
  bf16*  T2 = ATTNC + 2097152;                    // (b,1024,256)
  bf16*  SQK = ATTN;                              // (b,512,2048)

  // ---- small-weight arena ----
  static const int widx[21] = {1,2,5,6,7,9,10,11,12,13,14,15,16,17,18,19,20,21,22,23,24};
  static const long long wsz[21] = {2048,2048,2048,2304,32,36,4,2048,2048,18432,2048,
                                    524288,1024,1024,1024,1024,1024,524288,2048,1048576,2048};
  WCvt21 wc;
  long long cum = 0;
  bf16* wp[21];
  for (int t = 0; t < 21; ++t){
    wc.src[t] = d_in[widx[t]];
    wc.cum[t] = cum;
    wp[t] = WBsm + cum;
    cum += wsz[t];
  }
  wc.cum[21] = cum;

  bf16 *w_ln1w = wp[0],  *w_ln1b = wp[1],  *w_bout = wp[2],  *w_spw = wp[3];
  bf16 *w_spb  = wp[4],  *w_specw= wp[5],  *w_specb= wp[6],  *w_ln2w= wp[7];
  bf16 *w_ln2b = wp[8],  *w_dww  = wp[9],  *w_dwb  = wp[10], *w_pww = wp[11];
  bf16 *w_pwb  = wp[12], *w_bng  = wp[13], *w_bnb  = wp[14], *w_bnm = wp[15];
  bf16 *w_bnv  = wp[16], *w_c1w  = wp[17], *w_c1b  = wp[18], *w_c2w = wp[19];
  bf16 *w_c2b  = wp[20];

  // ---- setup ----
  detect_k<<<1, 256, 0, stream>>>((const unsigned*)d_in[0], FLAG);
  cvt_x_k<<<8192, 256, 0, stream>>>(d_in[0], X, FLAG);
  cvt_w_k<<<(int)((cum + 255)/256), 256, 0, stream>>>(wc, WBsm, cum, FLAG);
  wtrans_k<<<dim3(8,24,4), 256, 0, stream>>>(d_in[3], WqkvT, 1536, 512, 786432LL, 786432LL, FLAG);
  wtrans_k<<<dim3(8, 8,4), 256, 0, stream>>>(d_in[4], WoutT,  512, 512, 262144LL, 262144LL, FLAG);
  wtrans_k<<<dim3(16,32,4),256, 0, stream>>>(d_in[8], WqsT,  3072,1024, 3145728LL,2097152LL, FLAG);
  bnaff_all_k<<<4, 256, 0, stream>>>(w_pwb, w_bng, w_bnb, w_bnm, w_bnv, BNAFF);

  for (int l = 0; l < 4; ++l){
    // --- spatial attention ---
    ln_k<<<4096, 256, 0, stream>>>(X, Hbuf, w_ln1w + l*512, w_ln1b + l*512);
    gmfma<4,4,bf16>(stream, 1, 4096, 1536, 512,
        Hbuf, 512, 0, WqkvT + (long long)l*786432, 512, 0, QKV, 1536, 0);
    vtrans_k<<<dim3(16,1,32), 256, 0, stream>>>(QKV, Vt);
    if (big){
      gmfma_x<4,4,bf16>(stream, 32, 1024, 1024, 64,
          QKV, 1536, 64, 1572864, QKV + 512, 1536, 64, 1572864,
          ATTN, 1024, 1048576, 8388608, 0.125f);
      softmax_k<bf16><<<32768, 256, 0, stream>>>(ATTN, 1024);
      conv_attn_k<<<dim3(16,256,4), 256, 0, stream>>>(ATTN, ATTNC, w_spw + l*576, w_spb + l*8);
      gmfma_x<2,2,bf16>(stream, 32, 1024, 64, 1024,
          ATTNC, 1024, 1048576, 8388608, Vt, 1024, 65536, 524288,
          OUTH, 512, 64, 524288);
    } else {
      for (int b = 0; b < 4; ++b){
        bf16* qkvb = QKV + (long long)b*1572864;
        gmfma<4,4,bf16>(stream, 8, 1024, 1024, 64,
            qkvb, 1536, 64, qkvb + 512, 1536, 64, ATTN, 1024, 1048576, 0.125f);
        softmax_k<bf16><<<8192, 256, 0, stream>>>(ATTN, 1024);
        conv_attn_k<<<dim3(16,256,1), 256, 0, stream>>>(ATTN, ATTNC, w_spw + l*576, w_spb + l*8);
        gmfma<2,2,bf16>(stream, 8, 1024, 64, 1024,
            ATTNC, 1024, 1048576, Vt + (long long)b*524288, 1024, 65536,
            OUTH + (long long)b*524288, 512, 64);
      }
    }
    gmfma<2,2,bf16>(stream, 1, 4096, 512, 512,
        OUTH, 512, 0, WoutT + (long long)l*262144, 512, 0, OUT, 512, 0,
        1.f, 0, w_bout + l*512);
    // --- spectral attention ---
    htrans_k<<<dim3(16,8,4), 256, 0, stream>>>(Hbuf, HbufT);
    gmfma<4,4,bf16>(stream, 4, 512, 2048, 1024,
        HbufT, 1024, 524288, WqsT + (long long)l*2097152, 1024, 0, SQK, 2048, 1048576);
    gmfma<2,2,float>(stream, 4, 512, 512, 1024,
        SQK, 2048, 1048576, SQK + 1024, 2048, 1048576, ASPEC, 512, 262144, 0.125f);
    softmax_k<float><<<2048, 256, 0, stream>>>(ASPEC, 512);
    conv_spec_k<<<dim3(8,8,4), 256, 0, stream>>>(ASPEC, ASPECCT, w_specw + l*9, w_specb + l);
    gmfma<2,2,float>(stream, 4, 1024, 512, 512,
        OUT, 512, 524288, ASPECCT, 512, 262144, X, 512, 524288, 1.f, 1);
    // --- conv FFN ---
    ln_k<<<4096, 256, 0, stream>>>(X, Hbuf, w_ln2w + l*512, w_ln2b + l*512);
    dwconv_k<<<4096, 256, 0, stream>>>(Hbuf, T1, w_dww + l*4608, w_dwb + l*512);
    gmfma<2,2,bf16>(stream, 4, 1024, 256, 512,
        T1, 512, 524288, w_pww + (long long)l*131072, 512, 0, T2, 256, 262144,
        1.f, 0, nullptr, BNAFF + l*512, BNAFF + l*512 + 256);
    gmfma<2,2,bf16>(stream, 4, 1024, 512, 256,
        T2, 256, 262144, w_c1w + (long long)l*131072, 256, 0, T3, 512, 524288,
        1.f, 0, w_c1b + l*512, nullptr, nullptr, nullptr, 1);
    // c2 with fused gelu + Hbuf add + X accumulate (add3 folded in)
    gmfma<2,2,float>(stream, 4, 1024, 512, 512,
        T3, 512, 524288, w_c2w + (long long)l*262144, 512, 0, X, 512, 524288,
        1.f, 1, w_c2b + l*512, nullptr, nullptr, Hbuf, 1);
  }

  store_out_k<<<8192, 256, 0, stream>>>(X, d_out, FLAG);
}

// Round 5
// 1291.000 us; speedup vs baseline: 20.1890x; 1.2563x over previous
//
#include <hip/hip_runtime.h>
#include <hip/hip_bf16.h>

typedef __hip_bfloat16 bf16;
typedef __attribute__((ext_vector_type(8))) short bf16x8;
typedef __attribute__((ext_vector_type(4))) float f32x4;

// ---------- helpers ----------
__device__ __forceinline__ float b2f(bf16 v){ return __bfloat162float(v); }
__device__ __forceinline__ bf16 f2b(float v){ return __float2bfloat16(v); }
__device__ __forceinline__ float bits2f(unsigned u){ return __uint_as_float(u << 16); }
__device__ __forceinline__ unsigned short f2bits(float v){ bf16 t = __float2bfloat16(v); return *(unsigned short*)&t; }

__device__ __forceinline__ float gelu_f(float x){
  return 0.5f * x * (1.f + erff(x * 0.7071067811865475f));
}

__device__ __forceinline__ void gload_lds(const void* g, void* l){
  __builtin_amdgcn_global_load_lds((const __attribute__((address_space(1))) void*)g,
                                   (__attribute__((address_space(3))) void*)l, 16, 0, 0);
}

template<bool MAX>
__device__ __forceinline__ float block_reduce(float v){
  __shared__ float s[4];
  #pragma unroll
  for (int o = 32; o > 0; o >>= 1){
    float t = __shfl_down(v, o, 64);
    v = MAX ? fmaxf(v, t) : (v + t);
  }
  int lane = threadIdx.x & 63, w = threadIdx.x >> 6;
  __syncthreads();
  if (lane == 0) s[w] = v;
  __syncthreads();
  return MAX ? fmaxf(fmaxf(s[0], s[1]), fmaxf(s[2], s[3]))
             : (s[0] + s[1] + s[2] + s[3]);
}

// ---------- dtype detect + converters ----------
__global__ void detect_k(const unsigned* __restrict__ x, int* __restrict__ flag){
  __shared__ int cnt[256];
  int tid = threadIdx.x;
  int c = 0;
  for (int i = tid; i < 4096; i += 256){
    unsigned h = x[i] & 0xffffu;
    int e = (int)((h >> 7) & 0xff);
    if (h == 0u || (e >= 100 && e <= 133)) c++;
  }
  cnt[tid] = c;
  __syncthreads();
  for (int o = 128; o > 0; o >>= 1){ if (tid < o) cnt[tid] += cnt[tid+o]; __syncthreads(); }
  if (tid == 0) *flag = (cnt[0] < 2048) ? 1 : 0;
}

__global__ __launch_bounds__(256) void cvt_x_k(const void* __restrict__ src,
                                               float* __restrict__ X,
                                               const int* __restrict__ flag){
  int p = blockIdx.x*256 + threadIdx.x;
  X[p] = (*flag) ? ((const float*)src)[p]
                 : __bfloat162float(((const bf16*)src)[p]);
}

struct WCvt21 { const void* src[21]; long long cum[22]; };

__global__ __launch_bounds__(256) void cvt_w_k(WCvt21 a, bf16* __restrict__ WB,
                                               long long total, const int* __restrict__ flag){
  long long i = (long long)blockIdx.x*256 + threadIdx.x;
  if (i >= total) return;
  int t = 0;
  while (a.cum[t+1] <= i) t++;
  long long e = i - a.cum[t];
  WB[i] = (*flag) ? __float2bfloat16(((const float*)a.src[t])[e])
                  : ((const bf16*)a.src[t])[e];
}

// transpose + convert weight: dst[z][c][r] = src[z][r][c], tiles 64x64
__global__ __launch_bounds__(256) void wtrans_k(const void* __restrict__ src, bf16* __restrict__ dst,
                                                int ld_src, int ldd, long long sSrc, long long sDst,
                                                const int* __restrict__ flag){
  __shared__ bf16 t[64][65];
  int z = blockIdx.z;
  int r0 = blockIdx.x*64, c0 = blockIdx.y*64;
  int lane = threadIdx.x & 63, quad = threadIdx.x >> 6;
  const float* sf = (const float*)src;
  const bf16* sb = (const bf16*)src;
  int fl = *flag;
  #pragma unroll
  for (int k = 0; k < 16; ++k){
    int r = quad*16 + k;
    long long idx = z*sSrc + (long long)(r0+r)*ld_src + c0 + lane;
    float v = fl ? sf[idx] : b2f(sb[idx]);
    t[r][lane] = f2b(v);
  }
  __syncthreads();
  #pragma unroll
  for (int k = 0; k < 16; ++k){
    int c = quad*16 + k;
    dst[z*sDst + (long long)(c0+c)*ldd + r0 + lane] = t[lane][c];
  }
}

// conv-attn weight shuffle: Wr[l][16][96]; Wr[l][ho][tap*8+hi] = spw[l][ho][hi][tap], 0-padded
__global__ void wprep_k(const bf16* __restrict__ spw, bf16* __restrict__ Wr){
  int l = blockIdx.x;
  for (int t = threadIdx.x; t < 1536; t += 256){
    int ho = t / 96, k = t - ho*96;
    float v = 0.f;
    if (ho < 8 && k < 72){
      int tap = k >> 3, hi = k & 7;
      v = b2f(spw[l*576 + ho*72 + hi*9 + tap]);
    }
    Wr[l*1536 + t] = f2b(v);
  }
}

__global__ __launch_bounds__(256) void store_out_k(const float* __restrict__ X,
                                                   void* __restrict__ out,
                                                   const int* __restrict__ flag){
  int p = blockIdx.x*256 + threadIdx.x;
  if (*flag) ((float*)out)[p] = X[p];
  else       ((bf16*)out)[p] = f2b(X[p]);
}

// ---------- MFMA GEMM ----------
// C[z] = epi( alpha * A(MxK,row) x Bt(NxK,row)^T ); z decomposes as (z&7, z>>3)
template<int MF, int NF, typename TC>
__global__ __launch_bounds__(256) void gmfma_k(
    int M, int N, int K,
    const bf16* __restrict__ A, int lda, long long sA, long long sA2,
    const bf16* __restrict__ Bt, int ldb, long long sB, long long sB2,
    TC* __restrict__ C, int ldc, long long sC, long long sC2,
    float alpha, int beta,
    const bf16* __restrict__ bias_n,
    const float* __restrict__ scale_n,
    const float* __restrict__ shift_n,
    const bf16* __restrict__ addF,
    int act)
{
  constexpr int BM = MF*32, BN = NF*32;
  constexpr int CHA = BM/16, CH = (BM+BN)/16;
  static_assert(CH % 4 == 0, "chunks must divide among 4 waves");
  __shared__ bf16 Asm[BM][32];
  __shared__ bf16 Bsm[BN][32];
  const int tid = threadIdx.x;
  const int lane = tid & 63, wid = tid >> 6;
  const int wm = wid >> 1, wn = wid & 1;
  const int m0 = blockIdx.y*BM, n0 = blockIdx.x*BN;
  const int z = blockIdx.z;
  const long long zl = z & 7, zh = z >> 3;
  const bf16* Ab = A + zl*sA + zh*sA2;
  const bf16* Bb = Bt + zl*sB + zh*sB2;
  TC* Cb = C + zl*sC + zh*sC2;
  const bf16* Fb = addF ? addF + zl*sC + zh*sC2 : nullptr;

  f32x4 acc[MF][NF];
  f32x4 zero = {0.f, 0.f, 0.f, 0.f};
  #pragma unroll
  for (int m = 0; m < MF; ++m)
    #pragma unroll
    for (int n = 0; n < NF; ++n) acc[m][n] = zero;

  const int rchunk = lane >> 2;
  const int kchunk = (lane & 3) * 8;
  const int row16 = lane & 15, kq = (lane >> 4) * 8;

  for (int k0 = 0; k0 < K; k0 += 32){
    #pragma unroll
    for (int cc = 0; cc < CH/4; ++cc){
      int c = wid + cc*4;
      if (c < CHA){
        int row = c*16 + rchunk;
        gload_lds(Ab + (long long)(m0+row)*lda + k0 + kchunk, &Asm[c*16][0]);
      } else {
        int row = (c-CHA)*16 + rchunk;
        gload_lds(Bb + (long long)(n0+row)*ldb + k0 + kchunk, &Bsm[(c-CHA)*16][0]);
      }
    }
    __syncthreads();
    bf16x8 af[MF], bfr[NF];
    #pragma unroll
    for (int m = 0; m < MF; ++m)
      af[m] = *(const bf16x8*)&Asm[wm*(MF*16) + m*16 + row16][kq];
    #pragma unroll
    for (int n = 0; n < NF; ++n)
      bfr[n] = *(const bf16x8*)&Bsm[wn*(NF*16) + n*16 + row16][kq];
    #pragma unroll
    for (int m = 0; m < MF; ++m)
      #pragma unroll
      for (int n = 0; n < NF; ++n)
        acc[m][n] = __builtin_amdgcn_mfma_f32_16x16x32_bf16(af[m], bfr[n], acc[m][n], 0, 0, 0);
    __syncthreads();
  }

  #pragma unroll
  for (int m = 0; m < MF; ++m){
    #pragma unroll
    for (int n = 0; n < NF; ++n){
      int gn = n0 + wn*(NF*16) + n*16 + (lane & 15);
      float bn_ = bias_n ? b2f(bias_n[gn]) : 0.f;
      float sc = scale_n ? scale_n[gn] : 1.f;
      float sh = shift_n ? shift_n[gn] : 0.f;
      #pragma unroll
      for (int r = 0; r < 4; ++r){
        int gm = m0 + wm*(MF*16) + m*16 + (lane >> 4)*4 + r;
        float v = acc[m][n][r] * alpha + bn_;
        v = v * sc + sh;
        if (act) v = gelu_f(v);
        long long idx = (long long)gm*ldc + gn;
        if (Fb) v += b2f(Fb[idx]);
        if (beta){
          float old;
          if constexpr (__is_same(TC, float)) old = Cb[idx]; else old = b2f(Cb[idx]);
          v += old;
        }
        if constexpr (__is_same(TC, float)) Cb[idx] = v; else Cb[idx] = f2b(v);
      }
    }
  }
}

template<int MF, int NF, typename TC>
static void gmfma_x(hipStream_t st, int z, int M, int N, int K,
                    const bf16* A, int lda, long long sA, long long sA2,
                    const bf16* Bt, int ldb, long long sB, long long sB2,
                    TC* C, int ldc, long long sC, long long sC2,
                    float alpha = 1.f, int beta = 0,
                    const bf16* bias_n = nullptr,
                    const float* scale_n = nullptr, const float* shift_n = nullptr,
                    const bf16* addF = nullptr, int act = 0)
{
  dim3 g(N/(NF*32), M/(MF*32), z);
  gmfma_k<MF,NF,TC><<<g, 256, 0, st>>>(M,N,K,A,lda,sA,sA2,Bt,ldb,sB,sB2,C,ldc,sC,sC2,
                                       alpha,beta,bias_n,scale_n,shift_n,addF,act);
}

template<int MF, int NF, typename TC>
static void gmfma(hipStream_t st, int z, int M, int N, int K,
                  const bf16* A, int lda, long long sA,
                  const bf16* Bt, int ldb, long long sB,
                  TC* C, int ldc, long long sC,
                  float alpha = 1.f, int beta = 0,
                  const bf16* bias_n = nullptr,
                  const float* scale_n = nullptr, const float* shift_n = nullptr,
                  const bf16* addF = nullptr, int act = 0)
{
  gmfma_x<MF,NF,TC>(st, z, M, N, K, A, lda, sA, 8*sA, Bt, ldb, sB, 8*sB,
                    C, ldc, sC, 8*sC, alpha, beta, bias_n, scale_n, shift_n, addF, act);
}

// ---------- LayerNorm fp32 -> bf16 ----------
__global__ __launch_bounds__(256) void ln_k(const float* __restrict__ X, bf16* __restrict__ Y,
                                            const bf16* __restrict__ w, const bf16* __restrict__ b){
  long long row = blockIdx.x;
  const float* x = X + row*512;
  bf16* y = Y + row*512;
  int tid = threadIdx.x;
  float v0 = x[tid], v1 = x[tid+256];
  float mean = block_reduce<false>(v0+v1) * (1.f/512.f);
  float msq  = block_reduce<false>(v0*v0+v1*v1) * (1.f/512.f);
  float var = msq - mean*mean;
  float rs = rsqrtf(var + 1e-5f);
  y[tid]     = f2b((v0-mean)*rs*b2f(w[tid])     + b2f(b[tid]));
  y[tid+256] = f2b((v1-mean)*rs*b2f(w[tid+256]) + b2f(b[tid+256]));
}

// ---------- softmax (float, spectral) ----------
__device__ __forceinline__ float ldf(const float* p){ return *p; }
__device__ __forceinline__ void stf(float* p, float v){ *p = v; }

__global__ __launch_bounds__(256) void softmax_k(float* __restrict__ data, int cols){
  long long row = blockIdx.x;
  float* p = data + row * (long long)cols;
  int tid = threadIdx.x;
  int per = cols >> 8;
  float v[4];
  float mx = -3.4e38f;
  for (int r = 0; r < per; ++r){ v[r] = p[tid + (r<<8)]; mx = fmaxf(mx, v[r]); }
  mx = block_reduce<true>(mx);
  float sum = 0.f;
  for (int r = 0; r < per; ++r){ v[r] = expf(v[r] - mx); sum += v[r]; }
  sum = block_reduce<false>(sum);
  float inv = 1.f / sum;
  for (int r = 0; r < per; ++r) p[tid + (r<<8)] = v[r] * inv;
}

// ---------- fused softmax + planar->interleaved transpose for attn maps ----------
// in : Sp[b][h][i][j] planar (raw scores, pre-softmax, already scaled)
// out: Sx[b][i][j][h] interleaved, softmaxed. grid (1024 rows, NB); block 256.
__global__ __launch_bounds__(256) void smT_k(const bf16* __restrict__ Sp, bf16* __restrict__ Sx,
                                             long long bstride){
  __shared__ unsigned short sm[8][1032];
  __shared__ float redmx[4][8];
  __shared__ float redsum[4][8];
  int i = blockIdx.x;
  long long b = blockIdx.y;
  const bf16* src = Sp + b*bstride + (long long)i*1024;
  bf16* dst = Sx + b*bstride + (long long)i*8192;
  int tid = threadIdx.x;
  int lane = tid & 63, w = tid >> 6;
  int j0 = tid*4;

  float v[8][4];
  #pragma unroll
  for (int h = 0; h < 8; ++h){
    ushort4 u = *(const ushort4*)&src[h*1048576 + j0];
    v[h][0] = bits2f(u.x); v[h][1] = bits2f(u.y);
    v[h][2] = bits2f(u.z); v[h][3] = bits2f(u.w);
  }
  // per-h max
  float mx[8];
  #pragma unroll
  for (int h = 0; h < 8; ++h){
    float m = fmaxf(fmaxf(v[h][0], v[h][1]), fmaxf(v[h][2], v[h][3]));
    #pragma unroll
    for (int o = 32; o > 0; o >>= 1) m = fmaxf(m, __shfl_xor(m, o, 64));
    if (lane == 0) redmx[w][h] = m;
    mx[h] = m;
  }
  __syncthreads();
  #pragma unroll
  for (int h = 0; h < 8; ++h)
    mx[h] = fmaxf(fmaxf(redmx[0][h], redmx[1][h]), fmaxf(redmx[2][h], redmx[3][h]));
  // exp + per-h sum
  float inv[8];
  #pragma unroll
  for (int h = 0; h < 8; ++h){
    float s = 0.f;
    #pragma unroll
    for (int r = 0; r < 4; ++r){ v[h][r] = expf(v[h][r] - mx[h]); s += v[h][r]; }
    #pragma unroll
    for (int o = 32; o > 0; o >>= 1) s += __shfl_xor(s, o, 64);
    if (lane == 0) redsum[w][h] = s;
  }
  __syncthreads();
  #pragma unroll
  for (int h = 0; h < 8; ++h)
    inv[h] = 1.f / (redsum[0][h] + redsum[1][h] + redsum[2][h] + redsum[3][h]);
  // normalize -> LDS
  #pragma unroll
  for (int h = 0; h < 8; ++h)
    #pragma unroll
    for (int r = 0; r < 4; ++r)
      sm[h][j0 + r] = f2bits(v[h][r] * inv[h]);
  __syncthreads();
  // interleaved write-out: 4 x 16B per thread, contiguous 64B
  #pragma unroll
  for (int r = 0; r < 4; ++r){
    int j = j0 + r;
    bf16x8 o;
    #pragma unroll
    for (int h = 0; h < 8; ++h) o[h] = (short)sm[h][j];
    *(bf16x8*)&dst[(long long)j*8] = o;
  }
}

// ---------- MFMA 3x3 conv on attn maps: Sx[b][i][j][8] -> Pout[b][h][i][j] ----------
// grid (16 j-tiles, 256 i-tiles, NB); block 256 = 4 waves, wave = 1 row x 64 j.
__global__ __launch_bounds__(256) void convmf_k(const bf16* __restrict__ Sx, bf16* __restrict__ Pout,
                                                const bf16* __restrict__ Wr, const bf16* __restrict__ bias,
                                                long long bstride){
  __shared__ bf16 tile[6][66][8];
  long long b = blockIdx.z;
  int i0 = blockIdx.y*4, j0 = blockIdx.x*64;
  int tid = threadIdx.x;
  const bf16* src = Sx + b*bstride;
  for (int t = tid; t < 396; t += 256){
    int row = t / 66, col = t - row*66;
    int gi = i0 + row - 1, gj = j0 + col - 1;
    bf16x8 val = {};
    if ((unsigned)gi < 1024u && (unsigned)gj < 1024u)
      val = *(const bf16x8*)&src[(long long)gi*8192 + gj*8];
    *(bf16x8*)&tile[row][col][0] = val;
  }
  int lane = tid & 63, wid = tid >> 6;
  int row16 = lane & 15, q = lane >> 4;
  bf16x8 bf0 = *(const bf16x8*)&Wr[row16*96 +  0 + q*8];
  bf16x8 bf1 = *(const bf16x8*)&Wr[row16*96 + 32 + q*8];
  bf16x8 bf2 = *(const bf16x8*)&Wr[row16*96 + 64 + q*8];
  __syncthreads();

  int ii = wid;
  f32x4 zero = {0.f,0.f,0.f,0.f};
  f32x4 acc[4] = {zero, zero, zero, zero};
  #pragma unroll
  for (int ks = 0; ks < 3; ++ks){
    int tap = ks*4 + q;                 // k-group tap index (0..11)
    int tcl = tap > 8 ? 0 : tap;        // invalid taps -> B rows are zero anyway
    int di = tcl / 3, dj = tcl - di*3;
    bf16x8 bsel = ks == 0 ? bf0 : (ks == 1 ? bf1 : bf2);
    #pragma unroll
    for (int mf = 0; mf < 4; ++mf){
      bf16x8 af = *(const bf16x8*)&tile[ii + di][mf*16 + row16 + dj][0];
      acc[mf] = __builtin_amdgcn_mfma_f32_16x16x32_bf16(af, bsel, acc[mf], 0, 0, 0);
    }
  }
  if (row16 < 8){
    float bv = b2f(bias[row16]);
    bf16* dst = Pout + b*bstride + (long long)row16*1048576 + (long long)(i0 + ii)*1024;
    #pragma unroll
    for (int mf = 0; mf < 4; ++mf){
      int j = j0 + mf*16 + q*4;
      ushort4 o;
      o.x = f2bits(acc[mf][0] + bv);
      o.y = f2bits(acc[mf][1] + bv);
      o.z = f2bits(acc[mf][2] + bv);
      o.w = f2bits(acc[mf][3] + bv);
      *(ushort4*)&dst[j] = o;
    }
  }
}

// ---------- 3x3 conv, 1 ch, (B,512,512) fp32 in -> bf16 TRANSPOSED out ----------
__global__ __launch_bounds__(256) void conv_spec_k(const float* __restrict__ in, bf16* __restrict__ out,
                                                   const bf16* __restrict__ w, const bf16* __restrict__ bias){
  __shared__ float ti[66][67];
  __shared__ bf16 toutT[64][65];
  int b = blockIdx.z;
  int i0 = blockIdx.y*64, j0 = blockIdx.x*64;
  int tid = threadIdx.x;
  const float* ib = in + (long long)b*262144;
  for (int t = tid; t < 66*66; t += 256){
    int r = t / 66, c = t - r*66;
    int gi = i0 + r - 1, gj = j0 + c - 1;
    float v = 0.f;
    if ((unsigned)gi < 512u && (unsigned)gj < 512u) v = ib[gi*512 + gj];
    ti[r][c] = v;
  }
  __syncthreads();
  float w9[9], bv = b2f(bias[0]);
  #pragma unroll
  for (int d = 0; d < 9; ++d) w9[d] = b2f(w[d]);
  int ii = tid & 63;
  #pragma unroll
  for (int q = 0; q < 16; ++q){
    int jj = (tid >> 6)*16 + q;
    float acc = bv;
    #pragma unroll
    for (int di = 0; di < 3; ++di)
      #pragma unroll
      for (int dj = 0; dj < 3; ++dj)
        acc += w9[di*3+dj] * ti[ii+di][jj+dj];
    toutT[jj][ii] = f2b(acc);
  }
  __syncthreads();
  #pragma unroll
  for (int q = 0; q < 16; ++q){
    int jj = (tid >> 6)*16 + q;
    out[(long long)b*262144 + (j0+jj)*512 + i0 + (tid & 63)] = toutT[jj][tid & 63];
  }
}

// ---------- depthwise 3x3; Hbuf (b,n,c) bf16 -> T1 (b,n,c) bf16 ----------
__global__ __launch_bounds__(256) void dwconv_k(const bf16* __restrict__ H2, bf16* __restrict__ T1,
                                                const bf16* __restrict__ w, const bf16* __restrict__ bias){
  int p = blockIdx.x*256 + threadIdx.x;
  int cp = p & 255;
  int n = (p >> 8) & 1023;
  int b = p >> 18;
  int c0 = cp*2;
  int wi = n >> 5, hg = n & 31;
  float a0 = b2f(bias[c0]), a1 = b2f(bias[c0+1]);
  #pragma unroll
  for (int di = 0; di < 3; ++di){
    int gw = wi + di - 1;
    if ((unsigned)gw >= 32u) continue;
    #pragma unroll
    for (int dj = 0; dj < 3; ++dj){
      int gh = hg + dj - 1;
      if ((unsigned)gh >= 32u) continue;
      unsigned hv = *(const unsigned*)&H2[((long long)b*1024 + (gw*32+gh))*512 + c0];
      float w0 = b2f(w[c0*9 + di*3 + dj]);
      float w1 = b2f(w[(c0+1)*9 + di*3 + dj]);
      a0 += w0 * bits2f(hv & 0xffffu);
      a1 += w1 * bits2f(hv >> 16);
    }
  }
  bf16 h0 = f2b(a0), h1 = f2b(a1);
  unsigned o = ((unsigned)*(unsigned short*)&h1 << 16) | (unsigned)*(unsigned short*)&h0;
  *(unsigned*)&T1[((long long)b*1024 + n)*512 + c0] = o;
}

// ---------- fold pw bias + BN(eval), all layers ----------
__global__ void bnaff_all_k(const bf16* __restrict__ pwb, const bf16* __restrict__ g,
                            const bf16* __restrict__ bb, const bf16* __restrict__ m,
                            const bf16* __restrict__ v, float* __restrict__ BNAFF){
  int l = blockIdx.x, o = threadIdx.x;
  float s = b2f(g[l*256+o]) * rsqrtf(b2f(v[l*256+o]) + 1e-5f);
  BNAFF[l*512 + o] = s;
  BNAFF[l*512 + 256 + o] = (b2f(pwb[l*256+o]) - b2f(m[l*256+o])) * s + b2f(bb[l*256+o]);
}

// ---------- Vt[b*8+h][d][n] = QKV[b][n][1024 + h*64 + d] ----------
__global__ __launch_bounds__(256) void vtrans_k(const bf16* __restrict__ QKV, bf16* __restrict__ Vt){
  __shared__ bf16 t[64][65];
  int z = blockIdx.z; int b = z >> 3, h = z & 7;
  const bf16* src = QKV + (long long)b*1572864 + 1024 + h*64;
  bf16* dst = Vt + (long long)z*65536;
  int n0 = blockIdx.x*64;
  int lane = threadIdx.x & 63, quad = threadIdx.x >> 6;
  #pragma unroll
  for (int k = 0; k < 16; ++k){
    int r = quad*16 + k;
    t[r][lane] = src[(long long)(n0+r)*1536 + lane];
  }
  __syncthreads();
  #pragma unroll
  for (int k = 0; k < 16; ++k){
    int d = quad*16 + k;
    dst[(long long)d*1024 + n0 + lane] = t[lane][d];
  }
}

// ---------- HbufT[b][c][n] = Hbuf[b][n][c] ----------
__global__ __launch_bounds__(256) void htrans_k(const bf16* __restrict__ Hb, bf16* __restrict__ HT){
  __shared__ bf16 t[64][65];
  int b = blockIdx.z;
  int n0 = blockIdx.x*64, c0 = blockIdx.y*64;
  int lane = threadIdx.x & 63, quad = threadIdx.x >> 6;
  #pragma unroll
  for (int k = 0; k < 16; ++k){
    int r = quad*16 + k;
    t[r][lane] = Hb[((long long)b*1024 + n0 + r)*512 + c0 + lane];
  }
  __syncthreads();
  #pragma unroll
  for (int k = 0; k < 16; ++k){
    int c = quad*16 + k;
    HT[(long long)b*524288 + (long long)(c0+c)*1024 + n0 + lane] = t[lane][c];
  }
}

// ---------- orchestration ----------
extern "C" void kernel_launch(void* const* d_in, const int* in_sizes, int n_in,
                              void* d_out, int out_size, void* d_ws, size_t ws_size,
                              hipStream_t stream)
{
  (void)in_sizes; (void)n_in; (void)out_size;

  const bool big = ws_size >= 206000000ull;
  const long long ATTN_SZ = big ? 33554432LL : 8388608LL;

  // ---- arena ----
  float* X     = (float*)d_ws;                    // 2,097,152 f32
  bf16*  WBsm  = (bf16*)(X + 2097152);            // 2,139,648
  bf16*  WqkvT = WBsm  + 2139648;                 // 3,145,728
  bf16*  WoutT = WqkvT + 3145728;                 // 1,048,576
  bf16*  WqsT  = WoutT + 1048576;                 // 8,388,608
  bf16*  Hbuf  = WqsT  + 8388608;                 // 2,097,152
  bf16*  HbufT = Hbuf  + 2097152;                 // 2,097,152
  bf16*  QKV   = HbufT + 2097152;                 // 6,291,456
  bf16*  Vt    = QKV   + 6291456;                 // 2,097,152
  bf16*  OUTH  = Vt    + 2097152;                 // 2,097,152  (alias ASPEC f32)
  bf16*  OUT   = OUTH  + 2097152;                 // 2,097,152
  bf16*  ATTN  = OUT   + 2097152;                 // ATTN_SZ    (alias SQK, T1, T3)
  bf16*  ATTNC = ATTN  + ATTN_SZ;                 // ATTN_SZ    (alias ASPECC_T, T2)
  float* BNAFF = (float*)(ATTNC + ATTN_SZ);       // 2048 f32
  bf16*  WR    = (bf16*)(BNAFF + 2048);           // 6144 bf16 (conv-attn weights)
  int*   FLAG  = (int*)(WR + 6144);

  float* ASPEC   = (float*)OUTH;
  bf16*  ASPECCT = ATTNC;
  bf16*  T1 = ATTN;
  bf16*  T3 = ATTN + 2097152;
  bf16*  T2 = ATTNC + 2097152;
  bf16*  SQK = ATTN;

  // ---- small-weight arena ----
  static const int widx[21] = {1,2,5,6,7,9,10,11,12,13,14,15,16,17,18,19,20,21,22,23,24};
  static const long long wsz[21] = {2048,2048,2048,2304,32,36,4,2048,2048,18432,2048,
                                    524288,1024,1024,1024,1024,1024,524288,2048,1048576,2048};
  WCvt21 wc;
  long long cum = 0;
  bf16* wp[21];
  for (int t = 0; t < 21; ++t){
    wc.src[t] = d_in[widx[t]];
    wc.cum[t] = cum;
    wp[t] = WBsm + cum;
    cum += wsz[t];
  }
  wc.cum[21] = cum;

  bf16 *w_ln1w = wp[0],  *w_ln1b = wp[1],  *w_bout = wp[2],  *w_spw = wp[3];
  bf16 *w_spb  = wp[4],  *w_specw= wp[5],  *w_specb= wp[6],  *w_ln2w= wp[7];
  bf16 *w_ln2b = wp[8],  *w_dww  = wp[9],  *w_dwb  = wp[10], *w_pww = wp[11];
  bf16 *w_pwb  = wp[12], *w_bng  = wp[13], *w_bnb  = wp[14], *w_bnm = wp[15];
  bf16 *w_bnv  = wp[16], *w_c1w  = wp[17], *w_c1b  = wp[18], *w_c2w = wp[19];
  bf16 *w_c2b  = wp[20];

  // ---- setup ----
  detect_k<<<1, 256, 0, stream>>>((const unsigned*)d_in[0], FLAG);
  cvt_x_k<<<8192, 256, 0, stream>>>(d_in[0], X, FLAG);
  cvt_w_k<<<(int)((cum + 255)/256), 256, 0, stream>>>(wc, WBsm, cum, FLAG);
  wtrans_k<<<dim3(8,24,4), 256, 0, stream>>>(d_in[3], WqkvT, 1536, 512, 786432LL, 786432LL, FLAG);
  wtrans_k<<<dim3(8, 8,4), 256, 0, stream>>>(d_in[4], WoutT,  512, 512, 262144LL, 262144LL, FLAG);
  wtrans_k<<<dim3(16,32,4),256, 0, stream>>>(d_in[8], WqsT,  3072,1024, 3145728LL,2097152LL, FLAG);
  bnaff_all_k<<<4, 256, 0, stream>>>(w_pwb, w_bng, w_bnb, w_bnm, w_bnv, BNAFF);
  wprep_k<<<4, 256, 0, stream>>>(w_spw, WR);

  for (int l = 0; l < 4; ++l){
    // --- spatial attention ---
    ln_k<<<4096, 256, 0, stream>>>(X, Hbuf, w_ln1w + l*512, w_ln1b + l*512);
    gmfma<4,4,bf16>(stream, 1, 4096, 1536, 512,
        Hbuf, 512, 0, WqkvT + (long long)l*786432, 512, 0, QKV, 1536, 0);
    vtrans_k<<<dim3(16,1,32), 256, 0, stream>>>(QKV, Vt);
    if (big){
      gmfma_x<4,4,bf16>(stream, 32, 1024, 1024, 64,
          QKV, 1536, 64, 1572864, QKV + 512, 1536, 64, 1572864,
          ATTN, 1024, 1048576, 8388608, 0.125f);
      smT_k<<<dim3(1024,4), 256, 0, stream>>>(ATTN, ATTNC, 8388608LL);
      convmf_k<<<dim3(16,256,4), 256, 0, stream>>>(ATTNC, ATTN, WR + l*1536, w_spb + l*8, 8388608LL);
      gmfma_x<2,2,bf16>(stream, 32, 1024, 64, 1024,
          ATTN, 1024, 1048576, 8388608, Vt, 1024, 65536, 524288,
          OUTH, 512, 64, 524288);
    } else {
      for (int b = 0; b < 4; ++b){
        bf16* qkvb = QKV + (long long)b*1572864;
        gmfma<4,4,bf16>(stream, 8, 1024, 1024, 64,
            qkvb, 1536, 64, qkvb + 512, 1536, 64, ATTN, 1024, 1048576, 0.125f);
        smT_k<<<dim3(1024,1), 256, 0, stream>>>(ATTN, ATTNC, 8388608LL);
        convmf_k<<<dim3(16,256,1), 256, 0, stream>>>(ATTNC, ATTN, WR + l*1536, w_spb + l*8, 8388608LL);
        gmfma<2,2,bf16>(stream, 8, 1024, 64, 1024,
            ATTN, 1024, 1048576, Vt + (long long)b*524288, 1024, 65536,
            OUTH + (long long)b*524288, 512, 64);
      }
    }
    gmfma<2,2,bf16>(stream, 1, 4096, 512, 512,
        OUTH, 512, 0, WoutT + (long long)l*262144, 512, 0, OUT, 512, 0,
        1.f, 0, w_bout + l*512);
    // --- spectral attention ---
    htrans_k<<<dim3(16,8,4), 256, 0, stream>>>(Hbuf, HbufT);
    gmfma<4,4,bf16>(stream, 4, 512, 2048, 1024,
        HbufT, 1024, 524288, WqsT + (long long)l*2097152, 1024, 0, SQK, 2048, 1048576);
    gmfma<2,2,float>(stream, 4, 512, 512, 1024,
        SQK, 2048, 1048576, SQK + 1024, 2048, 1048576, ASPEC, 512, 262144, 0.125f);
    softmax_k<<<2048, 256, 0, stream>>>(ASPEC, 512);
    conv_spec_k<<<dim3(8,8,4), 256, 0, stream>>>(ASPEC, ASPECCT, w_specw + l*9, w_specb + l);
    gmfma<2,2,float>(stream, 4, 1024, 512, 512,
        OUT, 512, 524288, ASPECCT, 512, 262144, X, 512, 524288, 1.f, 1);
    // --- conv FFN ---
    ln_k<<<4096, 256, 0, stream>>>(X, Hbuf, w_ln2w + l*512, w_ln2b + l*512);
    dwconv_k<<<4096, 256, 0, stream>>>(Hbuf, T1, w_dww + l*4608, w_dwb + l*512);
    gmfma<2,2,bf16>(stream, 4, 1024, 256, 512,
        T1, 512, 524288, w_pww + (long long)l*131072, 512, 0, T2, 256, 262144,
        1.f, 0, nullptr, BNAFF + l*512, BNAFF + l*512 + 256);
    gmfma<2,2,bf16>(stream, 4, 1024, 512, 256,
        T2, 256, 262144, w_c1w + (long long)l*131072, 256, 0, T3, 512, 524288,
        1.f, 0, w_c1b + l*512, nullptr, nullptr, nullptr, 1);
    gmfma<2,2,float>(stream, 4, 1024, 512, 512,
        T3, 512, 524288, w_c2w + (long long)l*262144, 512, 0, X, 512, 524288,
        1.f, 1, w_c2b + l*512, nullptr, nullptr, Hbuf, 1);
  }

  store_out_k<<<8192, 256, 0, stream>>>(X, d_out, FLAG);
}

// Round 6
// 1282.727 us; speedup vs baseline: 20.3192x; 1.0064x over previous
//
#include <hip/hip_runtime.h>
#include <hip/hip_bf16.h>

typedef __hip_bfloat16 bf16;
typedef __attribute__((ext_vector_type(8))) short bf16x8;
typedef __attribute__((ext_vector_type(4))) float f32x4;

// ---------- helpers ----------
__device__ __forceinline__ float b2f(bf16 v){ return __bfloat162float(v); }
__device__ __forceinline__ bf16 f2b(float v){ return __float2bfloat16(v); }
__device__ __forceinline__ float bits2f(unsigned u){ return __uint_as_float(u << 16); }
__device__ __forceinline__ unsigned short f2bits(float v){ bf16 t = __float2bfloat16(v); return *(unsigned short*)&t; }

__device__ __forceinline__ float gelu_f(float x){
  return 0.5f * x * (1.f + erff(x * 0.7071067811865475f));
}

__device__ __forceinline__ void gload_lds(const void* g, void* l){
  __builtin_amdgcn_global_load_lds((const __attribute__((address_space(1))) void*)g,
                                   (__attribute__((address_space(3))) void*)l, 16, 0, 0);
}

template<bool MAX>
__device__ __forceinline__ float block_reduce(float v){
  __shared__ float s[4];
  #pragma unroll
  for (int o = 32; o > 0; o >>= 1){
    float t = __shfl_down(v, o, 64);
    v = MAX ? fmaxf(v, t) : (v + t);
  }
  int lane = threadIdx.x & 63, w = threadIdx.x >> 6;
  __syncthreads();
  if (lane == 0) s[w] = v;
  __syncthreads();
  return MAX ? fmaxf(fmaxf(s[0], s[1]), fmaxf(s[2], s[3]))
             : (s[0] + s[1] + s[2] + s[3]);
}

// ---------- dtype detect + converters ----------
__global__ void detect_k(const unsigned* __restrict__ x, int* __restrict__ flag){
  __shared__ int cnt[256];
  int tid = threadIdx.x;
  int c = 0;
  for (int i = tid; i < 4096; i += 256){
    unsigned h = x[i] & 0xffffu;
    int e = (int)((h >> 7) & 0xff);
    if (h == 0u || (e >= 100 && e <= 133)) c++;
  }
  cnt[tid] = c;
  __syncthreads();
  for (int o = 128; o > 0; o >>= 1){ if (tid < o) cnt[tid] += cnt[tid+o]; __syncthreads(); }
  if (tid == 0) *flag = (cnt[0] < 2048) ? 1 : 0;
}

__global__ __launch_bounds__(256) void cvt_x_k(const void* __restrict__ src,
                                               float* __restrict__ X,
                                               const int* __restrict__ flag){
  int p = blockIdx.x*256 + threadIdx.x;
  X[p] = (*flag) ? ((const float*)src)[p]
                 : __bfloat162float(((const bf16*)src)[p]);
}

struct WCvt21 { const void* src[21]; long long cum[22]; };

__global__ __launch_bounds__(256) void cvt_w_k(WCvt21 a, bf16* __restrict__ WB,
                                               long long total, const int* __restrict__ flag){
  long long i = (long long)blockIdx.x*256 + threadIdx.x;
  if (i >= total) return;
  int t = 0;
  while (a.cum[t+1] <= i) t++;
  long long e = i - a.cum[t];
  WB[i] = (*flag) ? __float2bfloat16(((const float*)a.src[t])[e])
                  : ((const bf16*)a.src[t])[e];
}

// transpose + convert weight: dst[z][c][r] = src[z][r][c], tiles 64x64
__global__ __launch_bounds__(256) void wtrans_k(const void* __restrict__ src, bf16* __restrict__ dst,
                                                int ld_src, int ldd, long long sSrc, long long sDst,
                                                const int* __restrict__ flag){
  __shared__ bf16 t[64][65];
  int z = blockIdx.z;
  int r0 = blockIdx.x*64, c0 = blockIdx.y*64;
  int lane = threadIdx.x & 63, quad = threadIdx.x >> 6;
  const float* sf = (const float*)src;
  const bf16* sb = (const bf16*)src;
  int fl = *flag;
  #pragma unroll
  for (int k = 0; k < 16; ++k){
    int r = quad*16 + k;
    long long idx = z*sSrc + (long long)(r0+r)*ld_src + c0 + lane;
    float v = fl ? sf[idx] : b2f(sb[idx]);
    t[r][lane] = f2b(v);
  }
  __syncthreads();
  #pragma unroll
  for (int k = 0; k < 16; ++k){
    int c = quad*16 + k;
    dst[z*sDst + (long long)(c0+c)*ldd + r0 + lane] = t[lane][c];
  }
}

// conv-attn weight shuffle: Wr[l][16][96]; Wr[l][ho][tap*8+hi] = spw[l][ho][hi][tap], 0-padded
__global__ void wprep_k(const bf16* __restrict__ spw, bf16* __restrict__ Wr){
  int l = blockIdx.x;
  for (int t = threadIdx.x; t < 1536; t += 256){
    int ho = t / 96, k = t - ho*96;
    float v = 0.f;
    if (ho < 8 && k < 72){
      int tap = k >> 3, hi = k & 7;
      v = b2f(spw[l*576 + ho*72 + hi*9 + tap]);
    }
    Wr[l*1536 + t] = f2b(v);
  }
}

__global__ __launch_bounds__(256) void store_out_k(const float* __restrict__ X,
                                                   void* __restrict__ out,
                                                   const int* __restrict__ flag){
  int p = blockIdx.x*256 + threadIdx.x;
  if (*flag) ((float*)out)[p] = X[p];
  else       ((bf16*)out)[p] = f2b(X[p]);
}

// ---------- MFMA GEMM ----------
// C[z] = epi( alpha * A(MxK,row) x Bt(NxK,row)^T ); z decomposes as (z&7, z>>3)
template<int MF, int NF, typename TC>
__global__ __launch_bounds__(256) void gmfma_k(
    int M, int N, int K,
    const bf16* __restrict__ A, int lda, long long sA, long long sA2,
    const bf16* __restrict__ Bt, int ldb, long long sB, long long sB2,
    TC* __restrict__ C, int ldc, long long sC, long long sC2,
    float alpha, int beta,
    const bf16* __restrict__ bias_n,
    const float* __restrict__ scale_n,
    const float* __restrict__ shift_n,
    const bf16* __restrict__ addF,
    int act)
{
  constexpr int BM = MF*32, BN = NF*32;
  constexpr int CHA = BM/16, CH = (BM+BN)/16;
  static_assert(CH % 4 == 0, "chunks must divide among 4 waves");
  __shared__ bf16 Asm[BM][32];
  __shared__ bf16 Bsm[BN][32];
  const int tid = threadIdx.x;
  const int lane = tid & 63, wid = tid >> 6;
  const int wm = wid >> 1, wn = wid & 1;
  const int m0 = blockIdx.y*BM, n0 = blockIdx.x*BN;
  const int z = blockIdx.z;
  const long long zl = z & 7, zh = z >> 3;
  const bf16* Ab = A + zl*sA + zh*sA2;
  const bf16* Bb = Bt + zl*sB + zh*sB2;
  TC* Cb = C + zl*sC + zh*sC2;
  const bf16* Fb = addF ? addF + zl*sC + zh*sC2 : nullptr;

  f32x4 acc[MF][NF];
  f32x4 zero = {0.f, 0.f, 0.f, 0.f};
  #pragma unroll
  for (int m = 0; m < MF; ++m)
    #pragma unroll
    for (int n = 0; n < NF; ++n) acc[m][n] = zero;

  const int rchunk = lane >> 2;
  const int kchunk = (lane & 3) * 8;
  const int row16 = lane & 15, kq = (lane >> 4) * 8;

  for (int k0 = 0; k0 < K; k0 += 32){
    #pragma unroll
    for (int cc = 0; cc < CH/4; ++cc){
      int c = wid + cc*4;
      if (c < CHA){
        int row = c*16 + rchunk;
        gload_lds(Ab + (long long)(m0+row)*lda + k0 + kchunk, &Asm[c*16][0]);
      } else {
        int row = (c-CHA)*16 + rchunk;
        gload_lds(Bb + (long long)(n0+row)*ldb + k0 + kchunk, &Bsm[(c-CHA)*16][0]);
      }
    }
    __syncthreads();
    bf16x8 af[MF], bfr[NF];
    #pragma unroll
    for (int m = 0; m < MF; ++m)
      af[m] = *(const bf16x8*)&Asm[wm*(MF*16) + m*16 + row16][kq];
    #pragma unroll
    for (int n = 0; n < NF; ++n)
      bfr[n] = *(const bf16x8*)&Bsm[wn*(NF*16) + n*16 + row16][kq];
    #pragma unroll
    for (int m = 0; m < MF; ++m)
      #pragma unroll
      for (int n = 0; n < NF; ++n)
        acc[m][n] = __builtin_amdgcn_mfma_f32_16x16x32_bf16(af[m], bfr[n], acc[m][n], 0, 0, 0);
    __syncthreads();
  }

  #pragma unroll
  for (int m = 0; m < MF; ++m){
    #pragma unroll
    for (int n = 0; n < NF; ++n){
      int gn = n0 + wn*(NF*16) + n*16 + (lane & 15);
      float bn_ = bias_n ? b2f(bias_n[gn]) : 0.f;
      float sc = scale_n ? scale_n[gn] : 1.f;
      float sh = shift_n ? shift_n[gn] : 0.f;
      #pragma unroll
      for (int r = 0; r < 4; ++r){
        int gm = m0 + wm*(MF*16) + m*16 + (lane >> 4)*4 + r;
        float v = acc[m][n][r] * alpha + bn_;
        v = v * sc + sh;
        if (act) v = gelu_f(v);
        long long idx = (long long)gm*ldc + gn;
        if (Fb) v += b2f(Fb[idx]);
        if (beta){
          float old;
          if constexpr (__is_same(TC, float)) old = Cb[idx]; else old = b2f(Cb[idx]);
          v += old;
        }
        if constexpr (__is_same(TC, float)) Cb[idx] = v; else Cb[idx] = f2b(v);
      }
    }
  }
}

template<int MF, int NF, typename TC>
static void gmfma_x(hipStream_t st, int z, int M, int N, int K,
                    const bf16* A, int lda, long long sA, long long sA2,
                    const bf16* Bt, int ldb, long long sB, long long sB2,
                    TC* C, int ldc, long long sC, long long sC2,
                    float alpha = 1.f, int beta = 0,
                    const bf16* bias_n = nullptr,
                    const float* scale_n = nullptr, const float* shift_n = nullptr,
                    const bf16* addF = nullptr, int act = 0)
{
  dim3 g(N/(NF*32), M/(MF*32), z);
  gmfma_k<MF,NF,TC><<<g, 256, 0, st>>>(M,N,K,A,lda,sA,sA2,Bt,ldb,sB,sB2,C,ldc,sC,sC2,
                                       alpha,beta,bias_n,scale_n,shift_n,addF,act);
}

template<int MF, int NF, typename TC>
static void gmfma(hipStream_t st, int z, int M, int N, int K,
                  const bf16* A, int lda, long long sA,
                  const bf16* Bt, int ldb, long long sB,
                  TC* C, int ldc, long long sC,
                  float alpha = 1.f, int beta = 0,
                  const bf16* bias_n = nullptr,
                  const float* scale_n = nullptr, const float* shift_n = nullptr,
                  const bf16* addF = nullptr, int act = 0)
{
  gmfma_x<MF,NF,TC>(st, z, M, N, K, A, lda, sA, 8*sA, Bt, ldb, sB, 8*sB,
                    C, ldc, sC, 8*sC, alpha, beta, bias_n, scale_n, shift_n, addF, act);
}

// ---------- LayerNorm fp32 -> bf16 ----------
__global__ __launch_bounds__(256) void ln_k(const float* __restrict__ X, bf16* __restrict__ Y,
                                            const bf16* __restrict__ w, const bf16* __restrict__ b){
  long long row = blockIdx.x;
  const float* x = X + row*512;
  bf16* y = Y + row*512;
  int tid = threadIdx.x;
  float v0 = x[tid], v1 = x[tid+256];
  float mean = block_reduce<false>(v0+v1) * (1.f/512.f);
  float msq  = block_reduce<false>(v0*v0+v1*v1) * (1.f/512.f);
  float var = msq - mean*mean;
  float rs = rsqrtf(var + 1e-5f);
  y[tid]     = f2b((v0-mean)*rs*b2f(w[tid])     + b2f(b[tid]));
  y[tid+256] = f2b((v1-mean)*rs*b2f(w[tid+256]) + b2f(b[tid+256]));
}

// ---------- softmax (float, spectral) ----------
__global__ __launch_bounds__(256) void softmax_k(float* __restrict__ data, int cols){
  long long row = blockIdx.x;
  float* p = data + row * (long long)cols;
  int tid = threadIdx.x;
  int per = cols >> 8;
  float v[4];
  float mx = -3.4e38f;
  for (int r = 0; r < per; ++r){ v[r] = p[tid + (r<<8)]; mx = fmaxf(mx, v[r]); }
  mx = block_reduce<true>(mx);
  float sum = 0.f;
  for (int r = 0; r < per; ++r){ v[r] = __expf(v[r] - mx); sum += v[r]; }
  sum = block_reduce<false>(sum);
  float inv = 1.f / sum;
  for (int r = 0; r < per; ++r) p[tid + (r<<8)] = v[r] * inv;
}

// ---------- per-row max + 1/sum(exp) of attn score rows ----------
// Sp[b][h][i][j] planar; Mrow/Irow[b][i][h]. grid (1024 rows, NB).
__global__ __launch_bounds__(256) void maxsum_k(const bf16* __restrict__ Sp,
                                                float* __restrict__ Mrow, float* __restrict__ Irow,
                                                long long bstride){
  __shared__ float redmx[4][8];
  __shared__ float redsum[4][8];
  int i = blockIdx.x;
  long long b = blockIdx.y;
  const bf16* src = Sp + b*bstride + (long long)i*1024;
  int tid = threadIdx.x;
  int lane = tid & 63, w = tid >> 6;
  int j0 = tid*4;

  float v[8][4];
  #pragma unroll
  for (int h = 0; h < 8; ++h){
    ushort4 u = *(const ushort4*)&src[h*1048576 + j0];
    v[h][0] = bits2f(u.x); v[h][1] = bits2f(u.y);
    v[h][2] = bits2f(u.z); v[h][3] = bits2f(u.w);
  }
  #pragma unroll
  for (int h = 0; h < 8; ++h){
    float m = fmaxf(fmaxf(v[h][0], v[h][1]), fmaxf(v[h][2], v[h][3]));
    #pragma unroll
    for (int o = 32; o > 0; o >>= 1) m = fmaxf(m, __shfl_xor(m, o, 64));
    if (lane == 0) redmx[w][h] = m;
  }
  __syncthreads();
  float mx[8];
  #pragma unroll
  for (int h = 0; h < 8; ++h)
    mx[h] = fmaxf(fmaxf(redmx[0][h], redmx[1][h]), fmaxf(redmx[2][h], redmx[3][h]));
  #pragma unroll
  for (int h = 0; h < 8; ++h){
    float s = 0.f;
    #pragma unroll
    for (int r = 0; r < 4; ++r) s += __expf(v[h][r] - mx[h]);
    #pragma unroll
    for (int o = 32; o > 0; o >>= 1) s += __shfl_xor(s, o, 64);
    if (lane == 0) redsum[w][h] = s;
  }
  __syncthreads();
  if (tid < 8){
    float s = redsum[0][tid] + redsum[1][tid] + redsum[2][tid] + redsum[3][tid];
    long long o = (b*1024 + i)*8 + tid;
    Mrow[o] = mx[tid];
    Irow[o] = 1.f / s;
  }
}

// ---------- fused normalize(softmax) + 3x3 MFMA conv ----------
// Sp[b][h][i][j] planar raw scores; Pout[b][h][i][j] planar conv'd softmaxed map.
// grid (16 j-tiles, 64 i-tiles, NB); block 256; i-tile 16 rows (18 with halo).
__global__ __launch_bounds__(256) void convNorm_k(const bf16* __restrict__ Sp, bf16* __restrict__ Pout,
                                                  const bf16* __restrict__ Wr, const bf16* __restrict__ bias,
                                                  const float* __restrict__ Mrow, const float* __restrict__ Irow,
                                                  long long bstride){
  __shared__ bf16 tile[18][66][8];
  __shared__ float mrow[18][8];
  __shared__ float irow[18][8];
  long long b = blockIdx.z;
  int i0 = blockIdx.y*16, j0 = blockIdx.x*64;
  int tid = threadIdx.x;
  const bf16* src = Sp + b*bstride;

  // stage normalizers for the 18 halo rows
  for (int t = tid; t < 144; t += 256){
    int r = t >> 3, h = t & 7;
    int gi = i0 + r - 1;
    float m = 0.f, iv = 0.f;
    if ((unsigned)gi < 1024u){
      long long o = (b*1024 + gi)*8 + h;
      m = Mrow[o]; iv = Irow[o];
    }
    mrow[r][h] = m; irow[r][h] = iv;
  }
  __syncthreads();

  // stage tile: planar gather + exp-normalize + interleave
  for (int t = tid; t < 18*66; t += 256){
    int row = t / 66, col = t - row*66;
    int gi = i0 + row - 1, gj = j0 + col - 1;
    bf16x8 val = {};
    if ((unsigned)gi < 1024u && (unsigned)gj < 1024u){
      long long base = (long long)gi*1024 + gj;
      #pragma unroll
      for (int h = 0; h < 8; ++h){
        float s = b2f(src[(long long)h*1048576 + base]);
        val[h] = (short)f2bits(__expf(s - mrow[row][h]) * irow[row][h]);
      }
    }
    *(bf16x8*)&tile[row][col][0] = val;
  }

  int lane = tid & 63, wid = tid >> 6;
  int row16 = lane & 15, q = lane >> 4;
  bf16x8 bf0 = *(const bf16x8*)&Wr[row16*96 +  0 + q*8];
  bf16x8 bf1 = *(const bf16x8*)&Wr[row16*96 + 32 + q*8];
  bf16x8 bf2 = *(const bf16x8*)&Wr[row16*96 + 64 + q*8];
  float bv = (row16 < 8) ? b2f(bias[row16]) : 0.f;
  __syncthreads();

  f32x4 zero = {0.f,0.f,0.f,0.f};
  #pragma unroll
  for (int rr = 0; rr < 4; ++rr){
    int ii = rr*4 + wid;                 // 0..15
    f32x4 acc[4] = {zero, zero, zero, zero};
    #pragma unroll
    for (int ks = 0; ks < 3; ++ks){
      int tap = ks*4 + q;                // 0..11
      int tcl = tap > 8 ? 0 : tap;       // invalid taps hit zero Wr rows
      int di = tcl / 3, dj = tcl - di*3;
      bf16x8 bsel = ks == 0 ? bf0 : (ks == 1 ? bf1 : bf2);
      #pragma unroll
      for (int mf = 0; mf < 4; ++mf){
        bf16x8 af = *(const bf16x8*)&tile[ii + di][mf*16 + row16 + dj][0];
        acc[mf] = __builtin_amdgcn_mfma_f32_16x16x32_bf16(af, bsel, acc[mf], 0, 0, 0);
      }
    }
    if (row16 < 8){
      bf16* dst = Pout + b*bstride + (long long)row16*1048576 + (long long)(i0 + ii)*1024;
      #pragma unroll
      for (int mf = 0; mf < 4; ++mf){
        int j = j0 + mf*16 + q*4;
        ushort4 o;
        o.x = f2bits(acc[mf][0] + bv);
        o.y = f2bits(acc[mf][1] + bv);
        o.z = f2bits(acc[mf][2] + bv);
        o.w = f2bits(acc[mf][3] + bv);
        *(ushort4*)&dst[j] = o;
      }
    }
  }
}

// ---------- 3x3 conv, 1 ch, (B,512,512) fp32 in -> bf16 TRANSPOSED out ----------
__global__ __launch_bounds__(256) void conv_spec_k(const float* __restrict__ in, bf16* __restrict__ out,
                                                   const bf16* __restrict__ w, const bf16* __restrict__ bias){
  __shared__ float ti[66][67];
  __shared__ bf16 toutT[64][65];
  int b = blockIdx.z;
  int i0 = blockIdx.y*64, j0 = blockIdx.x*64;
  int tid = threadIdx.x;
  const float* ib = in + (long long)b*262144;
  for (int t = tid; t < 66*66; t += 256){
    int r = t / 66, c = t - r*66;
    int gi = i0 + r - 1, gj = j0 + c - 1;
    float v = 0.f;
    if ((unsigned)gi < 512u && (unsigned)gj < 512u) v = ib[gi*512 + gj];
    ti[r][c] = v;
  }
  __syncthreads();
  float w9[9], bv = b2f(bias[0]);
  #pragma unroll
  for (int d = 0; d < 9; ++d) w9[d] = b2f(w[d]);
  int ii = tid & 63;
  #pragma unroll
  for (int q = 0; q < 16; ++q){
    int jj = (tid >> 6)*16 + q;
    float acc = bv;
    #pragma unroll
    for (int di = 0; di < 3; ++di)
      #pragma unroll
      for (int dj = 0; dj < 3; ++dj)
        acc += w9[di*3+dj] * ti[ii+di][jj+dj];
    toutT[jj][ii] = f2b(acc);
  }
  __syncthreads();
  #pragma unroll
  for (int q = 0; q < 16; ++q){
    int jj = (tid >> 6)*16 + q;
    out[(long long)b*262144 + (j0+jj)*512 + i0 + (tid & 63)] = toutT[jj][tid & 63];
  }
}

// ---------- depthwise 3x3; Hbuf (b,n,c) bf16 -> T1 (b,n,c) bf16 ----------
__global__ __launch_bounds__(256) void dwconv_k(const bf16* __restrict__ H2, bf16* __restrict__ T1,
                                                const bf16* __restrict__ w, const bf16* __restrict__ bias){
  int p = blockIdx.x*256 + threadIdx.x;
  int cp = p & 255;
  int n = (p >> 8) & 1023;
  int b = p >> 18;
  int c0 = cp*2;
  int wi = n >> 5, hg = n & 31;
  float a0 = b2f(bias[c0]), a1 = b2f(bias[c0+1]);
  #pragma unroll
  for (int di = 0; di < 3; ++di){
    int gw = wi + di - 1;
    if ((unsigned)gw >= 32u) continue;
    #pragma unroll
    for (int dj = 0; dj < 3; ++dj){
      int gh = hg + dj - 1;
      if ((unsigned)gh >= 32u) continue;
      unsigned hv = *(const unsigned*)&H2[((long long)b*1024 + (gw*32+gh))*512 + c0];
      float w0 = b2f(w[c0*9 + di*3 + dj]);
      float w1 = b2f(w[(c0+1)*9 + di*3 + dj]);
      a0 += w0 * bits2f(hv & 0xffffu);
      a1 += w1 * bits2f(hv >> 16);
    }
  }
  bf16 h0 = f2b(a0), h1 = f2b(a1);
  unsigned o = ((unsigned)*(unsigned short*)&h1 << 16) | (unsigned)*(unsigned short*)&h0;
  *(unsigned*)&T1[((long long)b*1024 + n)*512 + c0] = o;
}

// ---------- fold pw bias + BN(eval), all layers ----------
__global__ void bnaff_all_k(const bf16* __restrict__ pwb, const bf16* __restrict__ g,
                            const bf16* __restrict__ bb, const bf16* __restrict__ m,
                            const bf16* __restrict__ v, float* __restrict__ BNAFF){
  int l = blockIdx.x, o = threadIdx.x;
  float s = b2f(g[l*256+o]) * rsqrtf(b2f(v[l*256+o]) + 1e-5f);
  BNAFF[l*512 + o] = s;
  BNAFF[l*512 + 256 + o] = (b2f(pwb[l*256+o]) - b2f(m[l*256+o])) * s + b2f(bb[l*256+o]);
}

// ---------- Vt[b*8+h][d][n] = QKV[b][n][1024 + h*64 + d] ----------
__global__ __launch_bounds__(256) void vtrans_k(const bf16* __restrict__ QKV, bf16* __restrict__ Vt){
  __shared__ bf16 t[64][65];
  int z = blockIdx.z; int b = z >> 3, h = z & 7;
  const bf16* src = QKV + (long long)b*1572864 + 1024 + h*64;
  bf16* dst = Vt + (long long)z*65536;
  int n0 = blockIdx.x*64;
  int lane = threadIdx.x & 63, quad = threadIdx.x >> 6;
  #pragma unroll
  for (int k = 0; k < 16; ++k){
    int r = quad*16 + k;
    t[r][lane] = src[(long long)(n0+r)*1536 + lane];
  }
  __syncthreads();
  #pragma unroll
  for (int k = 0; k < 16; ++k){
    int d = quad*16 + k;
    dst[(long long)d*1024 + n0 + lane] = t[lane][d];
  }
}

// ---------- HbufT[b][c][n] = Hbuf[b][n][c] ----------
__global__ __launch_bounds__(256) void htrans_k(const bf16* __restrict__ Hb, bf16* __restrict__ HT){
  __shared__ bf16 t[64][65];
  int b = blockIdx.z;
  int n0 = blockIdx.x*64, c0 = blockIdx.y*64;
  int lane = threadIdx.x & 63, quad = threadIdx.x >> 6;
  #pragma unroll
  for (int k = 0; k < 16; ++k){
    int r = quad*16 + k;
    t[r][lane] = Hb[((long long)b*1024 + n0 + r)*512 + c0 + lane];
  }
  __syncthreads();
  #pragma unroll
  for (int k = 0; k < 16; ++k){
    int c = quad*16 + k;
    HT[(long long)b*524288 + (long long)(c0+c)*1024 + n0 + lane] = t[lane][c];
  }
}

// ---------- orchestration ----------
extern "C" void kernel_launch(void* const* d_in, const int* in_sizes, int n_in,
                              void* d_out, int out_size, void* d_ws, size_t ws_size,
                              hipStream_t stream)
{
  (void)in_sizes; (void)n_in; (void)out_size;

  const bool big = ws_size >= 207000000ull;
  const long long ATTN_SZ = big ? 33554432LL : 8388608LL;

  // ---- arena ----
  float* X     = (float*)d_ws;                    // 2,097,152 f32
  bf16*  WBsm  = (bf16*)(X + 2097152);            // 2,139,648
  bf16*  WqkvT = WBsm  + 2139648;                 // 3,145,728
  bf16*  WoutT = WqkvT + 3145728;                 // 1,048,576
  bf16*  WqsT  = WoutT + 1048576;                 // 8,388,608
  bf16*  Hbuf  = WqsT  + 8388608;                 // 2,097,152
  bf16*  HbufT = Hbuf  + 2097152;                 // 2,097,152
  bf16*  QKV   = HbufT + 2097152;                 // 6,291,456
  bf16*  Vt    = QKV   + 6291456;                 // 2,097,152
  bf16*  OUTH  = Vt    + 2097152;                 // 2,097,152  (alias ASPEC f32)
  bf16*  OUT   = OUTH  + 2097152;                 // 2,097,152
  bf16*  ATTN  = OUT   + 2097152;                 // ATTN_SZ    (alias SQK, T1, T3)
  bf16*  ATTNC = ATTN  + ATTN_SZ;                 // ATTN_SZ    (alias ASPECC_T, T2)
  float* BNAFF = (float*)(ATTNC + ATTN_SZ);       // 2048 f32
  bf16*  WR    = (bf16*)(BNAFF + 2048);           // 6144 bf16
  float* MROW  = (float*)(WR + 6144);             // 32768 f32
  float* IROW  = MROW + 32768;                    // 32768 f32
  int*   FLAG  = (int*)(IROW + 32768);

  float* ASPEC   = (float*)OUTH;
  bf16*  ASPECCT = ATTNC;
  bf16*  T1 = ATTN;
  bf16*  T3 = ATTN + 2097152;
  bf16*  T2 = ATTNC + 2097152;
  bf16*  SQK = ATTN;

  // ---- small-weight arena ----
  static const int widx[21] = {1,2,5,6,7,9,10,11,12,13,14,15,16,17,18,19,20,21,22,23,24};
  static const long long wsz[21] = {2048,2048,2048,2304,32,36,4,2048,2048,18432,2048,
                                    524288,1024,1024,1024,1024,1024,524288,2048,1048576,2048};
  WCvt21 wc;
  long long cum = 0;
  bf16* wp[21];
  for (int t = 0; t < 21; ++t){
    wc.src[t] = d_in[widx[t]];
    wc.cum[t] = cum;
    wp[t] = WBsm + cum;
    cum += wsz[t];
  }
  wc.cum[21] = cum;

  bf16 *w_ln1w = wp[0],  *w_ln1b = wp[1],  *w_bout = wp[2],  *w_spw = wp[3];
  bf16 *w_spb  = wp[4],  *w_specw= wp[5],  *w_specb= wp[6],  *w_ln2w= wp[7];
  bf16 *w_ln2b = wp[8],  *w_dww  = wp[9],  *w_dwb  = wp[10], *w_pww = wp[11];
  bf16 *w_pwb  = wp[12], *w_bng  = wp[13], *w_bnb  = wp[14], *w_bnm = wp[15];
  bf16 *w_bnv  = wp[16], *w_c1w  = wp[17], *w_c1b  = wp[18], *w_c2w = wp[19];
  bf16 *w_c2b  = wp[20];

  // ---- setup ----
  detect_k<<<1, 256, 0, stream>>>((const unsigned*)d_in[0], FLAG);
  cvt_x_k<<<8192, 256, 0, stream>>>(d_in[0], X, FLAG);
  cvt_w_k<<<(int)((cum + 255)/256), 256, 0, stream>>>(wc, WBsm, cum, FLAG);
  wtrans_k<<<dim3(8,24,4), 256, 0, stream>>>(d_in[3], WqkvT, 1536, 512, 786432LL, 786432LL, FLAG);
  wtrans_k<<<dim3(8, 8,4), 256, 0, stream>>>(d_in[4], WoutT,  512, 512, 262144LL, 262144LL, FLAG);
  wtrans_k<<<dim3(16,32,4),256, 0, stream>>>(d_in[8], WqsT,  3072,1024, 3145728LL,2097152LL, FLAG);
  bnaff_all_k<<<4, 256, 0, stream>>>(w_pwb, w_bng, w_bnb, w_bnm, w_bnv, BNAFF);
  wprep_k<<<4, 256, 0, stream>>>(w_spw, WR);

  for (int l = 0; l < 4; ++l){
    // --- spatial attention ---
    ln_k<<<4096, 256, 0, stream>>>(X, Hbuf, w_ln1w + l*512, w_ln1b + l*512);
    gmfma<4,4,bf16>(stream, 1, 4096, 1536, 512,
        Hbuf, 512, 0, WqkvT + (long long)l*786432, 512, 0, QKV, 1536, 0);
    vtrans_k<<<dim3(16,1,32), 256, 0, stream>>>(QKV, Vt);
    if (big){
      gmfma_x<4,4,bf16>(stream, 32, 1024, 1024, 64,
          QKV, 1536, 64, 1572864, QKV + 512, 1536, 64, 1572864,
          ATTN, 1024, 1048576, 8388608, 0.125f);
      maxsum_k<<<dim3(1024,4), 256, 0, stream>>>(ATTN, MROW, IROW, 8388608LL);
      convNorm_k<<<dim3(16,64,4), 256, 0, stream>>>(ATTN, ATTNC, WR + l*1536, w_spb + l*8,
                                                    MROW, IROW, 8388608LL);
      gmfma_x<2,2,bf16>(stream, 32, 1024, 64, 1024,
          ATTNC, 1024, 1048576, 8388608, Vt, 1024, 65536, 524288,
          OUTH, 512, 64, 524288);
    } else {
      for (int b = 0; b < 4; ++b){
        bf16* qkvb = QKV + (long long)b*1572864;
        gmfma<4,4,bf16>(stream, 8, 1024, 1024, 64,
            qkvb, 1536, 64, qkvb + 512, 1536, 64, ATTN, 1024, 1048576, 0.125f);
        maxsum_k<<<dim3(1024,1), 256, 0, stream>>>(ATTN, MROW, IROW, 8388608LL);
        convNorm_k<<<dim3(16,64,1), 256, 0, stream>>>(ATTN, ATTNC, WR + l*1536, w_spb + l*8,
                                                      MROW, IROW, 8388608LL);
        gmfma<2,2,bf16>(stream, 8, 1024, 64, 1024,
            ATTNC, 1024, 1048576, Vt + (long long)b*524288, 1024, 65536,
            OUTH + (long long)b*524288, 512, 64);
      }
    }
    gmfma<2,2,bf16>(stream, 1, 4096, 512, 512,
        OUTH, 512, 0, WoutT + (long long)l*262144, 512, 0, OUT, 512, 0,
        1.f, 0, w_bout + l*512);
    // --- spectral attention ---
    htrans_k<<<dim3(16,8,4), 256, 0, stream>>>(Hbuf, HbufT);
    gmfma<4,4,bf16>(stream, 4, 512, 2048, 1024,
        HbufT, 1024, 524288, WqsT + (long long)l*2097152, 1024, 0, SQK, 2048, 1048576);
    gmfma<2,2,float>(stream, 4, 512, 512, 1024,
        SQK, 2048, 1048576, SQK + 1024, 2048, 1048576, ASPEC, 512, 262144, 0.125f);
    softmax_k<<<2048, 256, 0, stream>>>(ASPEC, 512);
    conv_spec_k<<<dim3(8,8,4), 256, 0, stream>>>(ASPEC, ASPECCT, w_specw + l*9, w_specb + l);
    gmfma<2,2,float>(stream, 4, 1024, 512, 512,
        OUT, 512, 524288, ASPECCT, 512, 262144, X, 512, 524288, 1.f, 1);
    // --- conv FFN ---
    ln_k<<<4096, 256, 0, stream>>>(X, Hbuf, w_ln2w + l*512, w_ln2b + l*512);
    dwconv_k<<<4096, 256, 0, stream>>>(Hbuf, T1, w_dww + l*4608, w_dwb + l*512);
    gmfma<2,2,bf16>(stream, 4, 1024, 256, 512,
        T1, 512, 524288, w_pww + (long long)l*131072, 512, 0, T2, 256, 262144,
        1.f, 0, nullptr, BNAFF + l*512, BNAFF + l*512 + 256);
    gmfma<2,2,bf16>(stream, 4, 1024, 512, 256,
        T2, 256, 262144, w_c1w + (long long)l*131072, 256, 0, T3, 512, 524288,
        1.f, 0, w_c1b + l*512, nullptr, nullptr, nullptr, 1);
    gmfma<2,2,float>(stream, 4, 1024, 512, 512,
        T3, 512, 524288, w_c2w + (long long)l*262144, 512, 0, X, 512, 524288,
        1.f, 1, w_c2b + l*512, nullptr, nullptr, Hbuf, 1);
  }

  store_out_k<<<8192, 256, 0, stream>>>(X, d_out, FLAG);
}

// Round 7
// 1245.859 us; speedup vs baseline: 20.9205x; 1.0296x over previous
//
#include <hip/hip_runtime.h>
#include <hip/hip_bf16.h>

typedef __hip_bfloat16 bf16;
typedef __attribute__((ext_vector_type(8))) short bf16x8;
typedef __attribute__((ext_vector_type(4))) float f32x4;

// ---------- helpers ----------
__device__ __forceinline__ float b2f(bf16 v){ return __bfloat162float(v); }
__device__ __forceinline__ bf16 f2b(float v){ return __float2bfloat16(v); }
__device__ __forceinline__ float bits2f(unsigned u){ return __uint_as_float(u << 16); }
__device__ __forceinline__ unsigned short f2bits(float v){ bf16 t = __float2bfloat16(v); return *(unsigned short*)&t; }

__device__ __forceinline__ float gelu_f(float x){
  return 0.5f * x * (1.f + erff(x * 0.7071067811865475f));
}

__device__ __forceinline__ void gload_lds(const void* g, void* l){
  __builtin_amdgcn_global_load_lds((const __attribute__((address_space(1))) void*)g,
                                   (__attribute__((address_space(3))) void*)l, 16, 0, 0);
}

template<bool MAX>
__device__ __forceinline__ float block_reduce(float v){
  __shared__ float s[4];
  #pragma unroll
  for (int o = 32; o > 0; o >>= 1){
    float t = __shfl_down(v, o, 64);
    v = MAX ? fmaxf(v, t) : (v + t);
  }
  int lane = threadIdx.x & 63, w = threadIdx.x >> 6;
  __syncthreads();
  if (lane == 0) s[w] = v;
  __syncthreads();
  return MAX ? fmaxf(fmaxf(s[0], s[1]), fmaxf(s[2], s[3]))
             : (s[0] + s[1] + s[2] + s[3]);
}

// ---------- dtype detect + converters ----------
__global__ void detect_k(const unsigned* __restrict__ x, int* __restrict__ flag){
  __shared__ int cnt[256];
  int tid = threadIdx.x;
  int c = 0;
  for (int i = tid; i < 4096; i += 256){
    unsigned h = x[i] & 0xffffu;
    int e = (int)((h >> 7) & 0xff);
    if (h == 0u || (e >= 100 && e <= 133)) c++;
  }
  cnt[tid] = c;
  __syncthreads();
  for (int o = 128; o > 0; o >>= 1){ if (tid < o) cnt[tid] += cnt[tid+o]; __syncthreads(); }
  if (tid == 0) *flag = (cnt[0] < 2048) ? 1 : 0;
}

__global__ __launch_bounds__(256) void cvt_x_k(const void* __restrict__ src,
                                               float* __restrict__ X,
                                               const int* __restrict__ flag){
  int p = blockIdx.x*256 + threadIdx.x;
  X[p] = (*flag) ? ((const float*)src)[p]
                 : __bfloat162float(((const bf16*)src)[p]);
}

struct WCvt21 { const void* src[21]; long long cum[22]; };

__global__ __launch_bounds__(256) void cvt_w_k(WCvt21 a, bf16* __restrict__ WB,
                                               long long total, const int* __restrict__ flag){
  long long i = (long long)blockIdx.x*256 + threadIdx.x;
  if (i >= total) return;
  int t = 0;
  while (a.cum[t+1] <= i) t++;
  long long e = i - a.cum[t];
  WB[i] = (*flag) ? __float2bfloat16(((const float*)a.src[t])[e])
                  : ((const bf16*)a.src[t])[e];
}

// transpose + convert weight: dst[z][c][r] = src[z][r][c], tiles 64x64
__global__ __launch_bounds__(256) void wtrans_k(const void* __restrict__ src, bf16* __restrict__ dst,
                                                int ld_src, int ldd, long long sSrc, long long sDst,
                                                const int* __restrict__ flag){
  __shared__ bf16 t[64][65];
  int z = blockIdx.z;
  int r0 = blockIdx.x*64, c0 = blockIdx.y*64;
  int lane = threadIdx.x & 63, quad = threadIdx.x >> 6;
  const float* sf = (const float*)src;
  const bf16* sb = (const bf16*)src;
  int fl = *flag;
  #pragma unroll
  for (int k = 0; k < 16; ++k){
    int r = quad*16 + k;
    long long idx = z*sSrc + (long long)(r0+r)*ld_src + c0 + lane;
    float v = fl ? sf[idx] : b2f(sb[idx]);
    t[r][lane] = f2b(v);
  }
  __syncthreads();
  #pragma unroll
  for (int k = 0; k < 16; ++k){
    int c = quad*16 + k;
    dst[z*sDst + (long long)(c0+c)*ldd + r0 + lane] = t[lane][c];
  }
}

// conv-attn weight shuffle: Wr[l][16][96]; Wr[l][ho][tap*8+hi] = spw[l][ho][hi][tap], 0-padded
__global__ void wprep_k(const bf16* __restrict__ spw, bf16* __restrict__ Wr){
  int l = blockIdx.x;
  for (int t = threadIdx.x; t < 1536; t += 256){
    int ho = t / 96, k = t - ho*96;
    float v = 0.f;
    if (ho < 8 && k < 72){
      int tap = k >> 3, hi = k & 7;
      v = b2f(spw[l*576 + ho*72 + hi*9 + tap]);
    }
    Wr[l*1536 + t] = f2b(v);
  }
}

__global__ __launch_bounds__(256) void store_out_k(const float* __restrict__ X,
                                                   void* __restrict__ out,
                                                   const int* __restrict__ flag){
  int p = blockIdx.x*256 + threadIdx.x;
  if (*flag) ((float*)out)[p] = X[p];
  else       ((bf16*)out)[p] = f2b(X[p]);
}

// ---------- MFMA GEMM ----------
// C[z] = epi( alpha * A(MxK,row) x Bt(NxK,row)^T ); z decomposes as (z&7, z>>3)
// Optional vt: scatter V columns (gn>=1024) of QKV output into Vt[(b,h)][d][n].
template<int MF, int NF, typename TC>
__global__ __launch_bounds__(256) void gmfma_k(
    int M, int N, int K,
    const bf16* __restrict__ A, int lda, long long sA, long long sA2,
    const bf16* __restrict__ Bt, int ldb, long long sB, long long sB2,
    TC* __restrict__ C, int ldc, long long sC, long long sC2,
    float alpha, int beta,
    const bf16* __restrict__ bias_n,
    const float* __restrict__ scale_n,
    const float* __restrict__ shift_n,
    const bf16* __restrict__ addF,
    int act,
    bf16* __restrict__ vt)
{
  constexpr int BM = MF*32, BN = NF*32;
  constexpr int CHA = BM/16, CH = (BM+BN)/16;
  static_assert(CH % 4 == 0, "chunks must divide among 4 waves");
  __shared__ bf16 Asm[BM][32];
  __shared__ bf16 Bsm[BN][32];
  const int tid = threadIdx.x;
  const int lane = tid & 63, wid = tid >> 6;
  const int wm = wid >> 1, wn = wid & 1;
  const int m0 = blockIdx.y*BM, n0 = blockIdx.x*BN;
  const int z = blockIdx.z;
  const long long zl = z & 7, zh = z >> 3;
  const bf16* Ab = A + zl*sA + zh*sA2;
  const bf16* Bb = Bt + zl*sB + zh*sB2;
  TC* Cb = C + zl*sC + zh*sC2;
  const bf16* Fb = addF ? addF + zl*sC + zh*sC2 : nullptr;

  f32x4 acc[MF][NF];
  f32x4 zero = {0.f, 0.f, 0.f, 0.f};
  #pragma unroll
  for (int m = 0; m < MF; ++m)
    #pragma unroll
    for (int n = 0; n < NF; ++n) acc[m][n] = zero;

  const int rchunk = lane >> 2;
  const int kchunk = (lane & 3) * 8;
  const int row16 = lane & 15, kq = (lane >> 4) * 8;

  for (int k0 = 0; k0 < K; k0 += 32){
    #pragma unroll
    for (int cc = 0; cc < CH/4; ++cc){
      int c = wid + cc*4;
      if (c < CHA){
        int row = c*16 + rchunk;
        gload_lds(Ab + (long long)(m0+row)*lda + k0 + kchunk, &Asm[c*16][0]);
      } else {
        int row = (c-CHA)*16 + rchunk;
        gload_lds(Bb + (long long)(n0+row)*ldb + k0 + kchunk, &Bsm[(c-CHA)*16][0]);
      }
    }
    __syncthreads();
    bf16x8 af[MF], bfr[NF];
    #pragma unroll
    for (int m = 0; m < MF; ++m)
      af[m] = *(const bf16x8*)&Asm[wm*(MF*16) + m*16 + row16][kq];
    #pragma unroll
    for (int n = 0; n < NF; ++n)
      bfr[n] = *(const bf16x8*)&Bsm[wn*(NF*16) + n*16 + row16][kq];
    #pragma unroll
    for (int m = 0; m < MF; ++m)
      #pragma unroll
      for (int n = 0; n < NF; ++n)
        acc[m][n] = __builtin_amdgcn_mfma_f32_16x16x32_bf16(af[m], bfr[n], acc[m][n], 0, 0, 0);
    __syncthreads();
  }

  #pragma unroll
  for (int m = 0; m < MF; ++m){
    #pragma unroll
    for (int n = 0; n < NF; ++n){
      int gn = n0 + wn*(NF*16) + n*16 + row16;
      float bn_ = bias_n ? b2f(bias_n[gn]) : 0.f;
      float sc = scale_n ? scale_n[gn] : 1.f;
      float sh = shift_n ? shift_n[gn] : 0.f;
      int gmb = m0 + wm*(MF*16) + m*16 + (lane >> 4)*4;
      float vals[4];
      #pragma unroll
      for (int r = 0; r < 4; ++r){
        int gm = gmb + r;
        float v = acc[m][n][r] * alpha + bn_;
        v = v * sc + sh;
        if (act) v = gelu_f(v);
        long long idx = (long long)gm*ldc + gn;
        if (Fb) v += b2f(Fb[idx]);
        if (beta){
          float old;
          if constexpr (__is_same(TC, float)) old = Cb[idx]; else old = b2f(Cb[idx]);
          v += old;
        }
        if constexpr (__is_same(TC, float)) Cb[idx] = v; else Cb[idx] = f2b(v);
        vals[r] = v;
      }
      if (vt && gn >= 1024){
        int h = (gn - 1024) >> 6, d = (gn - 1024) & 63;
        int bb = gmb >> 10, nn = gmb & 1023;
        ushort4 o;
        o.x = f2bits(vals[0]); o.y = f2bits(vals[1]);
        o.z = f2bits(vals[2]); o.w = f2bits(vals[3]);
        *(ushort4*)&vt[(((long long)bb*8 + h)*64 + d)*1024 + nn] = o;
      }
    }
  }
}

template<int MF, int NF, typename TC>
static void gmfma_x(hipStream_t st, int z, int M, int N, int K,
                    const bf16* A, int lda, long long sA, long long sA2,
                    const bf16* Bt, int ldb, long long sB, long long sB2,
                    TC* C, int ldc, long long sC, long long sC2,
                    float alpha = 1.f, int beta = 0,
                    const bf16* bias_n = nullptr,
                    const float* scale_n = nullptr, const float* shift_n = nullptr,
                    const bf16* addF = nullptr, int act = 0, bf16* vt = nullptr)
{
  dim3 g(N/(NF*32), M/(MF*32), z);
  gmfma_k<MF,NF,TC><<<g, 256, 0, st>>>(M,N,K,A,lda,sA,sA2,Bt,ldb,sB,sB2,C,ldc,sC,sC2,
                                       alpha,beta,bias_n,scale_n,shift_n,addF,act,vt);
}

template<int MF, int NF, typename TC>
static void gmfma(hipStream_t st, int z, int M, int N, int K,
                  const bf16* A, int lda, long long sA,
                  const bf16* Bt, int ldb, long long sB,
                  TC* C, int ldc, long long sC,
                  float alpha = 1.f, int beta = 0,
                  const bf16* bias_n = nullptr,
                  const float* scale_n = nullptr, const float* shift_n = nullptr,
                  const bf16* addF = nullptr, int act = 0, bf16* vt = nullptr)
{
  gmfma_x<MF,NF,TC>(st, z, M, N, K, A, lda, sA, 8*sA, Bt, ldb, sB, 8*sB,
                    C, ldc, sC, 8*sC, alpha, beta, bias_n, scale_n, shift_n, addF, act, vt);
}

// ---------- LayerNorm fp32 -> bf16 ----------
__global__ __launch_bounds__(256) void ln_k(const float* __restrict__ X, bf16* __restrict__ Y,
                                            const bf16* __restrict__ w, const bf16* __restrict__ b){
  long long row = blockIdx.x;
  const float* x = X + row*512;
  bf16* y = Y + row*512;
  int tid = threadIdx.x;
  float v0 = x[tid], v1 = x[tid+256];
  float mean = block_reduce<false>(v0+v1) * (1.f/512.f);
  float msq  = block_reduce<false>(v0*v0+v1*v1) * (1.f/512.f);
  float var = msq - mean*mean;
  float rs = rsqrtf(var + 1e-5f);
  y[tid]     = f2b((v0-mean)*rs*b2f(w[tid])     + b2f(b[tid]));
  y[tid+256] = f2b((v1-mean)*rs*b2f(w[tid+256]) + b2f(b[tid+256]));
}

// ---------- per-row max + 1/sum(exp) of attn score rows ----------
__global__ __launch_bounds__(256) void maxsum_k(const bf16* __restrict__ Sp,
                                                float* __restrict__ Mrow, float* __restrict__ Irow,
                                                long long bstride){
  __shared__ float redmx[4][8];
  __shared__ float redsum[4][8];
  int i = blockIdx.x;
  long long b = blockIdx.y;
  const bf16* src = Sp + b*bstride + (long long)i*1024;
  int tid = threadIdx.x;
  int lane = tid & 63, w = tid >> 6;
  int j0 = tid*4;

  float v[8][4];
  #pragma unroll
  for (int h = 0; h < 8; ++h){
    ushort4 u = *(const ushort4*)&src[h*1048576 + j0];
    v[h][0] = bits2f(u.x); v[h][1] = bits2f(u.y);
    v[h][2] = bits2f(u.z); v[h][3] = bits2f(u.w);
  }
  #pragma unroll
  for (int h = 0; h < 8; ++h){
    float m = fmaxf(fmaxf(v[h][0], v[h][1]), fmaxf(v[h][2], v[h][3]));
    #pragma unroll
    for (int o = 32; o > 0; o >>= 1) m = fmaxf(m, __shfl_xor(m, o, 64));
    if (lane == 0) redmx[w][h] = m;
  }
  __syncthreads();
  float mx[8];
  #pragma unroll
  for (int h = 0; h < 8; ++h)
    mx[h] = fmaxf(fmaxf(redmx[0][h], redmx[1][h]), fmaxf(redmx[2][h], redmx[3][h]));
  #pragma unroll
  for (int h = 0; h < 8; ++h){
    float s = 0.f;
    #pragma unroll
    for (int r = 0; r < 4; ++r) s += __expf(v[h][r] - mx[h]);
    #pragma unroll
    for (int o = 32; o > 0; o >>= 1) s += __shfl_xor(s, o, 64);
    if (lane == 0) redsum[w][h] = s;
  }
  __syncthreads();
  if (tid < 8){
    float s = redsum[0][tid] + redsum[1][tid] + redsum[2][tid] + redsum[3][tid];
    long long o = (b*1024 + i)*8 + tid;
    Mrow[o] = mx[tid];
    Irow[o] = 1.f / s;
  }
}

// ---------- fused normalize(softmax) + 3x3 MFMA conv (aligned streaming) ----------
// Sp[b][h][i][j] planar raw scores -> Pout[b][h][i][j] conv'd softmaxed map.
// grid (2 j-halves, 64 i-tiles, NB); block 256; internal loop over 8 chunks of 64 cols.
__global__ __launch_bounds__(256) void convNorm_k(
    const bf16* __restrict__ Sp, bf16* __restrict__ Pout,
    const bf16* __restrict__ Wr, const bf16* __restrict__ bias,
    const float* __restrict__ Mrow, const float* __restrict__ Irow,
    long long bstride)
{
  __shared__ bf16 tile[18][66][8];     // col t <-> input col base-1+t
  __shared__ float mrow[18][8];
  __shared__ float irow[18][8];
  long long b = blockIdx.z;
  int i0 = blockIdx.y*16;
  int jh0 = blockIdx.x*512;
  int tid = threadIdx.x;
  const bf16* src = Sp + b*bstride;

  for (int t = tid; t < 144; t += 256){
    int r = t >> 3, h = t & 7;
    int gi = i0 + r - 1;
    float m = 0.f, iv = 0.f;
    if ((unsigned)gi < 1024u){ long long o = (b*1024 + gi)*8 + h; m = Mrow[o]; iv = Irow[o]; }
    mrow[r][h] = m; irow[r][h] = iv;
  }

  int lane = tid & 63, wid = tid >> 6;
  int row16 = lane & 15, q = lane >> 4;
  bf16x8 wf0 = *(const bf16x8*)&Wr[row16*96 +  0 + q*8];
  bf16x8 wf1 = *(const bf16x8*)&Wr[row16*96 + 32 + q*8];
  bf16x8 wf2 = *(const bf16x8*)&Wr[row16*96 + 64 + q*8];
  float bv = (row16 < 8) ? b2f(bias[row16]) : 0.f;

  for (int c = 0; c < 8; ++c){
    int base = jh0 + c*64;
    __syncthreads();   // protects mrow (c==0) / prev-chunk compute reads (c>0)
    // main staging: 576 units (row, hp, seg) — aligned 16B loads per plane
    for (int t = tid; t < 576; t += 256){
      int row = t >> 5, rem = t & 31;
      int hp = rem >> 3, seg = rem & 7;
      int gi = i0 + row - 1;
      int g0 = base + seg*8;
      unsigned ov[8];
      if ((unsigned)gi < 1024u){
        const bf16* p0 = src + (long long)(2*hp)*1048576 + (long long)gi*1024 + g0;
        bf16x8 a0 = *(const bf16x8*)p0;
        bf16x8 a1 = *(const bf16x8*)(p0 + 1048576);
        float m0 = mrow[row][2*hp],   i0v = irow[row][2*hp];
        float m1 = mrow[row][2*hp+1], i1v = irow[row][2*hp+1];
        #pragma unroll
        for (int k = 0; k < 8; ++k){
          float e0 = __expf(bits2f((unsigned)(unsigned short)a0[k]) - m0) * i0v;
          float e1 = __expf(bits2f((unsigned)(unsigned short)a1[k]) - m1) * i1v;
          ov[k] = (unsigned)f2bits(e0) | ((unsigned)f2bits(e1) << 16);
        }
      } else {
        #pragma unroll
        for (int k = 0; k < 8; ++k) ov[k] = 0u;
      }
      #pragma unroll
      for (int k = 0; k < 8; ++k)
        *(unsigned*)&tile[row][1 + seg*8 + k][2*hp] = ov[k];
    }
    // halo cols 0 (base-1) and 65 (base+64): 72 units (row,hp), L1/L2 hits
    if (tid < 72){
      int row = tid >> 2, hp = tid & 3;
      int gi = i0 + row - 1;
      unsigned L = 0u, R = 0u;
      if ((unsigned)gi < 1024u){
        long long rb = (long long)gi*1024;
        int cl = base - 1, cr = base + 64;
        float m0 = mrow[row][2*hp],   i0v = irow[row][2*hp];
        float m1 = mrow[row][2*hp+1], i1v = irow[row][2*hp+1];
        if (cl >= 0){
          float e0 = __expf(b2f(src[(long long)(2*hp)*1048576 + rb + cl]) - m0) * i0v;
          float e1 = __expf(b2f(src[(long long)(2*hp+1)*1048576 + rb + cl]) - m1) * i1v;
          L = (unsigned)f2bits(e0) | ((unsigned)f2bits(e1) << 16);
        }
        if (cr < 1024){
          float e0 = __expf(b2f(src[(long long)(2*hp)*1048576 + rb + cr]) - m0) * i0v;
          float e1 = __expf(b2f(src[(long long)(2*hp+1)*1048576 + rb + cr]) - m1) * i1v;
          R = (unsigned)f2bits(e0) | ((unsigned)f2bits(e1) << 16);
        }
      }
      *(unsigned*)&tile[row][0][2*hp] = L;
      *(unsigned*)&tile[row][65][2*hp] = R;
    }
    __syncthreads();
    // compute: per wave 4 rr x 3 ks x 4 mf MFMA
    #pragma unroll
    for (int rr = 0; rr < 4; ++rr){
      int ii = rr*4 + wid;
      f32x4 zero = {0.f,0.f,0.f,0.f};
      f32x4 acc[4] = {zero,zero,zero,zero};
      #pragma unroll
      for (int ks = 0; ks < 3; ++ks){
        int tap = ks*4 + q;
        int tcl = tap > 8 ? 0 : tap;
        int di = tcl/3, dj = tcl - di*3;
        bf16x8 wsel = ks==0 ? wf0 : (ks==1 ? wf1 : wf2);
        #pragma unroll
        for (int mf = 0; mf < 4; ++mf){
          bf16x8 af = *(const bf16x8*)&tile[ii+di][mf*16 + row16 + dj][0];
          acc[mf] = __builtin_amdgcn_mfma_f32_16x16x32_bf16(af, wsel, acc[mf], 0, 0, 0);
        }
      }
      if (row16 < 8){
        bf16* dst = Pout + b*bstride + (long long)row16*1048576 + (long long)(i0+ii)*1024;
        #pragma unroll
        for (int mf = 0; mf < 4; ++mf){
          int j = base + mf*16 + q*4;
          ushort4 o;
          o.x = f2bits(acc[mf][0] + bv);
          o.y = f2bits(acc[mf][1] + bv);
          o.z = f2bits(acc[mf][2] + bv);
          o.w = f2bits(acc[mf][3] + bv);
          *(ushort4*)&dst[j] = o;
        }
      }
    }
  }
}

// ---------- spectral softmax stats: per row of (B*512,512) f32 ----------
__global__ __launch_bounds__(256) void spec_ms_k(const float* __restrict__ A,
                                                 float* __restrict__ Sm, float* __restrict__ Si){
  int row = blockIdx.x;
  const float* p = A + (long long)row*512;
  int tid = threadIdx.x;
  float v0 = p[tid], v1 = p[tid+256];
  float mx = block_reduce<true>(fmaxf(v0, v1));
  float s = block_reduce<false>(__expf(v0-mx) + __expf(v1-mx));
  if (tid == 0){ Sm[row] = mx; Si[row] = 1.f/s; }
}

// ---------- 3x3 conv, 1 ch, normalize-during-staging, bf16 TRANSPOSED out ----------
__global__ __launch_bounds__(256) void conv_spec_k(const float* __restrict__ in, bf16* __restrict__ out,
                                                   const bf16* __restrict__ w, const bf16* __restrict__ bias,
                                                   const float* __restrict__ Sm, const float* __restrict__ Si){
  __shared__ float ti[66][67];
  __shared__ bf16 toutT[64][65];
  __shared__ float sms[66], sis[66];
  int b = blockIdx.z;
  int i0 = blockIdx.y*64, j0 = blockIdx.x*64;
  int tid = threadIdx.x;
  const float* ib = in + (long long)b*262144;
  if (tid < 66){
    int gi = i0 + tid - 1;
    float m = 0.f, iv = 0.f;
    if ((unsigned)gi < 512u){ m = Sm[b*512 + gi]; iv = Si[b*512 + gi]; }
    sms[tid] = m; sis[tid] = iv;
  }
  __syncthreads();
  for (int t = tid; t < 66*66; t += 256){
    int r = t / 66, cc = t - r*66;
    int gi = i0 + r - 1, gj = j0 + cc - 1;
    float v = 0.f;
    if ((unsigned)gi < 512u && (unsigned)gj < 512u)
      v = __expf(ib[gi*512 + gj] - sms[r]) * sis[r];
    ti[r][cc] = v;
  }
  __syncthreads();
  float w9[9], bv = b2f(bias[0]);
  #pragma unroll
  for (int d = 0; d < 9; ++d) w9[d] = b2f(w[d]);
  int ii = tid & 63;
  #pragma unroll
  for (int q = 0; q < 16; ++q){
    int jj = (tid >> 6)*16 + q;
    float acc = bv;
    #pragma unroll
    for (int di = 0; di < 3; ++di)
      #pragma unroll
      for (int dj = 0; dj < 3; ++dj)
        acc += w9[di*3+dj] * ti[ii+di][jj+dj];
    toutT[jj][ii] = f2b(acc);
  }
  __syncthreads();
  #pragma unroll
  for (int q = 0; q < 16; ++q){
    int jj = (tid >> 6)*16 + q;
    out[(long long)b*262144 + (j0+jj)*512 + i0 + (tid & 63)] = toutT[jj][tid & 63];
  }
}

// ---------- depthwise 3x3; Hbuf (b,n,c) bf16 -> T1 (b,n,c) bf16 ----------
__global__ __launch_bounds__(256) void dwconv_k(const bf16* __restrict__ H2, bf16* __restrict__ T1,
                                                const bf16* __restrict__ w, const bf16* __restrict__ bias){
  int p = blockIdx.x*256 + threadIdx.x;
  int cp = p & 255;
  int n = (p >> 8) & 1023;
  int b = p >> 18;
  int c0 = cp*2;
  int wi = n >> 5, hg = n & 31;
  float a0 = b2f(bias[c0]), a1 = b2f(bias[c0+1]);
  #pragma unroll
  for (int di = 0; di < 3; ++di){
    int gw = wi + di - 1;
    if ((unsigned)gw >= 32u) continue;
    #pragma unroll
    for (int dj = 0; dj < 3; ++dj){
      int gh = hg + dj - 1;
      if ((unsigned)gh >= 32u) continue;
      unsigned hv = *(const unsigned*)&H2[((long long)b*1024 + (gw*32+gh))*512 + c0];
      float w0 = b2f(w[c0*9 + di*3 + dj]);
      float w1 = b2f(w[(c0+1)*9 + di*3 + dj]);
      a0 += w0 * bits2f(hv & 0xffffu);
      a1 += w1 * bits2f(hv >> 16);
    }
  }
  bf16 h0 = f2b(a0), h1 = f2b(a1);
  unsigned o = ((unsigned)*(unsigned short*)&h1 << 16) | (unsigned)*(unsigned short*)&h0;
  *(unsigned*)&T1[((long long)b*1024 + n)*512 + c0] = o;
}

// ---------- fold pw bias + BN(eval), all layers ----------
__global__ void bnaff_all_k(const bf16* __restrict__ pwb, const bf16* __restrict__ g,
                            const bf16* __restrict__ bb, const bf16* __restrict__ m,
                            const bf16* __restrict__ v, float* __restrict__ BNAFF){
  int l = blockIdx.x, o = threadIdx.x;
  float s = b2f(g[l*256+o]) * rsqrtf(b2f(v[l*256+o]) + 1e-5f);
  BNAFF[l*512 + o] = s;
  BNAFF[l*512 + 256 + o] = (b2f(pwb[l*256+o]) - b2f(m[l*256+o])) * s + b2f(bb[l*256+o]);
}

// ---------- HbufT[b][c][n] = Hbuf[b][n][c] ----------
__global__ __launch_bounds__(256) void htrans_k(const bf16* __restrict__ Hb, bf16* __restrict__ HT){
  __shared__ bf16 t[64][65];
  int b = blockIdx.z;
  int n0 = blockIdx.x*64, c0 = blockIdx.y*64;
  int lane = threadIdx.x & 63, quad = threadIdx.x >> 6;
  #pragma unroll
  for (int k = 0; k < 16; ++k){
    int r = quad*16 + k;
    t[r][lane] = Hb[((long long)b*1024 + n0 + r)*512 + c0 + lane];
  }
  __syncthreads();
  #pragma unroll
  for (int k = 0; k < 16; ++k){
    int c = quad*16 + k;
    HT[(long long)b*524288 + (long long)(c0+c)*1024 + n0 + lane] = t[lane][c];
  }
}

// ---------- orchestration ----------
extern "C" void kernel_launch(void* const* d_in, const int* in_sizes, int n_in,
                              void* d_out, int out_size, void* d_ws, size_t ws_size,
                              hipStream_t stream)
{
  (void)in_sizes; (void)n_in; (void)out_size;

  const bool big = ws_size >= 207000000ull;
  const long long ATTN_SZ = big ? 33554432LL : 8388608LL;

  // ---- arena ----
  float* X     = (float*)d_ws;                    // 2,097,152 f32
  bf16*  WBsm  = (bf16*)(X + 2097152);            // 2,139,648
  bf16*  WqkvT = WBsm  + 2139648;                 // 3,145,728
  bf16*  WoutT = WqkvT + 3145728;                 // 1,048,576
  bf16*  WqsT  = WoutT + 1048576;                 // 8,388,608
  bf16*  Hbuf  = WqsT  + 8388608;                 // 2,097,152
  bf16*  HbufT = Hbuf  + 2097152;                 // 2,097,152
  bf16*  QKV   = HbufT + 2097152;                 // 6,291,456
  bf16*  Vt    = QKV   + 6291456;                 // 2,097,152
  bf16*  OUTH  = Vt    + 2097152;                 // 2,097,152  (alias ASPEC f32)
  bf16*  OUT   = OUTH  + 2097152;                 // 2,097,152
  bf16*  ATTN  = OUT   + 2097152;                 // ATTN_SZ    (alias SQK, T1, T3)
  bf16*  ATTNC = ATTN  + ATTN_SZ;                 // ATTN_SZ    (alias ASPECC_T, T2)
  float* BNAFF = (float*)(ATTNC + ATTN_SZ);       // 2048 f32
  bf16*  WR    = (bf16*)(BNAFF + 2048);           // 6144 bf16
  float* MROW  = (float*)(WR + 6144);             // 32768 f32
  float* IROW  = MROW + 32768;                    // 32768 f32
  float* SMS   = IROW + 32768;                    // 2048 f32
  float* SIS   = SMS + 2048;                      // 2048 f32
  int*   FLAG  = (int*)(SIS + 2048);

  float* ASPEC   = (float*)OUTH;
  bf16*  ASPECCT = ATTNC;
  bf16*  T1 = ATTN;
  bf16*  T3 = ATTN + 2097152;
  bf16*  T2 = ATTNC + 2097152;
  bf16*  SQK = ATTN;

  // ---- small-weight arena ----
  static const int widx[21] = {1,2,5,6,7,9,10,11,12,13,14,15,16,17,18,19,20,21,22,23,24};
  static const long long wsz[21] = {2048,2048,2048,2304,32,36,4,2048,2048,18432,2048,
                                    524288,1024,1024,1024,1024,1024,524288,2048,1048576,2048};
  WCvt21 wc;
  long long cum = 0;
  bf16* wp[21];
  for (int t = 0; t < 21; ++t){
    wc.src[t] = d_in[widx[t]];
    wc.cum[t] = cum;
    wp[t] = WBsm + cum;
    cum += wsz[t];
  }
  wc.cum[21] = cum;

  bf16 *w_ln1w = wp[0],  *w_ln1b = wp[1],  *w_bout = wp[2],  *w_spw = wp[3];
  bf16 *w_spb  = wp[4],  *w_specw= wp[5],  *w_specb= wp[6],  *w_ln2w= wp[7];
  bf16 *w_ln2b = wp[8],  *w_dww  = wp[9],  *w_dwb  = wp[10], *w_pww = wp[11];
  bf16 *w_pwb  = wp[12], *w_bng  = wp[13], *w_bnb  = wp[14], *w_bnm = wp[15];
  bf16 *w_bnv  = wp[16], *w_c1w  = wp[17], *w_c1b  = wp[18], *w_c2w = wp[19];
  bf16 *w_c2b  = wp[20];

  // ---- setup ----
  detect_k<<<1, 256, 0, stream>>>((const unsigned*)d_in[0], FLAG);
  cvt_x_k<<<8192, 256, 0, stream>>>(d_in[0], X, FLAG);
  cvt_w_k<<<(int)((cum + 255)/256), 256, 0, stream>>>(wc, WBsm, cum, FLAG);
  wtrans_k<<<dim3(8,24,4), 256, 0, stream>>>(d_in[3], WqkvT, 1536, 512, 786432LL, 786432LL, FLAG);
  wtrans_k<<<dim3(8, 8,4), 256, 0, stream>>>(d_in[4], WoutT,  512, 512, 262144LL, 262144LL, FLAG);
  wtrans_k<<<dim3(16,32,4),256, 0, stream>>>(d_in[8], WqsT,  3072,1024, 3145728LL,2097152LL, FLAG);
  bnaff_all_k<<<4, 256, 0, stream>>>(w_pwb, w_bng, w_bnb, w_bnm, w_bnv, BNAFF);
  wprep_k<<<4, 256, 0, stream>>>(w_spw, WR);

  for (int l = 0; l < 4; ++l){
    // --- spatial attention ---
    ln_k<<<4096, 256, 0, stream>>>(X, Hbuf, w_ln1w + l*512, w_ln1b + l*512);
    gmfma<4,4,bf16>(stream, 1, 4096, 1536, 512,
        Hbuf, 512, 0, WqkvT + (long long)l*786432, 512, 0, QKV, 1536, 0,
        1.f, 0, nullptr, nullptr, nullptr, nullptr, 0, Vt);
    if (big){
      gmfma_x<4,4,bf16>(stream, 32, 1024, 1024, 64,
          QKV, 1536, 64, 1572864, QKV + 512, 1536, 64, 1572864,
          ATTN, 1024, 1048576, 8388608, 0.125f);
      maxsum_k<<<dim3(1024,4), 256, 0, stream>>>(ATTN, MROW, IROW, 8388608LL);
      convNorm_k<<<dim3(2,64,4), 256, 0, stream>>>(ATTN, ATTNC, WR + l*1536, w_spb + l*8,
                                                   MROW, IROW, 8388608LL);
      gmfma_x<2,2,bf16>(stream, 32, 1024, 64, 1024,
          ATTNC, 1024, 1048576, 8388608, Vt, 1024, 65536, 524288,
          OUTH, 512, 64, 524288);
    } else {
      for (int b = 0; b < 4; ++b){
        bf16* qkvb = QKV + (long long)b*1572864;
        gmfma<4,4,bf16>(stream, 8, 1024, 1024, 64,
            qkvb, 1536, 64, qkvb + 512, 1536, 64, ATTN, 1024, 1048576, 0.125f);
        maxsum_k<<<dim3(1024,1), 256, 0, stream>>>(ATTN, MROW, IROW, 8388608LL);
        convNorm_k<<<dim3(2,64,1), 256, 0, stream>>>(ATTN, ATTNC, WR + l*1536, w_spb + l*8,
                                                     MROW, IROW, 8388608LL);
        gmfma<2,2,bf16>(stream, 8, 1024, 64, 1024,
            ATTNC, 1024, 1048576, Vt + (long long)b*524288, 1024, 65536,
            OUTH + (long long)b*524288, 512, 64);
      }
    }
    gmfma<2,2,bf16>(stream, 1, 4096, 512, 512,
        OUTH, 512, 0, WoutT + (long long)l*262144, 512, 0, OUT, 512, 0,
        1.f, 0, w_bout + l*512);
    // --- spectral attention ---
    htrans_k<<<dim3(16,8,4), 256, 0, stream>>>(Hbuf, HbufT);
    gmfma<4,4,bf16>(stream, 4, 512, 2048, 1024,
        HbufT, 1024, 524288, WqsT + (long long)l*2097152, 1024, 0, SQK, 2048, 1048576);
    gmfma<2,2,float>(stream, 4, 512, 512, 1024,
        SQK, 2048, 1048576, SQK + 1024, 2048, 1048576, ASPEC, 512, 262144, 0.125f);
    spec_ms_k<<<2048, 256, 0, stream>>>(ASPEC, SMS, SIS);
    conv_spec_k<<<dim3(8,8,4), 256, 0, stream>>>(ASPEC, ASPECCT, w_specw + l*9, w_specb + l,
                                                 SMS, SIS);
    gmfma<2,2,float>(stream, 4, 1024, 512, 512,
        OUT, 512, 524288, ASPECCT, 512, 262144, X, 512, 524288, 1.f, 1);
    // --- conv FFN ---
    ln_k<<<4096, 256, 0, stream>>>(X, Hbuf, w_ln2w + l*512, w_ln2b + l*512);
    dwconv_k<<<4096, 256, 0, stream>>>(Hbuf, T1, w_dww + l*4608, w_dwb + l*512);
    gmfma<2,2,bf16>(stream, 4, 1024, 256, 512,
        T1, 512, 524288, w_pww + (long long)l*131072, 512, 0, T2, 256, 262144,
        1.f, 0, nullptr, BNAFF + l*512, BNAFF + l*512 + 256);
    gmfma<2,2,bf16>(stream, 4, 1024, 512, 256,
        T2, 256, 262144, w_c1w + (long long)l*131072, 256, 0, T3, 512, 524288,
        1.f, 0, w_c1b + l*512, nullptr, nullptr, nullptr, 1);
    gmfma<2,2,float>(stream, 4, 1024, 512, 512,
        T3, 512, 524288, w_c2w + (long long)l*262144, 512, 0, X, 512, 524288,
        1.f, 1, w_c2b + l*512, nullptr, nullptr, Hbuf, 1);
  }

  store_out_k<<<8192, 256, 0, stream>>>(X, d_out, FLAG);
}

// Round 8
// 1232.609 us; speedup vs baseline: 21.1454x; 1.0107x over previous
//
#include <hip/hip_runtime.h>
#include <hip/hip_bf16.h>

typedef __hip_bfloat16 bf16;
typedef __attribute__((ext_vector_type(8))) short bf16x8;
typedef __attribute__((ext_vector_type(4))) float f32x4;

// ---------- helpers ----------
__device__ __forceinline__ float b2f(bf16 v){ return __bfloat162float(v); }
__device__ __forceinline__ bf16 f2b(float v){ return __float2bfloat16(v); }
__device__ __forceinline__ float bits2f(unsigned u){ return __uint_as_float(u << 16); }
__device__ __forceinline__ unsigned short f2bits(float v){ bf16 t = __float2bfloat16(v); return *(unsigned short*)&t; }

__device__ __forceinline__ float gelu_f(float x){
  return 0.5f * x * (1.f + erff(x * 0.7071067811865475f));
}

__device__ __forceinline__ void gload_lds(const void* g, void* l){
  __builtin_amdgcn_global_load_lds((const __attribute__((address_space(1))) void*)g,
                                   (__attribute__((address_space(3))) void*)l, 16, 0, 0);
}

template<bool MAX>
__device__ __forceinline__ float block_reduce(float v){
  __shared__ float s[4];
  #pragma unroll
  for (int o = 32; o > 0; o >>= 1){
    float t = __shfl_down(v, o, 64);
    v = MAX ? fmaxf(v, t) : (v + t);
  }
  int lane = threadIdx.x & 63, w = threadIdx.x >> 6;
  __syncthreads();
  if (lane == 0) s[w] = v;
  __syncthreads();
  return MAX ? fmaxf(fmaxf(s[0], s[1]), fmaxf(s[2], s[3]))
             : (s[0] + s[1] + s[2] + s[3]);
}

// ---------- dtype detect + converters ----------
__global__ void detect_k(const unsigned* __restrict__ x, int* __restrict__ flag){
  __shared__ int cnt[256];
  int tid = threadIdx.x;
  int c = 0;
  for (int i = tid; i < 4096; i += 256){
    unsigned h = x[i] & 0xffffu;
    int e = (int)((h >> 7) & 0xff);
    if (h == 0u || (e >= 100 && e <= 133)) c++;
  }
  cnt[tid] = c;
  __syncthreads();
  for (int o = 128; o > 0; o >>= 1){ if (tid < o) cnt[tid] += cnt[tid+o]; __syncthreads(); }
  if (tid == 0) *flag = (cnt[0] < 2048) ? 1 : 0;
}

__global__ __launch_bounds__(256) void cvt_x_k(const void* __restrict__ src,
                                               float* __restrict__ X,
                                               const int* __restrict__ flag){
  int p = blockIdx.x*256 + threadIdx.x;
  X[p] = (*flag) ? ((const float*)src)[p]
                 : __bfloat162float(((const bf16*)src)[p]);
}

struct WCvt21 { const void* src[21]; long long cum[22]; };

__global__ __launch_bounds__(256) void cvt_w_k(WCvt21 a, bf16* __restrict__ WB,
                                               long long total, const int* __restrict__ flag){
  long long i = (long long)blockIdx.x*256 + threadIdx.x;
  if (i >= total) return;
  int t = 0;
  while (a.cum[t+1] <= i) t++;
  long long e = i - a.cum[t];
  WB[i] = (*flag) ? __float2bfloat16(((const float*)a.src[t])[e])
                  : ((const bf16*)a.src[t])[e];
}

// transpose + convert weight: dst[z][c][r] = src[z][r][c], tiles 64x64
__global__ __launch_bounds__(256) void wtrans_k(const void* __restrict__ src, bf16* __restrict__ dst,
                                                int ld_src, int ldd, long long sSrc, long long sDst,
                                                const int* __restrict__ flag){
  __shared__ bf16 t[64][65];
  int z = blockIdx.z;
  int r0 = blockIdx.x*64, c0 = blockIdx.y*64;
  int lane = threadIdx.x & 63, quad = threadIdx.x >> 6;
  const float* sf = (const float*)src;
  const bf16* sb = (const bf16*)src;
  int fl = *flag;
  #pragma unroll
  for (int k = 0; k < 16; ++k){
    int r = quad*16 + k;
    long long idx = z*sSrc + (long long)(r0+r)*ld_src + c0 + lane;
    float v = fl ? sf[idx] : b2f(sb[idx]);
    t[r][lane] = f2b(v);
  }
  __syncthreads();
  #pragma unroll
  for (int k = 0; k < 16; ++k){
    int c = quad*16 + k;
    dst[z*sDst + (long long)(c0+c)*ldd + r0 + lane] = t[lane][c];
  }
}

// conv-attn weight shuffle: Wr[l][16][96]; Wr[l][ho][tap*8+hi] = spw[l][ho][hi][tap], 0-padded
__global__ void wprep_k(const bf16* __restrict__ spw, bf16* __restrict__ Wr){
  int l = blockIdx.x;
  for (int t = threadIdx.x; t < 1536; t += 256){
    int ho = t / 96, k = t - ho*96;
    float v = 0.f;
    if (ho < 8 && k < 72){
      int tap = k >> 3, hi = k & 7;
      v = b2f(spw[l*576 + ho*72 + hi*9 + tap]);
    }
    Wr[l*1536 + t] = f2b(v);
  }
}

__global__ __launch_bounds__(256) void store_out_k(const float* __restrict__ X,
                                                   void* __restrict__ out,
                                                   const int* __restrict__ flag){
  int p = blockIdx.x*256 + threadIdx.x;
  if (*flag) ((float*)out)[p] = X[p];
  else       ((bf16*)out)[p] = f2b(X[p]);
}

// ---------- MFMA GEMM ----------
// C[z] = epi( alpha * A(MxK,row) x Bt(NxK,row)^T ); z decomposes as (z&7, z>>3)
// Optional vt: scatter V columns (gn>=1024) of QKV output into Vt[(b,h)][d][n].
template<int MF, int NF, typename TC>
__global__ __launch_bounds__(256) void gmfma_k(
    int M, int N, int K,
    const bf16* __restrict__ A, int lda, long long sA, long long sA2,
    const bf16* __restrict__ Bt, int ldb, long long sB, long long sB2,
    TC* __restrict__ C, int ldc, long long sC, long long sC2,
    float alpha, int beta,
    const bf16* __restrict__ bias_n,
    const float* __restrict__ scale_n,
    const float* __restrict__ shift_n,
    const bf16* __restrict__ addF,
    int act,
    bf16* __restrict__ vt)
{
  constexpr int BM = MF*32, BN = NF*32;
  constexpr int CHA = BM/16, CH = (BM+BN)/16;
  static_assert(CH % 4 == 0, "chunks must divide among 4 waves");
  __shared__ bf16 Asm[BM][32];
  __shared__ bf16 Bsm[BN][32];
  const int tid = threadIdx.x;
  const int lane = tid & 63, wid = tid >> 6;
  const int wm = wid >> 1, wn = wid & 1;
  const int m0 = blockIdx.y*BM, n0 = blockIdx.x*BN;
  const int z = blockIdx.z;
  const long long zl = z & 7, zh = z >> 3;
  const bf16* Ab = A + zl*sA + zh*sA2;
  const bf16* Bb = Bt + zl*sB + zh*sB2;
  TC* Cb = C + zl*sC + zh*sC2;
  const bf16* Fb = addF ? addF + zl*sC + zh*sC2 : nullptr;

  f32x4 acc[MF][NF];
  f32x4 zero = {0.f, 0.f, 0.f, 0.f};
  #pragma unroll
  for (int m = 0; m < MF; ++m)
    #pragma unroll
    for (int n = 0; n < NF; ++n) acc[m][n] = zero;

  const int rchunk = lane >> 2;
  const int kchunk = (lane & 3) * 8;
  const int row16 = lane & 15, kq = (lane >> 4) * 8;

  for (int k0 = 0; k0 < K; k0 += 32){
    #pragma unroll
    for (int cc = 0; cc < CH/4; ++cc){
      int c = wid + cc*4;
      if (c < CHA){
        int row = c*16 + rchunk;
        gload_lds(Ab + (long long)(m0+row)*lda + k0 + kchunk, &Asm[c*16][0]);
      } else {
        int row = (c-CHA)*16 + rchunk;
        gload_lds(Bb + (long long)(n0+row)*ldb + k0 + kchunk, &Bsm[(c-CHA)*16][0]);
      }
    }
    __syncthreads();
    bf16x8 af[MF], bfr[NF];
    #pragma unroll
    for (int m = 0; m < MF; ++m)
      af[m] = *(const bf16x8*)&Asm[wm*(MF*16) + m*16 + row16][kq];
    #pragma unroll
    for (int n = 0; n < NF; ++n)
      bfr[n] = *(const bf16x8*)&Bsm[wn*(NF*16) + n*16 + row16][kq];
    #pragma unroll
    for (int m = 0; m < MF; ++m)
      #pragma unroll
      for (int n = 0; n < NF; ++n)
        acc[m][n] = __builtin_amdgcn_mfma_f32_16x16x32_bf16(af[m], bfr[n], acc[m][n], 0, 0, 0);
    __syncthreads();
  }

  #pragma unroll
  for (int m = 0; m < MF; ++m){
    #pragma unroll
    for (int n = 0; n < NF; ++n){
      int gn = n0 + wn*(NF*16) + n*16 + row16;
      float bn_ = bias_n ? b2f(bias_n[gn]) : 0.f;
      float sc = scale_n ? scale_n[gn] : 1.f;
      float sh = shift_n ? shift_n[gn] : 0.f;
      int gmb = m0 + wm*(MF*16) + m*16 + (lane >> 4)*4;
      float vals[4];
      #pragma unroll
      for (int r = 0; r < 4; ++r){
        int gm = gmb + r;
        float v = acc[m][n][r] * alpha + bn_;
        v = v * sc + sh;
        if (act) v = gelu_f(v);
        long long idx = (long long)gm*ldc + gn;
        if (Fb) v += b2f(Fb[idx]);
        if (beta){
          float old;
          if constexpr (__is_same(TC, float)) old = Cb[idx]; else old = b2f(Cb[idx]);
          v += old;
        }
        if constexpr (__is_same(TC, float)) Cb[idx] = v; else Cb[idx] = f2b(v);
        vals[r] = v;
      }
      if (vt && gn >= 1024){
        int h = (gn - 1024) >> 6, d = (gn - 1024) & 63;
        int bb = gmb >> 10, nn = gmb & 1023;
        ushort4 o;
        o.x = f2bits(vals[0]); o.y = f2bits(vals[1]);
        o.z = f2bits(vals[2]); o.w = f2bits(vals[3]);
        *(ushort4*)&vt[(((long long)bb*8 + h)*64 + d)*1024 + nn] = o;
      }
    }
  }
}

template<int MF, int NF, typename TC>
static void gmfma_x(hipStream_t st, int z, int M, int N, int K,
                    const bf16* A, int lda, long long sA, long long sA2,
                    const bf16* Bt, int ldb, long long sB, long long sB2,
                    TC* C, int ldc, long long sC, long long sC2,
                    float alpha = 1.f, int beta = 0,
                    const bf16* bias_n = nullptr,
                    const float* scale_n = nullptr, const float* shift_n = nullptr,
                    const bf16* addF = nullptr, int act = 0, bf16* vt = nullptr)
{
  dim3 g(N/(NF*32), M/(MF*32), z);
  gmfma_k<MF,NF,TC><<<g, 256, 0, st>>>(M,N,K,A,lda,sA,sA2,Bt,ldb,sB,sB2,C,ldc,sC,sC2,
                                       alpha,beta,bias_n,scale_n,shift_n,addF,act,vt);
}

template<int MF, int NF, typename TC>
static void gmfma(hipStream_t st, int z, int M, int N, int K,
                  const bf16* A, int lda, long long sA,
                  const bf16* Bt, int ldb, long long sB,
                  TC* C, int ldc, long long sC,
                  float alpha = 1.f, int beta = 0,
                  const bf16* bias_n = nullptr,
                  const float* scale_n = nullptr, const float* shift_n = nullptr,
                  const bf16* addF = nullptr, int act = 0, bf16* vt = nullptr)
{
  gmfma_x<MF,NF,TC>(st, z, M, N, K, A, lda, sA, 8*sA, Bt, ldb, sB, 8*sB,
                    C, ldc, sC, 8*sC, alpha, beta, bias_n, scale_n, shift_n, addF, act, vt);
}

// ---------- LayerNorm fp32 -> bf16 ----------
__global__ __launch_bounds__(256) void ln_k(const float* __restrict__ X, bf16* __restrict__ Y,
                                            const bf16* __restrict__ w, const bf16* __restrict__ b){
  long long row = blockIdx.x;
  const float* x = X + row*512;
  bf16* y = Y + row*512;
  int tid = threadIdx.x;
  float v0 = x[tid], v1 = x[tid+256];
  float mean = block_reduce<false>(v0+v1) * (1.f/512.f);
  float msq  = block_reduce<false>(v0*v0+v1*v1) * (1.f/512.f);
  float var = msq - mean*mean;
  float rs = rsqrtf(var + 1e-5f);
  y[tid]     = f2b((v0-mean)*rs*b2f(w[tid])     + b2f(b[tid]));
  y[tid+256] = f2b((v1-mean)*rs*b2f(w[tid+256]) + b2f(b[tid+256]));
}

// ---------- per-row max + 1/sum(exp) of attn score rows ----------
__global__ __launch_bounds__(256) void maxsum_k(const bf16* __restrict__ Sp,
                                                float* __restrict__ Mrow, float* __restrict__ Irow,
                                                long long bstride){
  __shared__ float redmx[4][8];
  __shared__ float redsum[4][8];
  int i = blockIdx.x;
  long long b = blockIdx.y;
  const bf16* src = Sp + b*bstride + (long long)i*1024;
  int tid = threadIdx.x;
  int lane = tid & 63, w = tid >> 6;
  int j0 = tid*4;

  float v[8][4];
  #pragma unroll
  for (int h = 0; h < 8; ++h){
    ushort4 u = *(const ushort4*)&src[h*1048576 + j0];
    v[h][0] = bits2f(u.x); v[h][1] = bits2f(u.y);
    v[h][2] = bits2f(u.z); v[h][3] = bits2f(u.w);
  }
  #pragma unroll
  for (int h = 0; h < 8; ++h){
    float m = fmaxf(fmaxf(v[h][0], v[h][1]), fmaxf(v[h][2], v[h][3]));
    #pragma unroll
    for (int o = 32; o > 0; o >>= 1) m = fmaxf(m, __shfl_xor(m, o, 64));
    if (lane == 0) redmx[w][h] = m;
  }
  __syncthreads();
  float mx[8];
  #pragma unroll
  for (int h = 0; h < 8; ++h)
    mx[h] = fmaxf(fmaxf(redmx[0][h], redmx[1][h]), fmaxf(redmx[2][h], redmx[3][h]));
  #pragma unroll
  for (int h = 0; h < 8; ++h){
    float s = 0.f;
    #pragma unroll
    for (int r = 0; r < 4; ++r) s += __expf(v[h][r] - mx[h]);
    #pragma unroll
    for (int o = 32; o > 0; o >>= 1) s += __shfl_xor(s, o, 64);
    if (lane == 0) redsum[w][h] = s;
  }
  __syncthreads();
  if (tid < 8){
    float s = redsum[0][tid] + redsum[1][tid] + redsum[2][tid] + redsum[3][tid];
    long long o = (b*1024 + i)*8 + tid;
    Mrow[o] = mx[tid];
    Irow[o] = 1.f / s;
  }
}

// ---------- fused normalize(softmax) + 3x3 MFMA conv (aligned + swizzled LDS) ----------
// Sp[b][h][i][j] planar raw scores -> Pout[b][h][i][j] conv'd softmaxed map.
// grid (2 j-halves, 128 i-tiles, NB); block 256; 8-row tiles; 8 chunks of 64 cols.
// LDS column swizzle: col' = col ^ ((col>>3)&7)  (applied on write AND read).
__device__ __forceinline__ int csw(int col){ return col ^ ((col >> 3) & 7); }

__global__ __launch_bounds__(256) void convNorm_k(
    const bf16* __restrict__ Sp, bf16* __restrict__ Pout,
    const bf16* __restrict__ Wr, const bf16* __restrict__ bias,
    const float* __restrict__ Mrow, const float* __restrict__ Irow,
    long long bstride)
{
  __shared__ bf16 tile[10][66][8];
  __shared__ float mrow[10][8];
  __shared__ float irow[10][8];
  long long b = blockIdx.z;
  int i0 = blockIdx.y*8;
  int jh0 = blockIdx.x*512;
  int tid = threadIdx.x;
  const bf16* src = Sp + b*bstride;

  if (tid < 80){
    int r = tid >> 3, h = tid & 7;
    int gi = i0 + r - 1;
    float m = 0.f, iv = 0.f;
    if ((unsigned)gi < 1024u){ long long o = (b*1024 + gi)*8 + h; m = Mrow[o]; iv = Irow[o]; }
    mrow[r][h] = m; irow[r][h] = iv;
  }

  int lane = tid & 63, wid = tid >> 6;
  int row16 = lane & 15, q = lane >> 4;
  bf16x8 wf0 = *(const bf16x8*)&Wr[row16*96 +  0 + q*8];
  bf16x8 wf1 = *(const bf16x8*)&Wr[row16*96 + 32 + q*8];
  bf16x8 wf2 = *(const bf16x8*)&Wr[row16*96 + 64 + q*8];
  float bv = (row16 < 8) ? b2f(bias[row16]) : 0.f;

  for (int c = 0; c < 8; ++c){
    int base = jh0 + c*64;
    __syncthreads();   // protects mrow (c==0) / prev-chunk tile reads (c>0)
    // main staging: 320 units (10 rows x 4 h-pairs x 8 segs), aligned 16B loads
    for (int t = tid; t < 320; t += 256){
      int row = t >> 5, rem = t & 31;
      int hp = rem >> 3, seg = rem & 7;
      int gi = i0 + row - 1;
      int g0 = base + seg*8;
      unsigned ov[8];
      if ((unsigned)gi < 1024u){
        const bf16* p0 = src + (long long)(2*hp)*1048576 + (long long)gi*1024 + g0;
        bf16x8 a0 = *(const bf16x8*)p0;
        bf16x8 a1 = *(const bf16x8*)(p0 + 1048576);
        float m0 = mrow[row][2*hp],   i0v = irow[row][2*hp];
        float m1 = mrow[row][2*hp+1], i1v = irow[row][2*hp+1];
        #pragma unroll
        for (int k = 0; k < 8; ++k){
          float e0 = __expf(bits2f((unsigned)(unsigned short)a0[k]) - m0) * i0v;
          float e1 = __expf(bits2f((unsigned)(unsigned short)a1[k]) - m1) * i1v;
          ov[k] = (unsigned)f2bits(e0) | ((unsigned)f2bits(e1) << 16);
        }
      } else {
        #pragma unroll
        for (int k = 0; k < 8; ++k) ov[k] = 0u;
      }
      #pragma unroll
      for (int k = 0; k < 8; ++k)
        *(unsigned*)&tile[row][csw(1 + seg*8 + k)][2*hp] = ov[k];
    }
    // halo cols 0 (base-1) and 65 (base+64): 40 units (row,hp), L1/L2 hits
    if (tid < 40){
      int row = tid >> 2, hp = tid & 3;
      int gi = i0 + row - 1;
      unsigned L = 0u, R = 0u;
      if ((unsigned)gi < 1024u){
        long long rb = (long long)gi*1024;
        int cl = base - 1, cr = base + 64;
        float m0 = mrow[row][2*hp],   i0v = irow[row][2*hp];
        float m1 = mrow[row][2*hp+1], i1v = irow[row][2*hp+1];
        if (cl >= 0){
          float e0 = __expf(b2f(src[(long long)(2*hp)*1048576 + rb + cl]) - m0) * i0v;
          float e1 = __expf(b2f(src[(long long)(2*hp+1)*1048576 + rb + cl]) - m1) * i1v;
          L = (unsigned)f2bits(e0) | ((unsigned)f2bits(e1) << 16);
        }
        if (cr < 1024){
          float e0 = __expf(b2f(src[(long long)(2*hp)*1048576 + rb + cr]) - m0) * i0v;
          float e1 = __expf(b2f(src[(long long)(2*hp+1)*1048576 + rb + cr]) - m1) * i1v;
          R = (unsigned)f2bits(e0) | ((unsigned)f2bits(e1) << 16);
        }
      }
      *(unsigned*)&tile[row][csw(0)][2*hp] = L;
      *(unsigned*)&tile[row][csw(65)][2*hp] = R;
    }
    __syncthreads();
    // compute: per wave 2 rr x 3 ks x 4 mf MFMA
    #pragma unroll
    for (int rr = 0; rr < 2; ++rr){
      int ii = rr*4 + wid;
      f32x4 zero = {0.f,0.f,0.f,0.f};
      f32x4 acc[4] = {zero,zero,zero,zero};
      #pragma unroll
      for (int ks = 0; ks < 3; ++ks){
        int tap = ks*4 + q;
        int tcl = tap > 8 ? 0 : tap;
        int di = tcl/3, dj = tcl - di*3;
        bf16x8 wsel = ks==0 ? wf0 : (ks==1 ? wf1 : wf2);
        #pragma unroll
        for (int mf = 0; mf < 4; ++mf){
          bf16x8 af = *(const bf16x8*)&tile[ii+di][csw(mf*16 + row16 + dj)][0];
          acc[mf] = __builtin_amdgcn_mfma_f32_16x16x32_bf16(af, wsel, acc[mf], 0, 0, 0);
        }
      }
      if (row16 < 8){
        bf16* dst = Pout + b*bstride + (long long)row16*1048576 + (long long)(i0+ii)*1024;
        #pragma unroll
        for (int mf = 0; mf < 4; ++mf){
          int j = base + mf*16 + q*4;
          ushort4 o;
          o.x = f2bits(acc[mf][0] + bv);
          o.y = f2bits(acc[mf][1] + bv);
          o.z = f2bits(acc[mf][2] + bv);
          o.w = f2bits(acc[mf][3] + bv);
          *(ushort4*)&dst[j] = o;
        }
      }
    }
  }
}

// ---------- spectral softmax stats: per row of (B*512,512) f32 ----------
__global__ __launch_bounds__(256) void spec_ms_k(const float* __restrict__ A,
                                                 float* __restrict__ Sm, float* __restrict__ Si){
  int row = blockIdx.x;
  const float* p = A + (long long)row*512;
  int tid = threadIdx.x;
  float v0 = p[tid], v1 = p[tid+256];
  float mx = block_reduce<true>(fmaxf(v0, v1));
  float s = block_reduce<false>(__expf(v0-mx) + __expf(v1-mx));
  if (tid == 0){ Sm[row] = mx; Si[row] = 1.f/s; }
}

// ---------- 3x3 conv, 1 ch, normalize-during-staging, bf16 TRANSPOSED out ----------
__global__ __launch_bounds__(256) void conv_spec_k(const float* __restrict__ in, bf16* __restrict__ out,
                                                   const bf16* __restrict__ w, const bf16* __restrict__ bias,
                                                   const float* __restrict__ Sm, const float* __restrict__ Si){
  __shared__ float ti[66][67];
  __shared__ bf16 toutT[64][65];
  __shared__ float sms[66], sis[66];
  int b = blockIdx.z;
  int i0 = blockIdx.y*64, j0 = blockIdx.x*64;
  int tid = threadIdx.x;
  const float* ib = in + (long long)b*262144;
  if (tid < 66){
    int gi = i0 + tid - 1;
    float m = 0.f, iv = 0.f;
    if ((unsigned)gi < 512u){ m = Sm[b*512 + gi]; iv = Si[b*512 + gi]; }
    sms[tid] = m; sis[tid] = iv;
  }
  __syncthreads();
  for (int t = tid; t < 66*66; t += 256){
    int r = t / 66, cc = t - r*66;
    int gi = i0 + r - 1, gj = j0 + cc - 1;
    float v = 0.f;
    if ((unsigned)gi < 512u && (unsigned)gj < 512u)
      v = __expf(ib[gi*512 + gj] - sms[r]) * sis[r];
    ti[r][cc] = v;
  }
  __syncthreads();
  float w9[9], bv = b2f(bias[0]);
  #pragma unroll
  for (int d = 0; d < 9; ++d) w9[d] = b2f(w[d]);
  int ii = tid & 63;
  #pragma unroll
  for (int q = 0; q < 16; ++q){
    int jj = (tid >> 6)*16 + q;
    float acc = bv;
    #pragma unroll
    for (int di = 0; di < 3; ++di)
      #pragma unroll
      for (int dj = 0; dj < 3; ++dj)
        acc += w9[di*3+dj] * ti[ii+di][jj+dj];
    toutT[jj][ii] = f2b(acc);
  }
  __syncthreads();
  #pragma unroll
  for (int q = 0; q < 16; ++q){
    int jj = (tid >> 6)*16 + q;
    out[(long long)b*262144 + (j0+jj)*512 + i0 + (tid & 63)] = toutT[jj][tid & 63];
  }
}

// ---------- depthwise 3x3; Hbuf (b,n,c) bf16 -> T1 (b,n,c) bf16 ----------
__global__ __launch_bounds__(256) void dwconv_k(const bf16* __restrict__ H2, bf16* __restrict__ T1,
                                                const bf16* __restrict__ w, const bf16* __restrict__ bias){
  int p = blockIdx.x*256 + threadIdx.x;
  int cp = p & 255;
  int n = (p >> 8) & 1023;
  int b = p >> 18;
  int c0 = cp*2;
  int wi = n >> 5, hg = n & 31;
  float a0 = b2f(bias[c0]), a1 = b2f(bias[c0+1]);
  #pragma unroll
  for (int di = 0; di < 3; ++di){
    int gw = wi + di - 1;
    if ((unsigned)gw >= 32u) continue;
    #pragma unroll
    for (int dj = 0; dj < 3; ++dj){
      int gh = hg + dj - 1;
      if ((unsigned)gh >= 32u) continue;
      unsigned hv = *(const unsigned*)&H2[((long long)b*1024 + (gw*32+gh))*512 + c0];
      float w0 = b2f(w[c0*9 + di*3 + dj]);
      float w1 = b2f(w[(c0+1)*9 + di*3 + dj]);
      a0 += w0 * bits2f(hv & 0xffffu);
      a1 += w1 * bits2f(hv >> 16);
    }
  }
  bf16 h0 = f2b(a0), h1 = f2b(a1);
  unsigned o = ((unsigned)*(unsigned short*)&h1 << 16) | (unsigned)*(unsigned short*)&h0;
  *(unsigned*)&T1[((long long)b*1024 + n)*512 + c0] = o;
}

// ---------- fold pw bias + BN(eval), all layers ----------
__global__ void bnaff_all_k(const bf16* __restrict__ pwb, const bf16* __restrict__ g,
                            const bf16* __restrict__ bb, const bf16* __restrict__ m,
                            const bf16* __restrict__ v, float* __restrict__ BNAFF){
  int l = blockIdx.x, o = threadIdx.x;
  float s = b2f(g[l*256+o]) * rsqrtf(b2f(v[l*256+o]) + 1e-5f);
  BNAFF[l*512 + o] = s;
  BNAFF[l*512 + 256 + o] = (b2f(pwb[l*256+o]) - b2f(m[l*256+o])) * s + b2f(bb[l*256+o]);
}

// ---------- HbufT[b][c][n] = Hbuf[b][n][c] ----------
__global__ __launch_bounds__(256) void htrans_k(const bf16* __restrict__ Hb, bf16* __restrict__ HT){
  __shared__ bf16 t[64][65];
  int b = blockIdx.z;
  int n0 = blockIdx.x*64, c0 = blockIdx.y*64;
  int lane = threadIdx.x & 63, quad = threadIdx.x >> 6;
  #pragma unroll
  for (int k = 0; k < 16; ++k){
    int r = quad*16 + k;
    t[r][lane] = Hb[((long long)b*1024 + n0 + r)*512 + c0 + lane];
  }
  __syncthreads();
  #pragma unroll
  for (int k = 0; k < 16; ++k){
    int c = quad*16 + k;
    HT[(long long)b*524288 + (long long)(c0+c)*1024 + n0 + lane] = t[lane][c];
  }
}

// ---------- orchestration ----------
extern "C" void kernel_launch(void* const* d_in, const int* in_sizes, int n_in,
                              void* d_out, int out_size, void* d_ws, size_t ws_size,
                              hipStream_t stream)
{
  (void)in_sizes; (void)n_in; (void)out_size;

  const bool big = ws_size >= 207000000ull;
  const long long ATTN_SZ = big ? 33554432LL : 8388608LL;

  // ---- arena ----
  float* X     = (float*)d_ws;                    // 2,097,152 f32
  bf16*  WBsm  = (bf16*)(X + 2097152);            // 2,139,648
  bf16*  WqkvT = WBsm  + 2139648;                 // 3,145,728
  bf16*  WoutT = WqkvT + 3145728;                 // 1,048,576
  bf16*  WqsT  = WoutT + 1048576;                 // 8,388,608
  bf16*  Hbuf  = WqsT  + 8388608;                 // 2,097,152
  bf16*  HbufT = Hbuf  + 2097152;                 // 2,097,152
  bf16*  QKV   = HbufT + 2097152;                 // 6,291,456
  bf16*  Vt    = QKV   + 6291456;                 // 2,097,152
  bf16*  OUTH  = Vt    + 2097152;                 // 2,097,152  (alias ASPEC f32)
  bf16*  OUT   = OUTH  + 2097152;                 // 2,097,152
  bf16*  ATTN  = OUT   + 2097152;                 // ATTN_SZ    (alias SQK, T1, T3)
  bf16*  ATTNC = ATTN  + ATTN_SZ;                 // ATTN_SZ    (alias ASPECC_T, T2)
  float* BNAFF = (float*)(ATTNC + ATTN_SZ);       // 2048 f32
  bf16*  WR    = (bf16*)(BNAFF + 2048);           // 6144 bf16
  float* MROW  = (float*)(WR + 6144);             // 32768 f32
  float* IROW  = MROW + 32768;                    // 32768 f32
  float* SMS   = IROW + 32768;                    // 2048 f32
  float* SIS   = SMS + 2048;                      // 2048 f32
  int*   FLAG  = (int*)(SIS + 2048);

  float* ASPEC   = (float*)OUTH;
  bf16*  ASPECCT = ATTNC;
  bf16*  T1 = ATTN;
  bf16*  T3 = ATTN + 2097152;
  bf16*  T2 = ATTNC + 2097152;
  bf16*  SQK = ATTN;

  // ---- small-weight arena ----
  static const int widx[21] = {1,2,5,6,7,9,10,11,12,13,14,15,16,17,18,19,20,21,22,23,24};
  static const long long wsz[21] = {2048,2048,2048,2304,32,36,4,2048,2048,18432,2048,
                                    524288,1024,1024,1024,1024,1024,524288,2048,1048576,2048};
  WCvt21 wc;
  long long cum = 0;
  bf16* wp[21];
  for (int t = 0; t < 21; ++t){
    wc.src[t] = d_in[widx[t]];
    wc.cum[t] = cum;
    wp[t] = WBsm + cum;
    cum += wsz[t];
  }
  wc.cum[21] = cum;

  bf16 *w_ln1w = wp[0],  *w_ln1b = wp[1],  *w_bout = wp[2],  *w_spw = wp[3];
  bf16 *w_spb  = wp[4],  *w_specw= wp[5],  *w_specb= wp[6],  *w_ln2w= wp[7];
  bf16 *w_ln2b = wp[8],  *w_dww  = wp[9],  *w_dwb  = wp[10], *w_pww = wp[11];
  bf16 *w_pwb  = wp[12], *w_bng  = wp[13], *w_bnb  = wp[14], *w_bnm = wp[15];
  bf16 *w_bnv  = wp[16], *w_c1w  = wp[17], *w_c1b  = wp[18], *w_c2w = wp[19];
  bf16 *w_c2b  = wp[20];

  // ---- setup ----
  detect_k<<<1, 256, 0, stream>>>((const unsigned*)d_in[0], FLAG);
  cvt_x_k<<<8192, 256, 0, stream>>>(d_in[0], X, FLAG);
  cvt_w_k<<<(int)((cum + 255)/256), 256, 0, stream>>>(wc, WBsm, cum, FLAG);
  wtrans_k<<<dim3(8,24,4), 256, 0, stream>>>(d_in[3], WqkvT, 1536, 512, 786432LL, 786432LL, FLAG);
  wtrans_k<<<dim3(8, 8,4), 256, 0, stream>>>(d_in[4], WoutT,  512, 512, 262144LL, 262144LL, FLAG);
  wtrans_k<<<dim3(16,32,4),256, 0, stream>>>(d_in[8], WqsT,  3072,1024, 3145728LL,2097152LL, FLAG);
  bnaff_all_k<<<4, 256, 0, stream>>>(w_pwb, w_bng, w_bnb, w_bnm, w_bnv, BNAFF);
  wprep_k<<<4, 256, 0, stream>>>(w_spw, WR);

  for (int l = 0; l < 4; ++l){
    // --- spatial attention ---
    ln_k<<<4096, 256, 0, stream>>>(X, Hbuf, w_ln1w + l*512, w_ln1b + l*512);
    gmfma<4,4,bf16>(stream, 1, 4096, 1536, 512,
        Hbuf, 512, 0, WqkvT + (long long)l*786432, 512, 0, QKV, 1536, 0,
        1.f, 0, nullptr, nullptr, nullptr, nullptr, 0, Vt);
    if (big){
      gmfma_x<4,4,bf16>(stream, 32, 1024, 1024, 64,
          QKV, 1536, 64, 1572864, QKV + 512, 1536, 64, 1572864,
          ATTN, 1024, 1048576, 8388608, 0.125f);
      maxsum_k<<<dim3(1024,4), 256, 0, stream>>>(ATTN, MROW, IROW, 8388608LL);
      convNorm_k<<<dim3(2,128,4), 256, 0, stream>>>(ATTN, ATTNC, WR + l*1536, w_spb + l*8,
                                                    MROW, IROW, 8388608LL);
      gmfma_x<2,2,bf16>(stream, 32, 1024, 64, 1024,
          ATTNC, 1024, 1048576, 8388608, Vt, 1024, 65536, 524288,
          OUTH, 512, 64, 524288);
    } else {
      for (int b = 0; b < 4; ++b){
        bf16* qkvb = QKV + (long long)b*1572864;
        gmfma<4,4,bf16>(stream, 8, 1024, 1024, 64,
            qkvb, 1536, 64, qkvb + 512, 1536, 64, ATTN, 1024, 1048576, 0.125f);
        maxsum_k<<<dim3(1024,1), 256, 0, stream>>>(ATTN, MROW, IROW, 8388608LL);
        convNorm_k<<<dim3(2,128,1), 256, 0, stream>>>(ATTN, ATTNC, WR + l*1536, w_spb + l*8,
                                                      MROW, IROW, 8388608LL);
        gmfma<2,2,bf16>(stream, 8, 1024, 64, 1024,
            ATTNC, 1024, 1048576, Vt + (long long)b*524288, 1024, 65536,
            OUTH + (long long)b*524288, 512, 64);
      }
    }
    gmfma<2,2,bf16>(stream, 1, 4096, 512, 512,
        OUTH, 512, 0, WoutT + (long long)l*262144, 512, 0, OUT, 512, 0,
        1.f, 0, w_bout + l*512);
    // --- spectral attention ---
    htrans_k<<<dim3(16,8,4), 256, 0, stream>>>(Hbuf, HbufT);
    gmfma<4,4,bf16>(stream, 4, 512, 2048, 1024,
        HbufT, 1024, 524288, WqsT + (long long)l*2097152, 1024, 0, SQK, 2048, 1048576);
    gmfma<2,2,float>(stream, 4, 512, 512, 1024,
        SQK, 2048, 1048576, SQK + 1024, 2048, 1048576, ASPEC, 512, 262144, 0.125f);
    spec_ms_k<<<2048, 256, 0, stream>>>(ASPEC, SMS, SIS);
    conv_spec_k<<<dim3(8,8,4), 256, 0, stream>>>(ASPEC, ASPECCT, w_specw + l*9, w_specb + l,
                                                 SMS, SIS);
    gmfma<2,2,float>(stream, 4, 1024, 512, 512,
        OUT, 512, 524288, ASPECCT, 512, 262144, X, 512, 524288, 1.f, 1);
    // --- conv FFN ---
    ln_k<<<4096, 256, 0, stream>>>(X, Hbuf, w_ln2w + l*512, w_ln2b + l*512);
    dwconv_k<<<4096, 256, 0, stream>>>(Hbuf, T1, w_dww + l*4608, w_dwb + l*512);
    gmfma<2,2,bf16>(stream, 4, 1024, 256, 512,
        T1, 512, 524288, w_pww + (long long)l*131072, 512, 0, T2, 256, 262144,
        1.f, 0, nullptr, BNAFF + l*512, BNAFF + l*512 + 256);
    gmfma<2,2,bf16>(stream, 4, 1024, 512, 256,
        T2, 256, 262144, w_c1w + (long long)l*131072, 256, 0, T3, 512, 524288,
        1.f, 0, w_c1b + l*512, nullptr, nullptr, nullptr, 1);
    gmfma<2,2,float>(stream, 4, 1024, 512, 512,
        T3, 512, 524288, w_c2w + (long long)l*262144, 512, 0, X, 512, 524288,
        1.f, 1, w_c2b + l*512, nullptr, nullptr, Hbuf, 1);
  }

  store_out_k<<<8192, 256, 0, stream>>>(X, d_out, FLAG);
}

// Round 10
// 1215.292 us; speedup vs baseline: 21.4467x; 1.0142x over previous
//
#include <hip/hip_runtime.h>
#include <hip/hip_bf16.h>

typedef __hip_bfloat16 bf16;
typedef __attribute__((ext_vector_type(8))) short bf16x8;
typedef __attribute__((ext_vector_type(4))) float f32x4;

// ---------- helpers ----------
__device__ __forceinline__ float b2f(bf16 v){ return __bfloat162float(v); }
__device__ __forceinline__ bf16 f2b(float v){ return __float2bfloat16(v); }
__device__ __forceinline__ float bits2f(unsigned u){ return __uint_as_float(u << 16); }
__device__ __forceinline__ unsigned short f2bits(float v){ bf16 t = __float2bfloat16(v); return *(unsigned short*)&t; }

__device__ __forceinline__ float gelu_f(float x){
  return 0.5f * x * (1.f + erff(x * 0.7071067811865475f));
}

__device__ __forceinline__ void gload_lds(const void* g, void* l){
  __builtin_amdgcn_global_load_lds((const __attribute__((address_space(1))) void*)g,
                                   (__attribute__((address_space(3))) void*)l, 16, 0, 0);
}

template<bool MAX>
__device__ __forceinline__ float block_reduce(float v){
  __shared__ float s[4];
  #pragma unroll
  for (int o = 32; o > 0; o >>= 1){
    float t = __shfl_down(v, o, 64);
    v = MAX ? fmaxf(v, t) : (v + t);
  }
  int lane = threadIdx.x & 63, w = threadIdx.x >> 6;
  __syncthreads();
  if (lane == 0) s[w] = v;
  __syncthreads();
  return MAX ? fmaxf(fmaxf(s[0], s[1]), fmaxf(s[2], s[3]))
             : (s[0] + s[1] + s[2] + s[3]);
}

// ---------- dtype detect + converters ----------
__global__ void detect_k(const unsigned* __restrict__ x, int* __restrict__ flag){
  __shared__ int cnt[256];
  int tid = threadIdx.x;
  int c = 0;
  for (int i = tid; i < 4096; i += 256){
    unsigned h = x[i] & 0xffffu;
    int e = (int)((h >> 7) & 0xff);
    if (h == 0u || (e >= 100 && e <= 133)) c++;
  }
  cnt[tid] = c;
  __syncthreads();
  for (int o = 128; o > 0; o >>= 1){ if (tid < o) cnt[tid] += cnt[tid+o]; __syncthreads(); }
  if (tid == 0) *flag = (cnt[0] < 2048) ? 1 : 0;
}

__global__ __launch_bounds__(256) void cvt_x_k(const void* __restrict__ src,
                                               float* __restrict__ X,
                                               const int* __restrict__ flag){
  int p = blockIdx.x*256 + threadIdx.x;
  X[p] = (*flag) ? ((const float*)src)[p]
                 : __bfloat162float(((const bf16*)src)[p]);
}

struct WCvt21 { const void* src[21]; long long cum[22]; };

__global__ __launch_bounds__(256) void cvt_w_k(WCvt21 a, bf16* __restrict__ WB,
                                               long long total, const int* __restrict__ flag){
  long long i = (long long)blockIdx.x*256 + threadIdx.x;
  if (i >= total) return;
  int t = 0;
  while (a.cum[t+1] <= i) t++;
  long long e = i - a.cum[t];
  WB[i] = (*flag) ? __float2bfloat16(((const float*)a.src[t])[e])
                  : ((const bf16*)a.src[t])[e];
}

// transpose + convert weight: dst[z][c][r] = src[z][r][c], tiles 64x64
__global__ __launch_bounds__(256) void wtrans_k(const void* __restrict__ src, bf16* __restrict__ dst,
                                                int ld_src, int ldd, long long sSrc, long long sDst,
                                                const int* __restrict__ flag){
  __shared__ bf16 t[64][65];
  int z = blockIdx.z;
  int r0 = blockIdx.x*64, c0 = blockIdx.y*64;
  int lane = threadIdx.x & 63, quad = threadIdx.x >> 6;
  const float* sf = (const float*)src;
  const bf16* sb = (const bf16*)src;
  int fl = *flag;
  #pragma unroll
  for (int k = 0; k < 16; ++k){
    int r = quad*16 + k;
    long long idx = z*sSrc + (long long)(r0+r)*ld_src + c0 + lane;
    float v = fl ? sf[idx] : b2f(sb[idx]);
    t[r][lane] = f2b(v);
  }
  __syncthreads();
  #pragma unroll
  for (int k = 0; k < 16; ++k){
    int c = quad*16 + k;
    dst[z*sDst + (long long)(c0+c)*ldd + r0 + lane] = t[lane][c];
  }
}

// conv-attn weight shuffle: Wr[l][16][96]; Wr[l][ho][tap*8+hi] = spw[l][ho][hi][tap], 0-padded
__global__ void wprep_k(const bf16* __restrict__ spw, bf16* __restrict__ Wr){
  int l = blockIdx.x;
  for (int t = threadIdx.x; t < 1536; t += 256){
    int ho = t / 96, k = t - ho*96;
    float v = 0.f;
    if (ho < 8 && k < 72){
      int tap = k >> 3, hi = k & 7;
      v = b2f(spw[l*576 + ho*72 + hi*9 + tap]);
    }
    Wr[l*1536 + t] = f2b(v);
  }
}

__global__ __launch_bounds__(256) void store_out_k(const float* __restrict__ X,
                                                   void* __restrict__ out,
                                                   const int* __restrict__ flag){
  int p = blockIdx.x*256 + threadIdx.x;
  if (*flag) ((float*)out)[p] = X[p];
  else       ((bf16*)out)[p] = f2b(X[p]);
}

__global__ __launch_bounds__(256) void zero_k(float* __restrict__ p, int n){
  int i = blockIdx.x*256 + threadIdx.x;
  if (i < n) p[i] = 0.f;
}

// ---------- MFMA GEMM ----------
// C[z] = epi( alpha * A(MxK,row) x Bt(NxK,row)^T ); z decomposes as (z&7, z>>3)
// EXP=1: C = exp(alpha*acc) (bf16/f32), row sums atomically added to srow.
template<int MF, int NF, typename TC, int EXP>
__global__ __launch_bounds__(256) void gmfma_k(
    int M, int N, int K,
    const bf16* __restrict__ A, int lda, long long sA, long long sA2,
    const bf16* __restrict__ Bt, int ldb, long long sB, long long sB2,
    TC* __restrict__ C, int ldc, long long sC, long long sC2,
    float alpha, int beta,
    const bf16* __restrict__ bias_n,
    const float* __restrict__ scale_n,
    const float* __restrict__ shift_n,
    const bf16* __restrict__ addF,
    int act,
    bf16* __restrict__ vt,
    float* __restrict__ srow, long long szl, long long szh, long long sgm)
{
  constexpr int BM = MF*32, BN = NF*32;
  constexpr int CHA = BM/16, CH = (BM+BN)/16;
  static_assert(CH % 4 == 0, "chunks must divide among 4 waves");
  __shared__ bf16 Asm[BM][32];
  __shared__ bf16 Bsm[BN][32];
  const int tid = threadIdx.x;
  const int lane = tid & 63, wid = tid >> 6;
  const int wm = wid >> 1, wn = wid & 1;
  const int m0 = blockIdx.y*BM, n0 = blockIdx.x*BN;
  const int z = blockIdx.z;
  const long long zl = z & 7, zh = z >> 3;
  const bf16* Ab = A + zl*sA + zh*sA2;
  const bf16* Bb = Bt + zl*sB + zh*sB2;
  TC* Cb = C + zl*sC + zh*sC2;
  const bf16* Fb = addF ? addF + zl*sC + zh*sC2 : nullptr;

  f32x4 acc[MF][NF];
  f32x4 zero = {0.f, 0.f, 0.f, 0.f};
  #pragma unroll
  for (int m = 0; m < MF; ++m)
    #pragma unroll
    for (int n = 0; n < NF; ++n) acc[m][n] = zero;

  const int rchunk = lane >> 2;
  const int kchunk = (lane & 3) * 8;
  const int row16 = lane & 15, kq = (lane >> 4) * 8;

  for (int k0 = 0; k0 < K; k0 += 32){
    #pragma unroll
    for (int cc = 0; cc < CH/4; ++cc){
      int c = wid + cc*4;
      if (c < CHA){
        int row = c*16 + rchunk;
        gload_lds(Ab + (long long)(m0+row)*lda + k0 + kchunk, &Asm[c*16][0]);
      } else {
        int row = (c-CHA)*16 + rchunk;
        gload_lds(Bb + (long long)(n0+row)*ldb + k0 + kchunk, &Bsm[(c-CHA)*16][0]);
      }
    }
    __syncthreads();
    bf16x8 af[MF], bfr[NF];
    #pragma unroll
    for (int m = 0; m < MF; ++m)
      af[m] = *(const bf16x8*)&Asm[wm*(MF*16) + m*16 + row16][kq];
    #pragma unroll
    for (int n = 0; n < NF; ++n)
      bfr[n] = *(const bf16x8*)&Bsm[wn*(NF*16) + n*16 + row16][kq];
    #pragma unroll
    for (int m = 0; m < MF; ++m)
      #pragma unroll
      for (int n = 0; n < NF; ++n)
        acc[m][n] = __builtin_amdgcn_mfma_f32_16x16x32_bf16(af[m], bfr[n], acc[m][n], 0, 0, 0);
    __syncthreads();
  }

  if constexpr (EXP){
    // e = exp(alpha*acc); store; butterfly row-sum over lane&15; atomicAdd per row.
    #pragma unroll
    for (int m = 0; m < MF; ++m){
      int gmb = m0 + wm*(MF*16) + m*16 + (lane >> 4)*4;
      float rowsum[4] = {0.f, 0.f, 0.f, 0.f};
      #pragma unroll
      for (int n = 0; n < NF; ++n){
        int gn = n0 + wn*(NF*16) + n*16 + row16;
        #pragma unroll
        for (int r = 0; r < 4; ++r){
          float e = __expf(acc[m][n][r] * alpha);
          long long idx = (long long)(gmb + r)*ldc + gn;
          if constexpr (__is_same(TC, float)) Cb[idx] = e; else Cb[idx] = f2b(e);
          rowsum[r] += e;
        }
      }
      #pragma unroll
      for (int r = 0; r < 4; ++r){
        float s = rowsum[r];
        #pragma unroll
        for (int o = 1; o < 16; o <<= 1) s += __shfl_xor(s, o, 64);
        if ((lane & 15) == 0)
          atomicAdd(&srow[zl*szl + zh*szh + (long long)(gmb + r)*sgm], s);
      }
    }
    return;
  }

  #pragma unroll
  for (int m = 0; m < MF; ++m){
    #pragma unroll
    for (int n = 0; n < NF; ++n){
      int gn = n0 + wn*(NF*16) + n*16 + row16;
      float bn_ = bias_n ? b2f(bias_n[gn]) : 0.f;
      float sc = scale_n ? scale_n[gn] : 1.f;
      float sh = shift_n ? shift_n[gn] : 0.f;
      int gmb = m0 + wm*(MF*16) + m*16 + (lane >> 4)*4;
      float vals[4];
      #pragma unroll
      for (int r = 0; r < 4; ++r){
        int gm = gmb + r;
        float v = acc[m][n][r] * alpha + bn_;
        v = v * sc + sh;
        if (act) v = gelu_f(v);
        long long idx = (long long)gm*ldc + gn;
        if (Fb) v += b2f(Fb[idx]);
        if (beta){
          float old;
          if constexpr (__is_same(TC, float)) old = Cb[idx]; else old = b2f(Cb[idx]);
          v += old;
        }
        if constexpr (__is_same(TC, float)) Cb[idx] = v; else Cb[idx] = f2b(v);
        vals[r] = v;
      }
      if (vt && gn >= 1024){
        int h = (gn - 1024) >> 6, d = (gn - 1024) & 63;
        int bb = gmb >> 10, nn = gmb & 1023;
        ushort4 o;
        o.x = f2bits(vals[0]); o.y = f2bits(vals[1]);
        o.z = f2bits(vals[2]); o.w = f2bits(vals[3]);
        *(ushort4*)&vt[(((long long)bb*8 + h)*64 + d)*1024 + nn] = o;
      }
    }
  }
}

template<int MF, int NF, typename TC>
static void gmfma_x(hipStream_t st, int z, int M, int N, int K,
                    const bf16* A, int lda, long long sA, long long sA2,
                    const bf16* Bt, int ldb, long long sB, long long sB2,
                    TC* C, int ldc, long long sC, long long sC2,
                    float alpha = 1.f, int beta = 0,
                    const bf16* bias_n = nullptr,
                    const float* scale_n = nullptr, const float* shift_n = nullptr,
                    const bf16* addF = nullptr, int act = 0, bf16* vt = nullptr)
{
  dim3 g(N/(NF*32), M/(MF*32), z);
  gmfma_k<MF,NF,TC,0><<<g, 256, 0, st>>>(M,N,K,A,lda,sA,sA2,Bt,ldb,sB,sB2,C,ldc,sC,sC2,
                                         alpha,beta,bias_n,scale_n,shift_n,addF,act,vt,
                                         nullptr,0,0,0);
}

template<int MF, int NF, typename TC>
static void gmfma(hipStream_t st, int z, int M, int N, int K,
                  const bf16* A, int lda, long long sA,
                  const bf16* Bt, int ldb, long long sB,
                  TC* C, int ldc, long long sC,
                  float alpha = 1.f, int beta = 0,
                  const bf16* bias_n = nullptr,
                  const float* scale_n = nullptr, const float* shift_n = nullptr,
                  const bf16* addF = nullptr, int act = 0, bf16* vt = nullptr)
{
  gmfma_x<MF,NF,TC>(st, z, M, N, K, A, lda, sA, 8*sA, Bt, ldb, sB, 8*sB,
                    C, ldc, sC, 8*sC, alpha, beta, bias_n, scale_n, shift_n, addF, act, vt);
}

template<int MF, int NF, typename TC>
static void gmfma_exp(hipStream_t st, int z, int M, int N, int K,
                      const bf16* A, int lda, long long sA, long long sA2,
                      const bf16* Bt, int ldb, long long sB, long long sB2,
                      TC* C, int ldc, long long sC, long long sC2,
                      float alpha,
                      float* srow, long long szl, long long szh, long long sgm)
{
  dim3 g(N/(NF*32), M/(MF*32), z);
  gmfma_k<MF,NF,TC,1><<<g, 256, 0, st>>>(M,N,K,A,lda,sA,sA2,Bt,ldb,sB,sB2,C,ldc,sC,sC2,
                                         alpha,0,nullptr,nullptr,nullptr,nullptr,0,nullptr,
                                         srow,szl,szh,sgm);
}

// ---------- LayerNorm fp32 -> bf16 ----------
__global__ __launch_bounds__(256) void ln_k(const float* __restrict__ X, bf16* __restrict__ Y,
                                            const bf16* __restrict__ w, const bf16* __restrict__ b){
  long long row = blockIdx.x;
  const float* x = X + row*512;
  bf16* y = Y + row*512;
  int tid = threadIdx.x;
  float v0 = x[tid], v1 = x[tid+256];
  float mean = block_reduce<false>(v0+v1) * (1.f/512.f);
  float msq  = block_reduce<false>(v0*v0+v1*v1) * (1.f/512.f);
  float var = msq - mean*mean;
  float rs = rsqrtf(var + 1e-5f);
  y[tid]     = f2b((v0-mean)*rs*b2f(w[tid])     + b2f(b[tid]));
  y[tid+256] = f2b((v1-mean)*rs*b2f(w[tid+256]) + b2f(b[tid+256]));
}

// ---------- fused normalize + 3x3 MFMA conv (input = exp scores, SROW = row sums) ----------
// Sp[b][h][i][j] planar exp-scores -> Pout[b][h][i][j] conv'd softmaxed map.
// grid (4 j-quarters, 128 i-tiles, NB); block 256; 8-row tiles; 4 chunks of 64 cols.
__device__ __forceinline__ int csw(int col){ return col ^ ((col >> 3) & 7); }

__global__ __launch_bounds__(256) void convNorm_k(
    const bf16* __restrict__ Sp, bf16* __restrict__ Pout,
    const bf16* __restrict__ Wr, const bf16* __restrict__ bias,
    const float* __restrict__ Srow,
    long long bstride)
{
  __shared__ bf16 tile[10][66][8];
  __shared__ float irow[10][8];
  long long b = blockIdx.z;
  int i0 = blockIdx.y*8;
  int jh0 = blockIdx.x*256;
  int tid = threadIdx.x;
  const bf16* src = Sp + b*bstride;

  if (tid < 80){
    int r = tid >> 3, h = tid & 7;
    int gi = i0 + r - 1;
    float iv = 0.f;
    if ((unsigned)gi < 1024u) iv = 1.f / Srow[(b*1024 + gi)*8 + h];
    irow[r][h] = iv;
  }

  int lane = tid & 63, wid = tid >> 6;
  int row16 = lane & 15, q = lane >> 4;
  bf16x8 wf0 = *(const bf16x8*)&Wr[row16*96 +  0 + q*8];
  bf16x8 wf1 = *(const bf16x8*)&Wr[row16*96 + 32 + q*8];
  bf16x8 wf2 = *(const bf16x8*)&Wr[row16*96 + 64 + q*8];
  float bv = (row16 < 8) ? b2f(bias[row16]) : 0.f;

  for (int c = 0; c < 4; ++c){
    int base = jh0 + c*64;
    __syncthreads();   // protects irow (c==0) / prev-chunk tile reads (c>0)
    // main staging: 320 units (10 rows x 4 h-pairs x 8 segs), aligned 16B loads
    for (int t = tid; t < 320; t += 256){
      int row = t >> 5, rem = t & 31;
      int hp = rem >> 3, seg = rem & 7;
      int gi = i0 + row - 1;
      int g0 = base + seg*8;
      unsigned ov[8];
      if ((unsigned)gi < 1024u){
        const bf16* p0 = src + (long long)(2*hp)*1048576 + (long long)gi*1024 + g0;
        bf16x8 a0 = *(const bf16x8*)p0;
        bf16x8 a1 = *(const bf16x8*)(p0 + 1048576);
        float i0v = irow[row][2*hp];
        float i1v = irow[row][2*hp+1];
        #pragma unroll
        for (int k = 0; k < 8; ++k){
          float e0 = bits2f((unsigned)(unsigned short)a0[k]) * i0v;
          float e1 = bits2f((unsigned)(unsigned short)a1[k]) * i1v;
          ov[k] = (unsigned)f2bits(e0) | ((unsigned)f2bits(e1) << 16);
        }
      } else {
        #pragma unroll
        for (int k = 0; k < 8; ++k) ov[k] = 0u;
      }
      #pragma unroll
      for (int k = 0; k < 8; ++k)
        *(unsigned*)&tile[row][csw(1 + seg*8 + k)][2*hp] = ov[k];
    }
    // halo cols 0 (base-1) and 65 (base+64): 40 units (row,hp), L1/L2 hits
    if (tid < 40){
      int row = tid >> 2, hp = tid & 3;
      int gi = i0 + row - 1;
      unsigned L = 0u, R = 0u;
      if ((unsigned)gi < 1024u){
        long long rb = (long long)gi*1024;
        int cl = base - 1, cr = base + 64;
        float i0v = irow[row][2*hp];
        float i1v = irow[row][2*hp+1];
        if (cl >= 0){
          float e0 = b2f(src[(long long)(2*hp)*1048576 + rb + cl]) * i0v;
          float e1 = b2f(src[(long long)(2*hp+1)*1048576 + rb + cl]) * i1v;
          L = (unsigned)f2bits(e0) | ((unsigned)f2bits(e1) << 16);
        }
        if (cr < 1024){
          float e0 = b2f(src[(long long)(2*hp)*1048576 + rb + cr]) * i0v;
          float e1 = b2f(src[(long long)(2*hp+1)*1048576 + rb + cr]) * i1v;
          R = (unsigned)f2bits(e0) | ((unsigned)f2bits(e1) << 16);
        }
      }
      *(unsigned*)&tile[row][csw(0)][2*hp] = L;
      *(unsigned*)&tile[row][csw(65)][2*hp] = R;
    }
    __syncthreads();
    // compute: per wave 2 rr x 3 ks x 4 mf MFMA
    #pragma unroll
    for (int rr = 0; rr < 2; ++rr){
      int ii = rr*4 + wid;
      f32x4 zero = {0.f,0.f,0.f,0.f};
      f32x4 acc[4] = {zero,zero,zero,zero};
      #pragma unroll
      for (int ks = 0; ks < 3; ++ks){
        int tap = ks*4 + q;
        int tcl = tap > 8 ? 0 : tap;
        int di = tcl/3, dj = tcl - di*3;
        bf16x8 wsel = ks==0 ? wf0 : (ks==1 ? wf1 : wf2);
        #pragma unroll
        for (int mf = 0; mf < 4; ++mf){
          bf16x8 af = *(const bf16x8*)&tile[ii+di][csw(mf*16 + row16 + dj)][0];
          acc[mf] = __builtin_amdgcn_mfma_f32_16x16x32_bf16(af, wsel, acc[mf], 0, 0, 0);
        }
      }
      if (row16 < 8){
        bf16* dst = Pout + b*bstride + (long long)row16*1048576 + (long long)(i0+ii)*1024;
        #pragma unroll
        for (int mf = 0; mf < 4; ++mf){
          int j = base + mf*16 + q*4;
          ushort4 o;
          o.x = f2bits(acc[mf][0] + bv);
          o.y = f2bits(acc[mf][1] + bv);
          o.z = f2bits(acc[mf][2] + bv);
          o.w = f2bits(acc[mf][3] + bv);
          *(ushort4*)&dst[j] = o;
        }
      }
    }
  }
}

// ---------- 3x3 conv, 1 ch, normalize-during-staging, bf16 TRANSPOSED out ----------
// in = exp aspec (f32), SSROW = row sums.
__global__ __launch_bounds__(256) void conv_spec_k(const float* __restrict__ in, bf16* __restrict__ out,
                                                   const bf16* __restrict__ w, const bf16* __restrict__ bias,
                                                   const float* __restrict__ SSrow){
  __shared__ float ti[66][67];
  __shared__ bf16 toutT[64][65];
  __shared__ float sis[66];
  int b = blockIdx.z;
  int i0 = blockIdx.y*64, j0 = blockIdx.x*64;
  int tid = threadIdx.x;
  const float* ib = in + (long long)b*262144;
  if (tid < 66){
    int gi = i0 + tid - 1;
    float iv = 0.f;
    if ((unsigned)gi < 512u) iv = 1.f / SSrow[b*512 + gi];
    sis[tid] = iv;
  }
  __syncthreads();
  for (int t = tid; t < 66*66; t += 256){
    int r = t / 66, cc = t - r*66;
    int gi = i0 + r - 1, gj = j0 + cc - 1;
    float v = 0.f;
    if ((unsigned)gi < 512u && (unsigned)gj < 512u)
      v = ib[gi*512 + gj] * sis[r];
    ti[r][cc] = v;
  }
  __syncthreads();
  float w9[9], bv = b2f(bias[0]);
  #pragma unroll
  for (int d = 0; d < 9; ++d) w9[d] = b2f(w[d]);
  int ii = tid & 63;
  #pragma unroll
  for (int q = 0; q < 16; ++q){
    int jj = (tid >> 6)*16 + q;
    float acc = bv;
    #pragma unroll
    for (int di = 0; di < 3; ++di)
      #pragma unroll
      for (int dj = 0; dj < 3; ++dj)
        acc += w9[di*3+dj] * ti[ii+di][jj+dj];
    toutT[jj][ii] = f2b(acc);
  }
  __syncthreads();
  #pragma unroll
  for (int q = 0; q < 16; ++q){
    int jj = (tid >> 6)*16 + q;
    out[(long long)b*262144 + (j0+jj)*512 + i0 + (tid & 63)] = toutT[jj][tid & 63];
  }
}

// ---------- depthwise 3x3; Hbuf (b,n,c) bf16 -> T1 (b,n,c) bf16 ----------
__global__ __launch_bounds__(256) void dwconv_k(const bf16* __restrict__ H2, bf16* __restrict__ T1,
                                                const bf16* __restrict__ w, const bf16* __restrict__ bias){
  int p = blockIdx.x*256 + threadIdx.x;
  int cp = p & 255;
  int n = (p >> 8) & 1023;
  int b = p >> 18;
  int c0 = cp*2;
  int wi = n >> 5, hg = n & 31;
  float a0 = b2f(bias[c0]), a1 = b2f(bias[c0+1]);
  #pragma unroll
  for (int di = 0; di < 3; ++di){
    int gw = wi + di - 1;
    if ((unsigned)gw >= 32u) continue;
    #pragma unroll
    for (int dj = 0; dj < 3; ++dj){
      int gh = hg + dj - 1;
      if ((unsigned)gh >= 32u) continue;
      unsigned hv = *(const unsigned*)&H2[((long long)b*1024 + (gw*32+gh))*512 + c0];
      float w0 = b2f(w[c0*9 + di*3 + dj]);
      float w1 = b2f(w[(c0+1)*9 + di*3 + dj]);
      a0 += w0 * bits2f(hv & 0xffffu);
      a1 += w1 * bits2f(hv >> 16);
    }
  }
  bf16 h0 = f2b(a0), h1 = f2b(a1);
  unsigned o = ((unsigned)*(unsigned short*)&h1 << 16) | (unsigned)*(unsigned short*)&h0;
  *(unsigned*)&T1[((long long)b*1024 + n)*512 + c0] = o;
}

// ---------- fold pw bias + BN(eval), all layers ----------
__global__ void bnaff_all_k(const bf16* __restrict__ pwb, const bf16* __restrict__ g,
                            const bf16* __restrict__ bb, const bf16* __restrict__ m,
                            const bf16* __restrict__ v, float* __restrict__ BNAFF){
  int l = blockIdx.x, o = threadIdx.x;
  float s = b2f(g[l*256+o]) * rsqrtf(b2f(v[l*256+o]) + 1e-5f);
  BNAFF[l*512 + o] = s;
  BNAFF[l*512 + 256 + o] = (b2f(pwb[l*256+o]) - b2f(m[l*256+o])) * s + b2f(bb[l*256+o]);
}

// ---------- HbufT[b][c][n] = Hbuf[b][n][c] ----------
__global__ __launch_bounds__(256) void htrans_k(const bf16* __restrict__ Hb, bf16* __restrict__ HT){
  __shared__ bf16 t[64][65];
  int b = blockIdx.z;
  int n0 = blockIdx.x*64, c0 = blockIdx.y*64;
  int lane = threadIdx.x & 63, quad = threadIdx.x >> 6;
  #pragma unroll
  for (int k = 0; k < 16; ++k){
    int r = quad*16 + k;
    t[r][lane] = Hb[((long long)b*1024 + n0 + r)*512 + c0 + lane];
  }
  __syncthreads();
  #pragma unroll
  for (int k = 0; k < 16; ++k){
    int c = quad*16 + k;
    HT[(long long)b*524288 + (long long)(c0+c)*1024 + n0 + lane] = t[lane][c];
  }
}

// ---------- orchestration ----------
extern "C" void kernel_launch(void* const* d_in, const int* in_sizes, int n_in,
                              void* d_out, int out_size, void* d_ws, size_t ws_size,
                              hipStream_t stream)
{
  (void)in_sizes; (void)n_in; (void)out_size;

  const bool big = ws_size >= 207000000ull;
  const long long ATTN_SZ = big ? 33554432LL : 8388608LL;

  // ---- arena ----
  float* X     = (float*)d_ws;                    // 2,097,152 f32
  bf16*  WBsm  = (bf16*)(X + 2097152);            // 2,139,648
  bf16*  WqkvT = WBsm  + 2139648;                 // 3,145,728
  bf16*  WoutT = WqkvT + 3145728;                 // 1,048,576
  bf16*  WqsT  = WoutT + 1048576;                 // 8,388,608
  bf16*  Hbuf  = WqsT  + 8388608;                 // 2,097,152
  bf16*  HbufT = Hbuf  + 2097152;                 // 2,097,152
  bf16*  QKV   = HbufT + 2097152;                 // 6,291,456
  bf16*  Vt    = QKV   + 6291456;                 // 2,097,152
  bf16*  OUTH  = Vt    + 2097152;                 // 2,097,152  (alias ASPEC f32)
  bf16*  OUT   = OUTH  + 2097152;                 // 2,097,152
  bf16*  ATTN  = OUT   + 2097152;                 // ATTN_SZ    (alias SQK, T1, T3)
  bf16*  ATTNC = ATTN  + ATTN_SZ;                 // ATTN_SZ    (alias ASPECC_T, T2)
  float* BNAFF = (float*)(ATTNC + ATTN_SZ);       // 2048 f32
  bf16*  WR    = (bf16*)(BNAFF + 2048);           // 6144 bf16
  float* SROW  = (float*)(WR + 6144);             // 32768 f32 (attn row sums)
  float* SSROW = SROW + 32768;                    // 2048 f32 (spectral row sums)
  int*   FLAG  = (int*)(SSROW + 2048);

  float* ASPEC   = (float*)OUTH;
  bf16*  ASPECCT = ATTNC;
  bf16*  T1 = ATTN;
  bf16*  T3 = ATTN + 2097152;
  bf16*  T2 = ATTNC + 2097152;
  bf16*  SQK = ATTN;

  // ---- small-weight arena ----
  static const int widx[21] = {1,2,5,6,7,9,10,11,12,13,14,15,16,17,18,19,20,21,22,23,24};
  static const long long wsz[21] = {2048,2048,2048,2304,32,36,4,2048,2048,18432,2048,
                                    524288,1024,1024,1024,1024,1024,524288,2048,1048576,2048};
  WCvt21 wc;
  long long cum = 0;
  bf16* wp[21];
  for (int t = 0; t < 21; ++t){
    wc.src[t] = d_in[widx[t]];
    wc.cum[t] = cum;
    wp[t] = WBsm + cum;
    cum += wsz[t];
  }
  wc.cum[21] = cum;

  bf16 *w_ln1w = wp[0],  *w_ln1b = wp[1],  *w_bout = wp[2],  *w_spw = wp[3];
  bf16 *w_spb  = wp[4],  *w_specw= wp[5],  *w_specb= wp[6],  *w_ln2w= wp[7];
  bf16 *w_ln2b = wp[8],  *w_dww  = wp[9],  *w_dwb  = wp[10], *w_pww = wp[11];
  bf16 *w_pwb  = wp[12], *w_bng  = wp[13], *w_bnb  = wp[14], *w_bnm = wp[15];
  bf16 *w_bnv  = wp[16], *w_c1w  = wp[17], *w_c1b  = wp[18], *w_c2w = wp[19];
  bf16 *w_c2b  = wp[20];

  // ---- setup ----
  detect_k<<<1, 256, 0, stream>>>((const unsigned*)d_in[0], FLAG);
  cvt_x_k<<<8192, 256, 0, stream>>>(d_in[0], X, FLAG);
  cvt_w_k<<<(int)((cum + 255)/256), 256, 0, stream>>>(wc, WBsm, cum, FLAG);
  wtrans_k<<<dim3(8,24,4), 256, 0, stream>>>(d_in[3], WqkvT, 1536, 512, 786432LL, 786432LL, FLAG);
  wtrans_k<<<dim3(8, 8,4), 256, 0, stream>>>(d_in[4], WoutT,  512, 512, 262144LL, 262144LL, FLAG);
  wtrans_k<<<dim3(16,32,4),256, 0, stream>>>(d_in[8], WqsT,  3072,1024, 3145728LL,2097152LL, FLAG);
  bnaff_all_k<<<4, 256, 0, stream>>>(w_pwb, w_bng, w_bnb, w_bnm, w_bnv, BNAFF);
  wprep_k<<<4, 256, 0, stream>>>(w_spw, WR);

  for (int l = 0; l < 4; ++l){
    zero_k<<<136, 256, 0, stream>>>(SROW, 34816);   // SROW + SSROW contiguous
    // --- spatial attention ---
    ln_k<<<4096, 256, 0, stream>>>(X, Hbuf, w_ln1w + l*512, w_ln1b + l*512);
    gmfma<4,4,bf16>(stream, 1, 4096, 1536, 512,
        Hbuf, 512, 0, WqkvT + (long long)l*786432, 512, 0, QKV, 1536, 0,
        1.f, 0, nullptr, nullptr, nullptr, nullptr, 0, Vt);
    if (big){
      // srow[(b*1024+i)*8+h]: zl=h -> stride 1... wait, NO: index = h*szl + b*szh + i*sgm
      // need h*1 + b*8192 + i*8  =>  szl=1, szh=8192, sgm=8.
      gmfma_exp<4,4,bf16>(stream, 32, 1024, 1024, 64,
          QKV, 1536, 64, 1572864, QKV + 512, 1536, 64, 1572864,
          ATTN, 1024, 1048576, 8388608, 0.125f,
          SROW, 1, 8192, 8);
      convNorm_k<<<dim3(4,128,4), 256, 0, stream>>>(ATTN, ATTNC, WR + l*1536, w_spb + l*8,
                                                    SROW, 8388608LL);
      gmfma_x<2,2,bf16>(stream, 32, 1024, 64, 1024,
          ATTNC, 1024, 1048576, 8388608, Vt, 1024, 65536, 524288,
          OUTH, 512, 64, 524288);
    } else {
      for (int b = 0; b < 4; ++b){
        bf16* qkvb = QKV + (long long)b*1572864;
        gmfma_exp<4,4,bf16>(stream, 8, 1024, 1024, 64,
            qkvb, 1536, 64, 8*64, qkvb + 512, 1536, 64, 8*64,
            ATTN, 1024, 1048576, 8*1048576, 0.125f,
            SROW + b*8192, 1, 0, 8);
        convNorm_k<<<dim3(4,128,1), 256, 0, stream>>>(ATTN, ATTNC, WR + l*1536, w_spb + l*8,
                                                      SROW + b*8192, 8388608LL);
        gmfma<2,2,bf16>(stream, 8, 1024, 64, 1024,
            ATTNC, 1024, 1048576, Vt + (long long)b*524288, 1024, 65536,
            OUTH + (long long)b*524288, 512, 64);
      }
    }
    gmfma<2,2,bf16>(stream, 1, 4096, 512, 512,
        OUTH, 512, 0, WoutT + (long long)l*262144, 512, 0, OUT, 512, 0,
        1.f, 0, w_bout + l*512);
    // --- spectral attention ---
    htrans_k<<<dim3(16,8,4), 256, 0, stream>>>(Hbuf, HbufT);
    gmfma<4,4,bf16>(stream, 4, 512, 2048, 1024,
        HbufT, 1024, 524288, WqsT + (long long)l*2097152, 1024, 0, SQK, 2048, 1048576);
    gmfma_exp<2,2,float>(stream, 4, 512, 512, 1024,
        SQK, 2048, 1048576, 8*1048576, SQK + 1024, 2048, 1048576, 8*1048576,
        ASPEC, 512, 262144, 8*262144, 0.125f,
        SSROW, 512, 0, 1);
    conv_spec_k<<<dim3(8,8,4), 256, 0, stream>>>(ASPEC, ASPECCT, w_specw + l*9, w_specb + l,
                                                 SSROW);
    gmfma<2,2,float>(stream, 4, 1024, 512, 512,
        OUT, 512, 524288, ASPECCT, 512, 262144, X, 512, 524288, 1.f, 1);
    // --- conv FFN ---
    ln_k<<<4096, 256, 0, stream>>>(X, Hbuf, w_ln2w + l*512, w_ln2b + l*512);
    dwconv_k<<<4096, 256, 0, stream>>>(Hbuf, T1, w_dww + l*4608, w_dwb + l*512);
    gmfma<2,2,bf16>(stream, 4, 1024, 256, 512,
        T1, 512, 524288, w_pww + (long long)l*131072, 512, 0, T2, 256, 262144,
        1.f, 0, nullptr, BNAFF + l*512, BNAFF + l*512 + 256);
    gmfma<2,2,bf16>(stream, 4, 1024, 512, 256,
        T2, 256, 262144, w_c1w + (long long)l*131072, 256, 0, T3, 512, 524288,
        1.f, 0, w_c1b + l*512, nullptr, nullptr, nullptr, 1);
    gmfma<2,2,float>(stream, 4, 1024, 512, 512,
        T3, 512, 524288, w_c2w + (long long)l*262144, 512, 0, X, 512, 524288,
        1.f, 1, w_c2b + l*512, nullptr, nullptr, Hbuf, 1);
  }

  store_out_k<<<8192, 256, 0, stream>>>(X, d_out, FLAG);
}